// Round 2
// baseline (16703.418 us; speedup 1.0000x reference)
//
#include <hip/hip_runtime.h>
#include <stdint.h>

typedef unsigned short u16;
typedef __attribute__((ext_vector_type(8))) __bf16 bf16x8;
typedef __attribute__((ext_vector_type(4))) float f32x4;

// ---------- bf16 helpers (raw-bit, exact bf16 semantics) ----------
__device__ __forceinline__ float bf2f(u16 u) {
    union { unsigned int i; float f; } v; v.i = ((unsigned int)u) << 16; return v.f;
}
__device__ __forceinline__ float bf2f_lo(unsigned int u) {
    union { unsigned int i; float f; } v; v.i = u << 16; return v.f;
}
__device__ __forceinline__ float bf2f_hi(unsigned int u) {
    union { unsigned int i; float f; } v; v.i = u & 0xffff0000u; return v.f;
}
__device__ __forceinline__ u16 f2bf(float f) {
    union { float f; unsigned int i; } v; v.f = f;
    unsigned int x = v.i;
    unsigned int r = (x + 0x7fffu + ((x >> 16) & 1u)) >> 16;
    return (u16)r;
}
// dual-dtype read: isbf ? bf16[i] : f32[i]
__device__ __forceinline__ float rdf(const void* p, size_t i, int isbf) {
    return isbf ? bf2f(((const u16*)p)[i]) : ((const float*)p)[i];
}
__device__ __forceinline__ float fast_sigmoid(float x) {
    return __builtin_amdgcn_rcpf(1.f + __expf(-x));
}
// tanh = 1 - 2/(e^{2x}+1); exact at +-inf, NaN-free for finite x
__device__ __forceinline__ float fast_tanh(float x) {
    float u = __expf(x + x);
    return 1.f - 2.f * __builtin_amdgcn_rcpf(u + 1.f);
}
__device__ __forceinline__ float rdlane_f(float v, int l) {
    return __int_as_float(__builtin_amdgcn_readlane(__float_as_int(v), l));
}

// Problem dims
#define BB 128
#define PP 64
#define KK 64
#define HH 300
#define MROWS 8192     // B*P = B*K
#define KPAD 320       // K padded to mult of 32; also row stride for s_proj/t_proj/h_fin
#define N3H 900        // i,g,o gates only (f-gate unused: c_prev=0)

// ---------- dtype detector: w_e ~ U[0,1) -> bf16 has no sign bits in u16 view ----------
__global__ void detect_dtype(const u16* __restrict__ raw, int* __restrict__ flag) {
    __shared__ int cnt;
    if (threadIdx.x == 0) cnt = 0;
    __syncthreads();
    if (threadIdx.x < 300 && (raw[threadIdx.x] & 0x8000u)) atomicAdd(&cnt, 1);
    __syncthreads();
    if (threadIdx.x == 0) *flag = (cnt < 8) ? 1 : 0;   // 1 = bf16, 0 = fp32
}

// ---------- prepack kernels ----------
__global__ void pack_w(const void* __restrict__ src, u16* __restrict__ dst,
                       int dstRowsPad, int nsrcRows, int srcld, int colOff, int igo,
                       const int* __restrict__ flag) {
    int i = blockIdx.x * 256 + threadIdx.x;
    if (i >= dstRowsPad * KPAD) return;
    int isbf = *flag;
    int r = i / KPAD, c = i % KPAD;
    u16 v = 0;
    if (r < nsrcRows && c < HH) {
        int sr = igo ? (r < HH ? r : r + HH) : r;
        v = f2bf(rdf(src, (size_t)sr * srcld + colOff + c, isbf));
    }
    dst[i] = v;
}

// W_m packed for scan phase-1 readlane matvec:
// dst[g*152 + jp] = uint4{ pack(W[2jp][4g],W[2jp][4g+1]), pack(W[2jp][4g+2],W[2jp][4g+3]),
//                          pack(W[2jp+1][4g],...),        pack(W[2jp+1][4g+2],...) }
// g<80 (h=4g+e, zeros for h>=300), jp<152 (zeros for j>=300). Coalesced across jp.
__global__ void pack_wm4(const void* __restrict__ Wm, uint4* __restrict__ dst,
                         const int* __restrict__ flag) {
    int o = blockIdx.x * 256 + threadIdx.x;
    if (o >= 80 * 152) return;
    int isbf = *flag;
    int g = o / 152, jp = o % 152;
    int j0 = 2 * jp, j1 = 2 * jp + 1;
    unsigned int e0 = 0, e1 = 0, e2 = 0, e3 = 0, f0 = 0, f1 = 0, f2 = 0, f3 = 0;
    if (j0 < 300) {
        int h0 = 4 * g, h1 = 4 * g + 1, h2 = 4 * g + 2, h3 = 4 * g + 3;
        if (h0 < 300) e0 = f2bf(rdf(Wm, (size_t)j0 * HH + h0, isbf));
        if (h1 < 300) e1 = f2bf(rdf(Wm, (size_t)j0 * HH + h1, isbf));
        if (h2 < 300) e2 = f2bf(rdf(Wm, (size_t)j0 * HH + h2, isbf));
        if (h3 < 300) e3 = f2bf(rdf(Wm, (size_t)j0 * HH + h3, isbf));
        if (h0 < 300) f0 = f2bf(rdf(Wm, (size_t)j1 * HH + h0, isbf));
        if (h1 < 300) f1 = f2bf(rdf(Wm, (size_t)j1 * HH + h1, isbf));
        if (h2 < 300) f2 = f2bf(rdf(Wm, (size_t)j1 * HH + h2, isbf));
        if (h3 < 300) f3 = f2bf(rdf(Wm, (size_t)j1 * HH + h3, isbf));
    }
    uint4 v;
    v.x = e0 | (e1 << 16);
    v.y = e2 | (e3 << 16);
    v.z = f0 | (f1 << 16);
    v.w = f2 | (f3 << 16);
    dst[o] = v;
}

__global__ void pack_bias(const void* bip, const void* bhp, const void* bih_, const void* bhh_,
                          const void* bim, const void* bhm,
                          float* bp, float* bh, float* bm, const int* __restrict__ flag) {
    int i = blockIdx.x * 256 + threadIdx.x;
    if (i >= 3 * N3H) return;
    int isbf = *flag;
    int which = i / N3H, r = i % N3H;
    int sr = (r < HH) ? r : r + HH;
    if (which == 0)      bp[r] = rdf(bip, sr, isbf) + rdf(bhp, sr, isbf);
    else if (which == 1) bh[r] = rdf(bih_, sr, isbf) + rdf(bhh_, sr, isbf);
    else                 bm[r] = rdf(bim, sr, isbf) + rdf(bhm, sr, isbf);
}

__global__ void gather_embed(const int* __restrict__ idx, const void* __restrict__ embed,
                             u16* __restrict__ X, const int* __restrict__ flag) {
    int i = blockIdx.x * 256 + threadIdx.x;   // 8192*320 exact
    int isbf = *flag;
    int r = i / KPAD, c = i % KPAD;
    X[i] = (c < HH) ? f2bf(rdf(embed, (size_t)idx[r] * HH + c, isbf)) : (u16)0;
}

__global__ void zero_out(u16* out) { out[threadIdx.x] = 0; }

// ---------- MFMA GEMM:  C[M x N] = A[M x 320] * B[Npad x 320]^T (+bias), bf16 out ----------
// Pads columns [N, ldc) with zeros (scan reads padded rows).
__global__ __launch_bounds__(256) void gemm_bt(
    const u16* __restrict__ A, const u16* __restrict__ B,
    u16* __restrict__ Cb, const float* __restrict__ bias, int N, int ldc)
{
    __shared__ __align__(16) u16 At[128 * 32];
    __shared__ __align__(16) u16 Bt[128 * 32];
    const int tid = threadIdx.x;
    const int m0 = blockIdx.x * 128;
    const int n0 = blockIdx.y * 128;
    const int lane = tid & 63;
    const int wave = tid >> 6;
    const int rm = (wave & 1) * 64;
    const int rn = (wave >> 1) * 64;
    const int qr = lane >> 4;
    const int lr = lane & 15;

    f32x4 acc[4][4] = {};

    const int c0 = tid, c1 = tid + 256;
    const int r0 = c0 >> 2, o0 = (c0 & 3) * 8;
    const int r1 = c1 >> 2, o1 = (c1 & 3) * 8;

    for (int k0 = 0; k0 < KPAD; k0 += 32) {
        uint4 a0v = *(const uint4*)(A + (size_t)(m0 + r0) * KPAD + k0 + o0);
        uint4 a1v = *(const uint4*)(A + (size_t)(m0 + r1) * KPAD + k0 + o1);
        uint4 b0v = *(const uint4*)(B + (size_t)(n0 + r0) * KPAD + k0 + o0);
        uint4 b1v = *(const uint4*)(B + (size_t)(n0 + r1) * KPAD + k0 + o1);
        __syncthreads();
        *(uint4*)(At + c0 * 8) = a0v;
        *(uint4*)(At + c1 * 8) = a1v;
        *(uint4*)(Bt + c0 * 8) = b0v;
        *(uint4*)(Bt + c1 * 8) = b1v;
        __syncthreads();
        bf16x8 af[4], bfr[4];
        #pragma unroll
        for (int i = 0; i < 4; ++i) {
            af[i]  = *(const bf16x8*)(At + (rm + i * 16 + lr) * 32 + qr * 8);
            bfr[i] = *(const bf16x8*)(Bt + (rn + i * 16 + lr) * 32 + qr * 8);
        }
        #pragma unroll
        for (int mi = 0; mi < 4; ++mi)
            #pragma unroll
            for (int ni = 0; ni < 4; ++ni)
                acc[mi][ni] = __builtin_amdgcn_mfma_f32_16x16x32_bf16(
                    af[mi], bfr[ni], acc[mi][ni], 0, 0, 0);
    }
    // C/D layout: col(n)=lane&15, row(m)=quad*4+reg   [verified m89/m91]
    #pragma unroll
    for (int mi = 0; mi < 4; ++mi) {
        #pragma unroll
        for (int ni = 0; ni < 4; ++ni) {
            int n = n0 + rn + ni * 16 + lr;
            if (n >= ldc) continue;
            int mb = m0 + rm + mi * 16 + qr * 4;
            if (n < N) {
                float bv = bias ? bias[n] : 0.f;
                #pragma unroll
                for (int r = 0; r < 4; ++r)
                    Cb[(size_t)(mb + r) * ldc + n] = f2bf(acc[mi][ni][r] + bv);
            } else {
                #pragma unroll
                for (int r = 0; r < 4; ++r)
                    Cb[(size_t)(mb + r) * ldc + n] = 0;
            }
        }
    }
}

// ---------- LSTM0 activation ----------
__global__ void lstm_act(const u16* __restrict__ gates, u16* __restrict__ hout) {
    int idx = blockIdx.x * 256 + threadIdx.x;   // 8192*320 exact
    int r = idx / KPAD, c = idx % KPAD;
    float h = 0.f;
    if (c < HH) {
        const u16* g = gates + (size_t)r * N3H;
        float gi = bf2f(g[c]);
        float gg = bf2f(g[c + HH]);
        float go = bf2f(g[c + 2 * HH]);
        float cc = fast_sigmoid(gi) * fast_tanh(gg);
        h = fast_sigmoid(go) * fast_tanh(cc);
    }
    hout[idx] = f2bf(h);
}

// ---------- sequential scan: 512 thr/WG ----------
// v3: LDS-pipe decongestion. Phase 1 uses readlane broadcast of hm (VALU pipe) with
// coalesced double-buffered W loads; phase 2 operands (s_proj, 2*w_e) cached in VGPRs
// outside the k-loop; phase 4 streams Gm from global via two 32-deep prefetch bursts
// covered by phase-2/3 compute. LDS per iter: 5 b32 + 10 b128 / thread (was ~200).
#define P1_LOAD(W, JB) { _Pragma("unroll") \
    for (int q = 0; q < 8; ++q) W[q] = wcol[(8 * (JB) + q) * 152]; }

#define P1_CONSUME(W, JB) { \
    const int _i = (JB) >> 1; \
    float _hsrc = (_i == 0) ? hmv0 : (_i == 1) ? hmv1 : (_i == 2) ? hmv2 : (_i == 3) ? hmv3 : hmv4; \
    _Pragma("unroll") \
    for (int u = 0; u < 32; ++u) { \
        float a = rdlane_f(_hsrc, ((JB) & 1) * 32 + u); \
        uint4 wv = W[u >> 2]; \
        unsigned int q0 = (u & 2) ? wv.y : wv.x; \
        unsigned int q1 = (u & 2) ? wv.w : wv.z; \
        if (u & 1) { a01 = fmaf(a, bf2f_hi(q0), a01); a11 = fmaf(a, bf2f_hi(q1), a11); } \
        else       { a00 = fmaf(a, bf2f_lo(q0), a00); a10 = fmaf(a, bf2f_lo(q1), a10); } \
    } }

__global__ __launch_bounds__(512) void scan_kernel(
    const u16* __restrict__ sproj,            // [8192][320] bf16, pads 0
    const u16* __restrict__ tproj,            // [8192][320] bf16, pads 0
    const unsigned int* __restrict__ G32,     // [8192][450] dwords (bf16 pairs)
    const unsigned int* __restrict__ hp32,    // [8192][450] dwords (bias folded)
    const uint4* __restrict__ Wm4,            // [80][152] uint4 (4h x 2j bf16)
    const void* __restrict__ w_e,             // [300] input dtype
    const int* __restrict__ premise_len,
    const int* __restrict__ hypothesis_len,
    float* __restrict__ hfin,                 // [128][320] fp32
    const int* __restrict__ flag)
{
    __shared__ __align__(16) float we2[320];   // 2*w_e (pads 0)
    __shared__ __align__(16) float tpm[320];   // DOUBLED: 2*(t_k + m_proj); pads stay 0
    __shared__ __align__(16) float hm[320];    // pads stay 0
    __shared__ float evals[64];
    __shared__ __align__(16) float gates[912];

    const int b = blockIdx.x, t = threadIdx.x;
    const int lane = t & 63;
    const int plen = premise_len[b], hlen = hypothesis_len[b];
    const int isbf = *flag;

    if (t < 320) {
        we2[t] = (t < 300) ? 2.f * rdf(w_e, t, isbf) : 0.f;
        hm[t] = 0.f;
        tpm[t] = 0.f;
    }
    __syncthreads();

    // ---- per-thread phase-2 caches: p = t>>3, s = t&7, h-slice [40s, 40s+40) ----
    const int p2p = t >> 3, p2s = t & 7;
    float wef[40];          // 2*w_e slice (f32)
    unsigned int spd[20];   // s_proj slice (bf16 pairs)
    {
        #pragma unroll
        for (int q = 0; q < 10; ++q) {
            float4 v = ((const float4*)we2)[10 * p2s + q];
            wef[4 * q] = v.x; wef[4 * q + 1] = v.y; wef[4 * q + 2] = v.z; wef[4 * q + 3] = v.w;
        }
        const uint4* sprow = (const uint4*)(sproj + (size_t)(b * PP + p2p) * KPAD + 40 * p2s);
        #pragma unroll
        for (int q = 0; q < 5; ++q) {
            uint4 v = sprow[q];
            spd[4 * q] = v.x; spd[4 * q + 1] = v.y; spd[4 * q + 2] = v.z; spd[4 * q + 3] = v.w;
        }
    }
    float wsum = 0.f;
    #pragma unroll
    for (int h = 0; h < 40; ++h) wsum += 0.5f * wef[h];

    const unsigned int* Gb = G32 + (size_t)b * PP * 450;

    for (int k = 0; k < hlen; ++k) {
        // prefetches (consumed late; drained at barrier A which phase 1 covers)
        unsigned int hpv = 0;
        if (t < 450) hpv = hp32[(size_t)(b * KK + k) * 450 + t];          // phase 4
        unsigned int tkp = 0;
        if (t < 152) tkp = *(const unsigned int*)(tproj + (size_t)(b * KK + k) * KPAD + 2 * t);

        // ---- phase 1 (t<152): output pair (2t,2t+1); hm broadcast via readlane ----
        float hmv0 = 0.f, hmv1 = 0.f, hmv2 = 0.f, hmv3 = 0.f, hmv4 = 0.f;
        if (t < 192) {          // full waves 0-2 so all readlane sources are defined
            hmv0 = hm[lane];
            hmv1 = hm[lane + 64];
            hmv2 = hm[lane + 128];
            hmv3 = hm[lane + 192];
            hmv4 = hm[lane + 256];
        }
        if (t < 152) {
            const uint4* wcol = Wm4 + t;
            float a00 = 0.f, a01 = 0.f, a10 = 0.f, a11 = 0.f;
            uint4 wA[8], wB[8];
            P1_LOAD(wA, 0)
            P1_LOAD(wB, 1)
            #pragma unroll
            for (int jj = 0; jj < 5; ++jj) {
                P1_CONSUME(wA, 2 * jj)
                if (jj < 4) P1_LOAD(wA, 2 * jj + 2)
                P1_CONSUME(wB, 2 * jj + 1)
                if (jj < 4) P1_LOAD(wB, 2 * jj + 3)
            }
            if (t < 150) {
                tpm[2 * t]     = 2.f * (bf2f_lo(tkp) + a00 + a01);
                tpm[2 * t + 1] = 2.f * (bf2f_hi(tkp) + a10 + a11);
            }
        }
        __syncthreads();   // A: tpm final

        // Gm first-half prefetch: latency hidden under phase 2 (drained at barrier B)
        unsigned int gpre[32];
        if (t < 450) {
            #pragma unroll
            for (int j = 0; j < 32; ++j) gpre[j] = Gb[(size_t)j * 450 + t];
        }

        // ---- phase 2 (all 512): e[p] = wsum - sum we2*rcp(e^{2x}+1) ----
        {
            float accn = 0.f;
            bool act = p2p < plen;
            if (act) {
                float tpf[40];
                #pragma unroll
                for (int q = 0; q < 10; ++q) {
                    float4 v = ((const float4*)tpm)[10 * p2s + q];
                    tpf[4 * q] = v.x; tpf[4 * q + 1] = v.y; tpf[4 * q + 2] = v.z; tpf[4 * q + 3] = v.w;
                }
                #pragma unroll
                for (int h = 0; h < 40; ++h) {
                    float spf = (h & 1) ? bf2f_hi(spd[h >> 1]) : bf2f_lo(spd[h >> 1]);
                    float arg = fmaf(2.f, spf, tpf[h]);   // = 2*(sp + t_k + m_proj)
                    accn = fmaf(wef[h], __builtin_amdgcn_rcpf(__expf(arg) + 1.f), accn);
                }
            }
            float val = act ? (wsum - accn) : 0.f;
            val += __shfl_down(val, 4);
            val += __shfl_down(val, 2);
            val += __shfl_down(val, 1);
            if (p2s == 0) evals[p2p] = act ? val : -1e30f;
        }
        __syncthreads();   // B: evals ready

        // Gm second-half prefetch: covered by phase 3 + first half of phase 4
        unsigned int gv2[32];
        if (t < 450) {
            #pragma unroll
            for (int j = 0; j < 32; ++j) gv2[j] = Gb[(size_t)(32 + j) * 450 + t];
        }

        // ---- phase 3 (per-wave, redundant): softmax; lane l holds alpha[l] ----
        float al;
        {
            float v = evals[lane];
            float mx = v;
            #pragma unroll
            for (int d = 32; d; d >>= 1) mx = fmaxf(mx, __shfl_xor(mx, d));
            float ex = (lane < plen) ? __expf(v - mx) : 0.f;
            float sm = ex;
            #pragma unroll
            for (int d = 32; d; d >>= 1) sm += __shfl_xor(sm, d);
            al = ex * __builtin_amdgcn_rcpf(sm);
        }

        // ---- phase 4 (t<450): gates pair; alpha broadcast via readlane ----
        if (t < 450) {
            float g0 = bf2f_lo(hpv), g1 = bf2f_hi(hpv);
            int ali = __float_as_int(al);
            #pragma unroll
            for (int p = 0; p < 32; ++p) {
                float a = __int_as_float(__builtin_amdgcn_readlane(ali, p));
                g0 = fmaf(a, bf2f_lo(gpre[p]), g0);
                g1 = fmaf(a, bf2f_hi(gpre[p]), g1);
            }
            #pragma unroll
            for (int p = 0; p < 32; ++p) {
                float a = __int_as_float(__builtin_amdgcn_readlane(ali, p + 32));
                g0 = fmaf(a, bf2f_lo(gv2[p]), g0);
                g1 = fmaf(a, bf2f_hi(gv2[p]), g1);
            }
            float2 gw; gw.x = g0; gw.y = g1;
            ((float2*)gates)[t] = gw;
        }
        __syncthreads();   // C: gates final

        // ---- phase 5 (t<300): h_m = sig(o)*tanh(sig(i)*tanh(g)) ----
        if (t < 300) {
            float gi = gates[t], gg = gates[300 + t], go = gates[600 + t];
            float cc = fast_sigmoid(gi) * fast_tanh(gg);
            float h = fast_sigmoid(go) * fast_tanh(cc);
            hm[t] = h;
            if (k == hlen - 1) hfin[(size_t)b * KPAD + t] = h;
        }
        __syncthreads();   // D: hm ready for next phase 1
    }
}

// ---------- final FC + softmax over 3 classes (dual-dtype in AND out) ----------
__global__ void fc_softmax(const float* __restrict__ hfin, const void* __restrict__ fcw,
                           const void* __restrict__ fcb, void* __restrict__ out,
                           const int* __restrict__ flag) {
    int b = threadIdx.x;     // 128 threads, 1 block
    int isbf = *flag;
    float l[3];
    #pragma unroll
    for (int c = 0; c < 3; ++c) {
        float acc = rdf(fcb, c, isbf);
        const float* hr = hfin + (size_t)b * KPAD;
        for (int h = 0; h < HH; ++h) acc += hr[h] * rdf(fcw, (size_t)c * HH + h, isbf);
        l[c] = acc;
    }
    float mx = fmaxf(l[0], fmaxf(l[1], l[2]));
    float e0 = __expf(l[0] - mx), e1 = __expf(l[1] - mx), e2 = __expf(l[2] - mx);
    float inv = __builtin_amdgcn_rcpf(e0 + e1 + e2);
    if (isbf) {
        u16* o = (u16*)out;
        o[b * 3 + 0] = f2bf(e0 * inv);
        o[b * 3 + 1] = f2bf(e1 * inv);
        o[b * 3 + 2] = f2bf(e2 * inv);
    } else {
        float* o = (float*)out;
        o[b * 3 + 0] = e0 * inv;
        o[b * 3 + 1] = e1 * inv;
        o[b * 3 + 2] = e2 * inv;
    }
}

extern "C" void kernel_launch(void* const* d_in, const int* in_sizes, int n_in,
                              void* d_out, int out_size, void* d_ws, size_t ws_size,
                              hipStream_t stream) {
    const int* premise        = (const int*)d_in[0];
    const int* premise_len    = (const int*)d_in[1];
    const int* hypothesis     = (const int*)d_in[2];
    const int* hypothesis_len = (const int*)d_in[3];
    const void* embed = d_in[4];
    const void* w_e   = d_in[5];
    const void* W_s   = d_in[6];
    const void* W_t   = d_in[7];
    const void* W_m   = d_in[8];
    const void* fc_w  = d_in[9];
    const void* fc_b  = d_in[10];
    const void* Wih_p = d_in[11];
    const void* bih_p = d_in[13];
    const void* bhh_p = d_in[14];
    const void* Wih_h = d_in[15];
    const void* bih_h = d_in[17];
    const void* bhh_h = d_in[18];
    const void* Wih_m = d_in[19];
    const void* bih_m = d_in[21];
    const void* bhh_m = d_in[22];
    (void)in_sizes; (void)n_in; (void)out_size;

    // ---- lifetime-overlapped workspace arena (~46 MB) ----
    char* w = (char*)d_ws;
    auto alloc = [&](size_t bytes) -> char* {
        char* r = (char*)(((uintptr_t)w + 255) & ~(uintptr_t)255);
        w = r + bytes;
        return r;
    };
    char* regA = alloc((size_t)MROWS * KPAD * 2);   // Xbuf -> s_proj
    char* regB = alloc((size_t)MROWS * N3H * 2);    // gates_p -> Gm
    char* regC = alloc((size_t)MROWS * N3H * 2);    // gates_h -> hproj
    char* regD = alloc((size_t)MROWS * KPAD * 2);   // h_s -> t_proj
    char* regE = alloc((size_t)MROWS * KPAD * 2);   // h_t -> h_fin
    u16* Wp_pad  = (u16*)alloc((size_t)1024 * KPAD * 2);
    u16* Wh_pad  = (u16*)alloc((size_t)1024 * KPAD * 2);
    u16* Wa_pad  = (u16*)alloc((size_t)1024 * KPAD * 2);
    u16* Whm_pad = (u16*)alloc((size_t)1024 * KPAD * 2);
    u16* Ws_pad  = (u16*)alloc((size_t)384 * KPAD * 2);
    u16* Wt_pad  = (u16*)alloc((size_t)384 * KPAD * 2);
    uint4* Wm4   = (uint4*)alloc((size_t)80 * 152 * 16);
    float* bsum_p = (float*)alloc(N3H * 4);
    float* bsum_h = (float*)alloc(N3H * 4);
    float* bsum_m = (float*)alloc(N3H * 4);
    int* dflag   = (int*)alloc(256);
    size_t needed = (size_t)(w - (char*)d_ws);
    if (needed > ws_size) {
        zero_out<<<1, 384, 0, stream>>>((u16*)d_out);
        return;
    }
    u16* Xbuf   = (u16*)regA;
    u16* s_proj = (u16*)regA;                       // after Xbuf dead
    u16* h_s    = (u16*)regD;
    u16* t_proj = (u16*)regD;                       // after h_s dead
    u16* h_t    = (u16*)regE;
    float* h_fin = (float*)regE;                    // after h_t dead (scan time)

    // dtype detect, then prepack
    detect_dtype<<<1, 320, 0, stream>>>((const u16*)w_e, dflag);
    pack_w<<<1280, 256, 0, stream>>>(Wih_p, Wp_pad, 1024, N3H, HH, 0, 1, dflag);
    pack_w<<<1280, 256, 0, stream>>>(Wih_h, Wh_pad, 1024, N3H, HH, 0, 1, dflag);
    pack_w<<<1280, 256, 0, stream>>>(Wih_m, Wa_pad, 1024, N3H, 600, 0, 1, dflag);
    pack_w<<<1280, 256, 0, stream>>>(Wih_m, Whm_pad, 1024, N3H, 600, HH, 1, dflag);
    pack_w<<<480, 256, 0, stream>>>(W_s, Ws_pad, 384, HH, HH, 0, 0, dflag);
    pack_w<<<480, 256, 0, stream>>>(W_t, Wt_pad, 384, HH, HH, 0, 0, dflag);
    pack_wm4<<<48, 256, 0, stream>>>(W_m, Wm4, dflag);
    pack_bias<<<11, 256, 0, stream>>>(bih_p, bhh_p, bih_h, bhh_h, bih_m, bhh_m,
                                      bsum_p, bsum_h, bsum_m, dflag);

    // premise: gather -> gates (bias folded) -> h_s
    gather_embed<<<10240, 256, 0, stream>>>(premise, embed, Xbuf, dflag);
    gemm_bt<<<dim3(64, 8), 256, 0, stream>>>(Xbuf, Wp_pad, (u16*)regB, bsum_p, N3H, N3H);
    lstm_act<<<10240, 256, 0, stream>>>((u16*)regB, h_s);
    // hypothesis: reuse Xbuf
    gather_embed<<<10240, 256, 0, stream>>>(hypothesis, embed, Xbuf, dflag);
    gemm_bt<<<dim3(64, 8), 256, 0, stream>>>(Xbuf, Wh_pad, (u16*)regC, bsum_h, N3H, N3H);
    lstm_act<<<10240, 256, 0, stream>>>((u16*)regC, h_t);

    // projections (ordering chosen so region reuse is safe); zero-padded to KPAD cols
    gemm_bt<<<dim3(64, 3), 256, 0, stream>>>(h_s, Ws_pad, s_proj, nullptr, HH, KPAD);     // into A (Xbuf dead)
    gemm_bt<<<dim3(64, 8), 256, 0, stream>>>(h_s, Wa_pad, (u16*)regB, nullptr, N3H, N3H); // Gm into B
    gemm_bt<<<dim3(64, 3), 256, 0, stream>>>(h_t, Wt_pad, t_proj, nullptr, HH, KPAD);     // into D (h_s dead)
    gemm_bt<<<dim3(64, 8), 256, 0, stream>>>(h_t, Whm_pad, (u16*)regC, bsum_m, N3H, N3H); // hproj into C

    // sequential match-LSTM scan, one WG per batch, 512 threads
    scan_kernel<<<BB, 512, 0, stream>>>(s_proj, t_proj, (const unsigned int*)regB,
                                        (const unsigned int*)regC, Wm4, w_e,
                                        premise_len, hypothesis_len, h_fin, dflag);
    // classifier
    fc_softmax<<<1, 128, 0, stream>>>(h_fin, fc_w, fc_b, d_out, dflag);
}

// Round 3
// 694.244 us; speedup vs baseline: 24.0599x; 24.0599x over previous
//
#include <hip/hip_runtime.h>
#include <stdint.h>

typedef unsigned short u16;
typedef __attribute__((ext_vector_type(8))) __bf16 bf16x8;
typedef __attribute__((ext_vector_type(4))) float f32x4;

// ---------- bf16 helpers (raw-bit, exact bf16 semantics) ----------
__device__ __forceinline__ float bf2f(u16 u) {
    union { unsigned int i; float f; } v; v.i = ((unsigned int)u) << 16; return v.f;
}
__device__ __forceinline__ float bf2f_lo(unsigned int u) {
    union { unsigned int i; float f; } v; v.i = u << 16; return v.f;
}
__device__ __forceinline__ float bf2f_hi(unsigned int u) {
    union { unsigned int i; float f; } v; v.i = u & 0xffff0000u; return v.f;
}
__device__ __forceinline__ u16 f2bf(float f) {
    union { float f; unsigned int i; } v; v.f = f;
    unsigned int x = v.i;
    unsigned int r = (x + 0x7fffu + ((x >> 16) & 1u)) >> 16;
    return (u16)r;
}
__device__ __forceinline__ float rdf(const void* p, size_t i, int isbf) {
    return isbf ? bf2f(((const u16*)p)[i]) : ((const float*)p)[i];
}
__device__ __forceinline__ float fast_sigmoid(float x) {
    return __builtin_amdgcn_rcpf(1.f + __expf(-x));
}
__device__ __forceinline__ float fast_tanh(float x) {
    float u = __expf(x + x);
    return 1.f - 2.f * __builtin_amdgcn_rcpf(u + 1.f);
}
__device__ __forceinline__ bf16x8 as_bf8(uint4 u) {
    union { uint4 a; bf16x8 b; } c; c.a = u; return c.b;
}

// Problem dims
#define BB 128
#define PP 64
#define KK 64
#define HH 300
#define MROWS 8192     // B*P = B*K
#define KPAD 320       // K padded; row stride for s_proj/t_proj/h_fin
#define N3H 900        // i,g,o gates only (f-gate unused: c_prev=0)
#define GLD 912        // Gm frag-padded col count (57 tiles x 16)
#define NT1 19         // phase-1 N-tiles (304 cols)
#define NT4 57         // phase-4 N-tiles (912 cols)

// ---------- dtype detector ----------
__global__ void detect_dtype(const u16* __restrict__ raw, int* __restrict__ flag) {
    __shared__ int cnt;
    if (threadIdx.x == 0) cnt = 0;
    __syncthreads();
    if (threadIdx.x < 300 && (raw[threadIdx.x] & 0x8000u)) atomicAdd(&cnt, 1);
    __syncthreads();
    if (threadIdx.x == 0) *flag = (cnt < 8) ? 1 : 0;   // 1 = bf16, 0 = fp32
}

// ---------- prepack kernels ----------
__global__ void pack_w(const void* __restrict__ src, u16* __restrict__ dst,
                       int dstRowsPad, int nsrcRows, int srcld, int colOff, int igo,
                       const int* __restrict__ flag) {
    int i = blockIdx.x * 256 + threadIdx.x;
    if (i >= dstRowsPad * KPAD) return;
    int isbf = *flag;
    int r = i / KPAD, c = i % KPAD;
    u16 v = 0;
    if (r < nsrcRows && c < HH) {
        int sr = igo ? (r < HH ? r : r + HH) : r;
        v = f2bf(rdf(src, (size_t)sr * srcld + colOff + c, isbf));
    }
    dst[i] = v;
}

// W_m packed to MFMA B-fragment layout: Wf[T][ks][lane] = bf16x8 of
// W_m[j = T*16 + (lane&15)][k = 32*ks + 8*(lane>>4) + e], e<8; zeros outside 300x300.
__global__ void pack_wf(const void* __restrict__ Wm, uint4* __restrict__ dst,
                        const int* __restrict__ flag) {
    int i = blockIdx.x * 256 + threadIdx.x;
    if (i >= NT1 * 10 * 64) return;
    int isbf = *flag;
    int lane = i & 63, ks = (i >> 6) % 10, T = i / 640;
    int j = T * 16 + (lane & 15);
    int k0 = 32 * ks + 8 * (lane >> 4);
    unsigned int d[4];
    #pragma unroll
    for (int q = 0; q < 4; ++q) {
        int ka = k0 + 2 * q, kb = k0 + 2 * q + 1;
        unsigned int lo = (j < 300 && ka < 300) ? f2bf(rdf(Wm, (size_t)j * HH + ka, isbf)) : 0;
        unsigned int hi = (j < 300 && kb < 300) ? f2bf(rdf(Wm, (size_t)j * HH + kb, isbf)) : 0;
        d[q] = lo | (hi << 16);
    }
    uint4 v; v.x = d[0]; v.y = d[1]; v.z = d[2]; v.w = d[3];
    dst[i] = v;
}

__global__ void pack_bias(const void* bip, const void* bhp, const void* bih_, const void* bhh_,
                          const void* bim, const void* bhm,
                          float* bp, float* bh, float* bm, const int* __restrict__ flag) {
    int i = blockIdx.x * 256 + threadIdx.x;
    if (i >= 3 * N3H) return;
    int isbf = *flag;
    int which = i / N3H, r = i % N3H;
    int sr = (r < HH) ? r : r + HH;
    if (which == 0)      bp[r] = rdf(bip, sr, isbf) + rdf(bhp, sr, isbf);
    else if (which == 1) bh[r] = rdf(bih_, sr, isbf) + rdf(bhh_, sr, isbf);
    else                 bm[r] = rdf(bim, sr, isbf) + rdf(bhm, sr, isbf);
}

__global__ void gather_embed(const int* __restrict__ idx, const void* __restrict__ embed,
                             u16* __restrict__ X, const int* __restrict__ flag) {
    int i = blockIdx.x * 256 + threadIdx.x;   // 8192*320 exact
    int isbf = *flag;
    int r = i / KPAD, c = i % KPAD;
    X[i] = (c < HH) ? f2bf(rdf(embed, (size_t)idx[r] * HH + c, isbf)) : (u16)0;
}

__global__ void zero_out(u16* out) { out[threadIdx.x] = 0; }

// ---------- MFMA GEMM:  C[M x N] = A[M x 320] * B[Npad x 320]^T (+bias) ----------
// frag=0: bf16 row-major out, cols [N, ldc) zero-padded.
// frag=1: write MFMA B-fragment layout for the scan's phase-4:
//   dst u16 idx = ((((row>>6)*57 + (n>>4))*2 + (p>>5))*64 + ((p>>3)&3)*16 + (n&15))*8 + (p&7),
//   p = row&63; cols [N, 912) zero-filled. (4 consecutive rows -> one uint2 store)
__global__ __launch_bounds__(256) void gemm_bt(
    const u16* __restrict__ A, const u16* __restrict__ B,
    u16* __restrict__ Cb, const float* __restrict__ bias, int N, int ldc, int frag)
{
    __shared__ __align__(16) u16 At[128 * 32];
    __shared__ __align__(16) u16 Bt[128 * 32];
    const int tid = threadIdx.x;
    const int m0 = blockIdx.x * 128;
    const int n0 = blockIdx.y * 128;
    const int lane = tid & 63;
    const int wave = tid >> 6;
    const int rm = (wave & 1) * 64;
    const int rn = (wave >> 1) * 64;
    const int qr = lane >> 4;
    const int lr = lane & 15;

    f32x4 acc[4][4] = {};

    const int c0 = tid, c1 = tid + 256;
    const int r0 = c0 >> 2, o0 = (c0 & 3) * 8;
    const int r1 = c1 >> 2, o1 = (c1 & 3) * 8;

    for (int k0 = 0; k0 < KPAD; k0 += 32) {
        uint4 a0v = *(const uint4*)(A + (size_t)(m0 + r0) * KPAD + k0 + o0);
        uint4 a1v = *(const uint4*)(A + (size_t)(m0 + r1) * KPAD + k0 + o1);
        uint4 b0v = *(const uint4*)(B + (size_t)(n0 + r0) * KPAD + k0 + o0);
        uint4 b1v = *(const uint4*)(B + (size_t)(n0 + r1) * KPAD + k0 + o1);
        __syncthreads();
        *(uint4*)(At + c0 * 8) = a0v;
        *(uint4*)(At + c1 * 8) = a1v;
        *(uint4*)(Bt + c0 * 8) = b0v;
        *(uint4*)(Bt + c1 * 8) = b1v;
        __syncthreads();
        bf16x8 af[4], bfr[4];
        #pragma unroll
        for (int i = 0; i < 4; ++i) {
            af[i]  = *(const bf16x8*)(At + (rm + i * 16 + lr) * 32 + qr * 8);
            bfr[i] = *(const bf16x8*)(Bt + (rn + i * 16 + lr) * 32 + qr * 8);
        }
        #pragma unroll
        for (int mi = 0; mi < 4; ++mi)
            #pragma unroll
            for (int ni = 0; ni < 4; ++ni)
                acc[mi][ni] = __builtin_amdgcn_mfma_f32_16x16x32_bf16(
                    af[mi], bfr[ni], acc[mi][ni], 0, 0, 0);
    }
    // C/D layout: col(n)=lane&15, row(m)=quad*4+reg   [verified m89/m91]
    #pragma unroll
    for (int mi = 0; mi < 4; ++mi) {
        #pragma unroll
        for (int ni = 0; ni < 4; ++ni) {
            int n = n0 + rn + ni * 16 + lr;
            int mb = m0 + rm + mi * 16 + qr * 4;
            if (!frag) {
                if (n >= ldc) continue;
                if (n < N) {
                    float bv = bias ? bias[n] : 0.f;
                    #pragma unroll
                    for (int r = 0; r < 4; ++r)
                        Cb[(size_t)(mb + r) * ldc + n] = f2bf(acc[mi][ni][r] + bv);
                } else {
                    #pragma unroll
                    for (int r = 0; r < 4; ++r)
                        Cb[(size_t)(mb + r) * ldc + n] = 0;
                }
            } else {
                if (n >= GLD) continue;
                int bb = mb >> 6, p0 = mb & 63;
                size_t base = ((((size_t)bb * NT4 + (n >> 4)) * 2 + (p0 >> 5)) * 64
                               + ((p0 >> 3) & 3) * 16 + (n & 15)) * 8 + (p0 & 7);
                u16 wv[4];
                if (n < N) {
                    float bv = bias ? bias[n] : 0.f;
                    #pragma unroll
                    for (int r = 0; r < 4; ++r) wv[r] = f2bf(acc[mi][ni][r] + bv);
                } else {
                    #pragma unroll
                    for (int r = 0; r < 4; ++r) wv[r] = 0;
                }
                uint2 st;
                st.x = (unsigned int)wv[0] | ((unsigned int)wv[1] << 16);
                st.y = (unsigned int)wv[2] | ((unsigned int)wv[3] << 16);
                *(uint2*)(Cb + base) = st;
            }
        }
    }
}

// ---------- LSTM0 activation ----------
__global__ void lstm_act(const u16* __restrict__ gates, u16* __restrict__ hout) {
    int idx = blockIdx.x * 256 + threadIdx.x;   // 8192*320 exact
    int r = idx / KPAD, c = idx % KPAD;
    float h = 0.f;
    if (c < HH) {
        const u16* g = gates + (size_t)r * N3H;
        float gi = bf2f(g[c]);
        float gg = bf2f(g[c + HH]);
        float go = bf2f(g[c + 2 * HH]);
        float cc = fast_sigmoid(gi) * fast_tanh(gg);
        h = fast_sigmoid(go) * fast_tanh(cc);
    }
    hout[idx] = f2bf(h);
}

// ---------- sequential scan: 512 thr/WG, MFMA matvecs ----------
// v4: phases 1 & 4 on the matrix pipe. A-rows 0/1 carry hi/lo bf16 split of the
// f32 vector (hm or alpha) -> ~f32 precision. W_m frags streamed from L2 with a
// 2-deep register double buffer; Gm frags staged once in LDS (iteration-invariant).
__global__ __launch_bounds__(512, 2) void scan_kernel(
    const u16* __restrict__ sproj,            // [8192][320] bf16, pads 0
    const u16* __restrict__ tproj,            // [8192][320] bf16, pads 0
    const uint4* __restrict__ Gmf,            // [128][57][2][64] frags
    const u16* __restrict__ hp,               // [8192][900] bf16 (bias folded)
    const uint4* __restrict__ Wf,             // [19][10][64] frags
    const void* __restrict__ w_e,             // [300] input dtype
    const int* __restrict__ premise_len,
    const int* __restrict__ hypothesis_len,
    float* __restrict__ hfin,                 // [128][320] fp32
    const int* __restrict__ flag)
{
    __shared__ __align__(16) uint4 gml[NT4 * 2 * 64];   // 116736 B
    __shared__ __align__(16) float we2[320];            // 2*w_e (pads 0)
    __shared__ __align__(16) float tpm[304];            // 2*(t_k + m_proj)
    __shared__ __align__(16) unsigned int hmhi[160];    // hm hi bf16 pairs (pads 0)
    __shared__ __align__(16) unsigned int hmlo[160];    // hm lo residual pairs
    __shared__ __align__(16) u16 ahi[64];               // alpha hi bf16
    __shared__ __align__(16) u16 alo[64];               // alpha lo residual
    __shared__ float evals[64];
    __shared__ __align__(16) float gates[912];

    const int b = blockIdx.x, t = threadIdx.x;
    const int lane = t & 63, w = t >> 6;
    const int lr = lane & 15, qr = lane >> 4;
    const int plen = premise_len[b], hlen = hypothesis_len[b];
    const int isbf = *flag;

    {   // stage Gm frags (iteration-invariant)
        const uint4* gsrc = Gmf + (size_t)b * (NT4 * 2 * 64);
        for (int i = t; i < NT4 * 2 * 64; i += 512) gml[i] = gsrc[i];
    }
    if (t < 320) we2[t] = (t < 300) ? 2.f * rdf(w_e, t, isbf) : 0.f;
    if (t < 160) { hmhi[t] = 0; hmlo[t] = 0; }   // hm starts at 0; pads stay 0
    __syncthreads();

    // phase-2 per-thread pinned s_proj slice (p = t>>3, s = t&7, v1 interleaving)
    const int p2p = t >> 3, p2s = t & 7;
    unsigned int spd[19];
    {
        const unsigned int* sprow = (const unsigned int*)(sproj + (size_t)(b * PP + p2p) * KPAD);
        #pragma unroll
        for (int i = 0; i < 19; ++i) spd[i] = sprow[p2s + 8 * i];
    }
    float wsum = 0.f;
    #pragma unroll
    for (int i = 0; i < 19; ++i) {
        float2 wv = ((const float2*)we2)[p2s + 8 * i];
        wsum += 0.5f * (wv.x + wv.y);
    }

    const int nt4 = (w == 0) ? 8 : 7;   // phase-4 tiles: T = w + 8i (57 total)

    for (int k = 0; k < hlen; ++k) {
        const u16* tprow = tproj + (size_t)(b * KK + k) * KPAD;
        const u16* hprow = hp + (size_t)(b * KK + k) * 900;

        // iter-start prefetches (lane<16 = the writer lanes)
        u16 hpv[8];
        #pragma unroll
        for (int i = 0; i < 8; ++i) {
            hpv[i] = 0;
            if (i < nt4 && lane < 16) hpv[i] = hprow[(w + 8 * i) * 16 + lane];
        }
        u16 tk0 = 0, tk1 = 0, tk2 = 0;
        if (lane < 16) {
            tk0 = tprow[w * 16 + lane];
            tk1 = tprow[(w + 8) * 16 + lane];
            if (w < 3) tk2 = tprow[(w + 16) * 16 + lane];
        }

        // ---- phase 1: tpm = 2*(t_k + hm . W_m^T) via MFMA ----
        // tiles: w, w+8, (w+16 if w<3) -> covers 19 tiles across 8 waves
        uint4 bA[10], bB[10];
        #pragma unroll
        for (int ks = 0; ks < 10; ++ks) bA[ks] = Wf[(size_t)w * 640 + ks * 64 + lane];
        #pragma unroll
        for (int ks = 0; ks < 10; ++ks) bB[ks] = Wf[(size_t)(w + 8) * 640 + ks * 64 + lane];

        bf16x8 a1[10];
        {
            const unsigned int* abase = (lr == 1) ? hmlo : hmhi;
            uint4 z; z.x = 0; z.y = 0; z.z = 0; z.w = 0;
            #pragma unroll
            for (int ks = 0; ks < 10; ++ks) {
                uint4 u = *(const uint4*)(abase + 16 * ks + 4 * qr);
                a1[ks] = as_bf8((lr < 2) ? u : z);
            }
        }
        {   // tile w
            f32x4 acc = {};
            #pragma unroll
            for (int ks = 0; ks < 10; ++ks)
                acc = __builtin_amdgcn_mfma_f32_16x16x32_bf16(a1[ks], as_bf8(bA[ks]), acc, 0, 0, 0);
            if (lane < 16) tpm[w * 16 + lane] = 2.f * (bf2f(tk0) + acc[0] + acc[1]);
        }
        if (w < 3) {   // refill bA with tile w+16 while tile w+8 computes
            #pragma unroll
            for (int ks = 0; ks < 10; ++ks) bA[ks] = Wf[(size_t)(w + 16) * 640 + ks * 64 + lane];
        }
        {   // tile w+8
            f32x4 acc = {};
            #pragma unroll
            for (int ks = 0; ks < 10; ++ks)
                acc = __builtin_amdgcn_mfma_f32_16x16x32_bf16(a1[ks], as_bf8(bB[ks]), acc, 0, 0, 0);
            if (lane < 16) tpm[(w + 8) * 16 + lane] = 2.f * (bf2f(tk1) + acc[0] + acc[1]);
        }
        if (w < 3) {   // tile w+16
            f32x4 acc = {};
            #pragma unroll
            for (int ks = 0; ks < 10; ++ks)
                acc = __builtin_amdgcn_mfma_f32_16x16x32_bf16(a1[ks], as_bf8(bA[ks]), acc, 0, 0, 0);
            if (lane < 16) tpm[(w + 16) * 16 + lane] = 2.f * (bf2f(tk2) + acc[0] + acc[1]);
        }
        __syncthreads();   // A: tpm final

        // ---- phase 2 (all 512): e[p] = wsum - sum we2*rcp(e^{2x}+1); 8 lanes per p ----
        {
            float accn = 0.f;
            bool act = p2p < plen;
            if (act) {
                #pragma unroll
                for (int i = 0; i < 19; ++i) {
                    unsigned int spv = spd[i];
                    float2 tv = ((const float2*)tpm)[p2s + 8 * i];
                    float2 wv = ((const float2*)we2)[p2s + 8 * i];
                    float x0 = fmaf(2.f, bf2f_lo(spv), tv.x);
                    float x1 = fmaf(2.f, bf2f_hi(spv), tv.y);
                    accn = fmaf(wv.x, __builtin_amdgcn_rcpf(__expf(x0) + 1.f), accn);
                    accn = fmaf(wv.y, __builtin_amdgcn_rcpf(__expf(x1) + 1.f), accn);
                }
            }
            float val = act ? (wsum - accn) : 0.f;
            val += __shfl_down(val, 4);
            val += __shfl_down(val, 2);
            val += __shfl_down(val, 1);
            if (p2s == 0) evals[p2p] = act ? val : -1e30f;
        }
        __syncthreads();   // B: evals ready

        // ---- phase 3 (wave 0 only): softmax + hi/lo bf16 pack of alpha ----
        if (w == 0) {
            float v = evals[lane];
            float mx = v;
            #pragma unroll
            for (int d = 32; d; d >>= 1) mx = fmaxf(mx, __shfl_xor(mx, d));
            float ex = (lane < plen) ? __expf(v - mx) : 0.f;
            float sm = ex;
            #pragma unroll
            for (int d = 32; d; d >>= 1) sm += __shfl_xor(sm, d);
            float al = ex * __builtin_amdgcn_rcpf(sm);
            u16 ah = f2bf(al);
            ahi[lane] = ah;
            alo[lane] = f2bf(al - bf2f(ah));
        }
        __syncthreads();   // B2: alpha packed

        // ---- phase 4: gates = alpha . Gm via MFMA (Gm frags LDS-resident) ----
        bf16x8 a4[2];
        {
            const u16* abase = (lr == 1) ? alo : ahi;
            uint4 z; z.x = 0; z.y = 0; z.z = 0; z.w = 0;
            #pragma unroll
            for (int ks = 0; ks < 2; ++ks) {
                uint4 u = *(const uint4*)(abase + 32 * ks + 8 * qr);
                a4[ks] = as_bf8((lr < 2) ? u : z);
            }
        }
        #pragma unroll
        for (int i = 0; i < 8; ++i) {
            if (i < nt4) {
                int T = w + 8 * i;
                bf16x8 g0 = as_bf8(gml[(T * 2 + 0) * 64 + lane]);
                bf16x8 g1 = as_bf8(gml[(T * 2 + 1) * 64 + lane]);
                f32x4 acc = {};
                acc = __builtin_amdgcn_mfma_f32_16x16x32_bf16(a4[0], g0, acc, 0, 0, 0);
                acc = __builtin_amdgcn_mfma_f32_16x16x32_bf16(a4[1], g1, acc, 0, 0, 0);
                if (lane < 16) gates[T * 16 + lane] = acc[0] + acc[1] + bf2f(hpv[i]);
            }
        }
        __syncthreads();   // C: gates final

        // ---- phase 5 (t<300): h_m = sig(o)*tanh(sig(i)*tanh(g)); pack hi/lo pairs ----
        if (t < 300) {
            float gi = gates[t], gg = gates[300 + t], go = gates[600 + t];
            float cc = fast_sigmoid(gi) * fast_tanh(gg);
            float h = fast_sigmoid(go) * fast_tanh(cc);
            if (k == hlen - 1) hfin[(size_t)b * KPAD + t] = h;
            u16 hh = f2bf(h);
            float res = h - bf2f(hh);
            float hn = __shfl_down(h, 1);     // partner t+1 (same wave, active)
            float rn2 = __shfl_down(res, 1);
            if ((t & 1) == 0) {
                hmhi[t >> 1] = (unsigned int)hh | ((unsigned int)f2bf(hn) << 16);
                hmlo[t >> 1] = (unsigned int)f2bf(res) | ((unsigned int)f2bf(rn2) << 16);
            }
        }
        __syncthreads();   // D: hm frags ready for next phase 1
    }
}

// ---------- final FC + softmax over 3 classes (dual-dtype in AND out) ----------
__global__ void fc_softmax(const float* __restrict__ hfin, const void* __restrict__ fcw,
                           const void* __restrict__ fcb, void* __restrict__ out,
                           const int* __restrict__ flag) {
    int b = threadIdx.x;     // 128 threads, 1 block
    int isbf = *flag;
    float l[3];
    #pragma unroll
    for (int c = 0; c < 3; ++c) {
        float acc = rdf(fcb, c, isbf);
        const float* hr = hfin + (size_t)b * KPAD;
        for (int h = 0; h < HH; ++h) acc += hr[h] * rdf(fcw, (size_t)c * HH + h, isbf);
        l[c] = acc;
    }
    float mx = fmaxf(l[0], fmaxf(l[1], l[2]));
    float e0 = __expf(l[0] - mx), e1 = __expf(l[1] - mx), e2 = __expf(l[2] - mx);
    float inv = __builtin_amdgcn_rcpf(e0 + e1 + e2);
    if (isbf) {
        u16* o = (u16*)out;
        o[b * 3 + 0] = f2bf(e0 * inv);
        o[b * 3 + 1] = f2bf(e1 * inv);
        o[b * 3 + 2] = f2bf(e2 * inv);
    } else {
        float* o = (float*)out;
        o[b * 3 + 0] = e0 * inv;
        o[b * 3 + 1] = e1 * inv;
        o[b * 3 + 2] = e2 * inv;
    }
}

extern "C" void kernel_launch(void* const* d_in, const int* in_sizes, int n_in,
                              void* d_out, int out_size, void* d_ws, size_t ws_size,
                              hipStream_t stream) {
    const int* premise        = (const int*)d_in[0];
    const int* premise_len    = (const int*)d_in[1];
    const int* hypothesis     = (const int*)d_in[2];
    const int* hypothesis_len = (const int*)d_in[3];
    const void* embed = d_in[4];
    const void* w_e   = d_in[5];
    const void* W_s   = d_in[6];
    const void* W_t   = d_in[7];
    const void* W_m   = d_in[8];
    const void* fc_w  = d_in[9];
    const void* fc_b  = d_in[10];
    const void* Wih_p = d_in[11];
    const void* bih_p = d_in[13];
    const void* bhh_p = d_in[14];
    const void* Wih_h = d_in[15];
    const void* bih_h = d_in[17];
    const void* bhh_h = d_in[18];
    const void* Wih_m = d_in[19];
    const void* bih_m = d_in[21];
    const void* bhh_m = d_in[22];
    (void)in_sizes; (void)n_in; (void)out_size;

    // ---- lifetime-overlapped workspace arena ----
    char* w = (char*)d_ws;
    auto alloc = [&](size_t bytes) -> char* {
        char* r = (char*)(((uintptr_t)w + 255) & ~(uintptr_t)255);
        w = r + bytes;
        return r;
    };
    char* regA = alloc((size_t)MROWS * KPAD * 2);   // Xbuf -> s_proj
    char* regB = alloc((size_t)MROWS * GLD * 2);    // gates_p -> Gm frags (14.94 MB)
    char* regC = alloc((size_t)MROWS * N3H * 2);    // gates_h -> hproj
    char* regD = alloc((size_t)MROWS * KPAD * 2);   // h_s -> t_proj
    char* regE = alloc((size_t)MROWS * KPAD * 2);   // h_t -> h_fin
    u16* Wp_pad  = (u16*)alloc((size_t)1024 * KPAD * 2);
    u16* Wh_pad  = (u16*)alloc((size_t)1024 * KPAD * 2);
    u16* Wa_pad  = (u16*)alloc((size_t)1024 * KPAD * 2);
    u16* Whm_pad = (u16*)alloc((size_t)1024 * KPAD * 2);
    u16* Ws_pad  = (u16*)alloc((size_t)384 * KPAD * 2);
    u16* Wt_pad  = (u16*)alloc((size_t)384 * KPAD * 2);
    uint4* Wf    = (uint4*)alloc((size_t)NT1 * 10 * 64 * 16);
    float* bsum_p = (float*)alloc(N3H * 4);
    float* bsum_h = (float*)alloc(N3H * 4);
    float* bsum_m = (float*)alloc(N3H * 4);
    int* dflag   = (int*)alloc(256);
    size_t needed = (size_t)(w - (char*)d_ws);
    if (needed > ws_size) {
        zero_out<<<1, 384, 0, stream>>>((u16*)d_out);
        return;
    }
    u16* Xbuf   = (u16*)regA;
    u16* s_proj = (u16*)regA;                       // after Xbuf dead
    u16* h_s    = (u16*)regD;
    u16* t_proj = (u16*)regD;                       // after h_s dead
    u16* h_t    = (u16*)regE;
    float* h_fin = (float*)regE;                    // after h_t dead (scan time)

    // dtype detect, then prepack
    detect_dtype<<<1, 320, 0, stream>>>((const u16*)w_e, dflag);
    pack_w<<<1280, 256, 0, stream>>>(Wih_p, Wp_pad, 1024, N3H, HH, 0, 1, dflag);
    pack_w<<<1280, 256, 0, stream>>>(Wih_h, Wh_pad, 1024, N3H, HH, 0, 1, dflag);
    pack_w<<<1280, 256, 0, stream>>>(Wih_m, Wa_pad, 1024, N3H, 600, 0, 1, dflag);
    pack_w<<<1280, 256, 0, stream>>>(Wih_m, Whm_pad, 1024, N3H, 600, HH, 1, dflag);
    pack_w<<<480, 256, 0, stream>>>(W_s, Ws_pad, 384, HH, HH, 0, 0, dflag);
    pack_w<<<480, 256, 0, stream>>>(W_t, Wt_pad, 384, HH, HH, 0, 0, dflag);
    pack_wf<<<48, 256, 0, stream>>>(W_m, Wf, dflag);
    pack_bias<<<11, 256, 0, stream>>>(bih_p, bhh_p, bih_h, bhh_h, bih_m, bhh_m,
                                      bsum_p, bsum_h, bsum_m, dflag);

    // premise: gather -> gates (bias folded) -> h_s
    gather_embed<<<10240, 256, 0, stream>>>(premise, embed, Xbuf, dflag);
    gemm_bt<<<dim3(64, 8), 256, 0, stream>>>(Xbuf, Wp_pad, (u16*)regB, bsum_p, N3H, N3H, 0);
    lstm_act<<<10240, 256, 0, stream>>>((u16*)regB, h_s);
    // hypothesis: reuse Xbuf
    gather_embed<<<10240, 256, 0, stream>>>(hypothesis, embed, Xbuf, dflag);
    gemm_bt<<<dim3(64, 8), 256, 0, stream>>>(Xbuf, Wh_pad, (u16*)regC, bsum_h, N3H, N3H, 0);
    lstm_act<<<10240, 256, 0, stream>>>((u16*)regC, h_t);

    // projections (ordering chosen so region reuse is safe)
    gemm_bt<<<dim3(64, 3), 256, 0, stream>>>(h_s, Ws_pad, s_proj, nullptr, HH, KPAD, 0);   // into A (Xbuf dead)
    gemm_bt<<<dim3(64, 8), 256, 0, stream>>>(h_s, Wa_pad, (u16*)regB, nullptr, N3H, 0, 1); // Gm FRAGS into B
    gemm_bt<<<dim3(64, 3), 256, 0, stream>>>(h_t, Wt_pad, t_proj, nullptr, HH, KPAD, 0);   // into D (h_s dead)
    gemm_bt<<<dim3(64, 8), 256, 0, stream>>>(h_t, Whm_pad, (u16*)regC, bsum_m, N3H, N3H, 0); // hproj into C

    // sequential match-LSTM scan, one WG per batch, 512 threads
    scan_kernel<<<BB, 512, 0, stream>>>(s_proj, t_proj, (const uint4*)regB,
                                        (const u16*)regC, Wf, w_e,
                                        premise_len, hypothesis_len, h_fin, dflag);
    // classifier
    fc_softmax<<<1, 128, 0, stream>>>(h_fin, fc_w, fc_b, d_out, dflag);
}

// Round 4
// 688.772 us; speedup vs baseline: 24.2510x; 1.0079x over previous
//
#include <hip/hip_runtime.h>
#include <stdint.h>

typedef unsigned short u16;
typedef __attribute__((ext_vector_type(8))) __bf16 bf16x8;
typedef __attribute__((ext_vector_type(4))) float f32x4;

// ---------- bf16 helpers (raw-bit, exact bf16 semantics) ----------
__device__ __forceinline__ float bf2f(u16 u) {
    union { unsigned int i; float f; } v; v.i = ((unsigned int)u) << 16; return v.f;
}
__device__ __forceinline__ float bf2f_lo(unsigned int u) {
    union { unsigned int i; float f; } v; v.i = u << 16; return v.f;
}
__device__ __forceinline__ float bf2f_hi(unsigned int u) {
    union { unsigned int i; float f; } v; v.i = u & 0xffff0000u; return v.f;
}
__device__ __forceinline__ u16 f2bf(float f) {
    union { float f; unsigned int i; } v; v.f = f;
    unsigned int x = v.i;
    unsigned int r = (x + 0x7fffu + ((x >> 16) & 1u)) >> 16;
    return (u16)r;
}
__device__ __forceinline__ float rdf(const void* p, size_t i, int isbf) {
    return isbf ? bf2f(((const u16*)p)[i]) : ((const float*)p)[i];
}
__device__ __forceinline__ float fast_sigmoid(float x) {
    return __builtin_amdgcn_rcpf(1.f + __expf(-x));
}
__device__ __forceinline__ float fast_tanh(float x) {
    float u = __expf(x + x);
    return 1.f - 2.f * __builtin_amdgcn_rcpf(u + 1.f);
}
__device__ __forceinline__ bf16x8 as_bf8(uint4 u) {
    union { uint4 a; bf16x8 b; } c; c.a = u; return c.b;
}

// Problem dims
#define BB 128
#define PP 64
#define KK 64
#define HH 300
#define MROWS 8192     // B*P = B*K
#define KPAD 320       // K padded; row stride for s_proj/t_proj/h_fin
#define N3H 900        // i,g,o gates only (f-gate unused: c_prev=0)
#define GLD 912        // Gm frag-padded col count (57 tiles x 16)
#define NT1 19         // phase-1 N-tiles (304 cols)
#define NT4 57         // phase-4 N-tiles (912 cols)

// ---------- dtype detector ----------
__global__ void detect_dtype(const u16* __restrict__ raw, int* __restrict__ flag) {
    __shared__ int cnt;
    if (threadIdx.x == 0) cnt = 0;
    __syncthreads();
    if (threadIdx.x < 300 && (raw[threadIdx.x] & 0x8000u)) atomicAdd(&cnt, 1);
    __syncthreads();
    if (threadIdx.x == 0) *flag = (cnt < 8) ? 1 : 0;   // 1 = bf16, 0 = fp32
}

// ---------- prepack kernels ----------
__global__ void pack_w(const void* __restrict__ src, u16* __restrict__ dst,
                       int dstRowsPad, int nsrcRows, int srcld, int colOff, int igo,
                       const int* __restrict__ flag) {
    int i = blockIdx.x * 256 + threadIdx.x;
    if (i >= dstRowsPad * KPAD) return;
    int isbf = *flag;
    int r = i / KPAD, c = i % KPAD;
    u16 v = 0;
    if (r < nsrcRows && c < HH) {
        int sr = igo ? (r < HH ? r : r + HH) : r;
        v = f2bf(rdf(src, (size_t)sr * srcld + colOff + c, isbf));
    }
    dst[i] = v;
}

// W_m packed to MFMA B-fragment layout: Wf[T][ks][lane] = bf16x8 of
// W_m[j = T*16 + (lane&15)][k = 32*ks + 8*(lane>>4) + e], e<8; zeros outside 300x300.
__global__ void pack_wf(const void* __restrict__ Wm, uint4* __restrict__ dst,
                        const int* __restrict__ flag) {
    int i = blockIdx.x * 256 + threadIdx.x;
    if (i >= NT1 * 10 * 64) return;
    int isbf = *flag;
    int lane = i & 63, ks = (i >> 6) % 10, T = i / 640;
    int j = T * 16 + (lane & 15);
    int k0 = 32 * ks + 8 * (lane >> 4);
    unsigned int d[4];
    #pragma unroll
    for (int q = 0; q < 4; ++q) {
        int ka = k0 + 2 * q, kb = k0 + 2 * q + 1;
        unsigned int lo = (j < 300 && ka < 300) ? f2bf(rdf(Wm, (size_t)j * HH + ka, isbf)) : 0;
        unsigned int hi = (j < 300 && kb < 300) ? f2bf(rdf(Wm, (size_t)j * HH + kb, isbf)) : 0;
        d[q] = lo | (hi << 16);
    }
    uint4 v; v.x = d[0]; v.y = d[1]; v.z = d[2]; v.w = d[3];
    dst[i] = v;
}

__global__ void pack_bias(const void* bip, const void* bhp, const void* bih_, const void* bhh_,
                          const void* bim, const void* bhm,
                          float* bp, float* bh, float* bm, const int* __restrict__ flag) {
    int i = blockIdx.x * 256 + threadIdx.x;
    if (i >= 3 * N3H) return;
    int isbf = *flag;
    int which = i / N3H, r = i % N3H;
    int sr = (r < HH) ? r : r + HH;
    if (which == 0)      bp[r] = rdf(bip, sr, isbf) + rdf(bhp, sr, isbf);
    else if (which == 1) bh[r] = rdf(bih_, sr, isbf) + rdf(bhh_, sr, isbf);
    else                 bm[r] = rdf(bim, sr, isbf) + rdf(bhm, sr, isbf);
}

__global__ void gather_embed(const int* __restrict__ idx, const void* __restrict__ embed,
                             u16* __restrict__ X, const int* __restrict__ flag) {
    int i = blockIdx.x * 256 + threadIdx.x;   // 8192*320 exact
    int isbf = *flag;
    int r = i / KPAD, c = i % KPAD;
    X[i] = (c < HH) ? f2bf(rdf(embed, (size_t)idx[r] * HH + c, isbf)) : (u16)0;
}

__global__ void zero_out(u16* out) { out[threadIdx.x] = 0; }

// ---------- MFMA GEMM:  C[M x N] = A[M x 320] * B[Npad x 320]^T (+bias) ----------
// frag=0: bf16 row-major out, cols [N, ldc) zero-padded.
// frag=1: write MFMA B-fragment layout for the scan's phase-4.
__global__ __launch_bounds__(256) void gemm_bt(
    const u16* __restrict__ A, const u16* __restrict__ B,
    u16* __restrict__ Cb, const float* __restrict__ bias, int N, int ldc, int frag)
{
    __shared__ __align__(16) u16 At[128 * 32];
    __shared__ __align__(16) u16 Bt[128 * 32];
    const int tid = threadIdx.x;
    const int m0 = blockIdx.x * 128;
    const int n0 = blockIdx.y * 128;
    const int lane = tid & 63;
    const int wave = tid >> 6;
    const int rm = (wave & 1) * 64;
    const int rn = (wave >> 1) * 64;
    const int qr = lane >> 4;
    const int lr = lane & 15;

    f32x4 acc[4][4] = {};

    const int c0 = tid, c1 = tid + 256;
    const int r0 = c0 >> 2, o0 = (c0 & 3) * 8;
    const int r1 = c1 >> 2, o1 = (c1 & 3) * 8;

    for (int k0 = 0; k0 < KPAD; k0 += 32) {
        uint4 a0v = *(const uint4*)(A + (size_t)(m0 + r0) * KPAD + k0 + o0);
        uint4 a1v = *(const uint4*)(A + (size_t)(m0 + r1) * KPAD + k0 + o1);
        uint4 b0v = *(const uint4*)(B + (size_t)(n0 + r0) * KPAD + k0 + o0);
        uint4 b1v = *(const uint4*)(B + (size_t)(n0 + r1) * KPAD + k0 + o1);
        __syncthreads();
        *(uint4*)(At + c0 * 8) = a0v;
        *(uint4*)(At + c1 * 8) = a1v;
        *(uint4*)(Bt + c0 * 8) = b0v;
        *(uint4*)(Bt + c1 * 8) = b1v;
        __syncthreads();
        bf16x8 af[4], bfr[4];
        #pragma unroll
        for (int i = 0; i < 4; ++i) {
            af[i]  = *(const bf16x8*)(At + (rm + i * 16 + lr) * 32 + qr * 8);
            bfr[i] = *(const bf16x8*)(Bt + (rn + i * 16 + lr) * 32 + qr * 8);
        }
        #pragma unroll
        for (int mi = 0; mi < 4; ++mi)
            #pragma unroll
            for (int ni = 0; ni < 4; ++ni)
                acc[mi][ni] = __builtin_amdgcn_mfma_f32_16x16x32_bf16(
                    af[mi], bfr[ni], acc[mi][ni], 0, 0, 0);
    }
    // C/D layout: col(n)=lane&15, row(m)=quad*4+reg   [verified m89/m91]
    #pragma unroll
    for (int mi = 0; mi < 4; ++mi) {
        #pragma unroll
        for (int ni = 0; ni < 4; ++ni) {
            int n = n0 + rn + ni * 16 + lr;
            int mb = m0 + rm + mi * 16 + qr * 4;
            if (!frag) {
                if (n >= ldc) continue;
                if (n < N) {
                    float bv = bias ? bias[n] : 0.f;
                    #pragma unroll
                    for (int r = 0; r < 4; ++r)
                        Cb[(size_t)(mb + r) * ldc + n] = f2bf(acc[mi][ni][r] + bv);
                } else {
                    #pragma unroll
                    for (int r = 0; r < 4; ++r)
                        Cb[(size_t)(mb + r) * ldc + n] = 0;
                }
            } else {
                if (n >= GLD) continue;
                int bb = mb >> 6, p0 = mb & 63;
                size_t base = ((((size_t)bb * NT4 + (n >> 4)) * 2 + (p0 >> 5)) * 64
                               + ((p0 >> 3) & 3) * 16 + (n & 15)) * 8 + (p0 & 7);
                u16 wv[4];
                if (n < N) {
                    float bv = bias ? bias[n] : 0.f;
                    #pragma unroll
                    for (int r = 0; r < 4; ++r) wv[r] = f2bf(acc[mi][ni][r] + bv);
                } else {
                    #pragma unroll
                    for (int r = 0; r < 4; ++r) wv[r] = 0;
                }
                uint2 st;
                st.x = (unsigned int)wv[0] | ((unsigned int)wv[1] << 16);
                st.y = (unsigned int)wv[2] | ((unsigned int)wv[3] << 16);
                *(uint2*)(Cb + base) = st;
            }
        }
    }
}

// ---------- LSTM0 activation ----------
__global__ void lstm_act(const u16* __restrict__ gates, u16* __restrict__ hout) {
    int idx = blockIdx.x * 256 + threadIdx.x;   // 8192*320 exact
    int r = idx / KPAD, c = idx % KPAD;
    float h = 0.f;
    if (c < HH) {
        const u16* g = gates + (size_t)r * N3H;
        float gi = bf2f(g[c]);
        float gg = bf2f(g[c + HH]);
        float go = bf2f(g[c + 2 * HH]);
        float cc = fast_sigmoid(gi) * fast_tanh(gg);
        h = fast_sigmoid(go) * fast_tanh(cc);
    }
    hout[idx] = f2bf(h);
}

// ---------- sequential scan: 512 thr/WG, MFMA matvecs, register-resident operands ----------
// v5: Wf tiles (2/wave) and Gm frags (7-8 tiles/wave) pinned in VGPRs before the
// k-loop (128 blocks on 256 CUs -> 1 block/CU regardless; launch_bounds(512,1)
// unlocks 256 VGPRs). 3 leftover W tiles in LDS (waves 0-2). Per-wave private
// softmax slot removes one barrier. Phase 2 on contiguous 40-wide h-slices
// (float4 LDS reads, 8-way broadcast).
__global__ __launch_bounds__(512, 1) void scan_kernel(
    const u16* __restrict__ sproj,            // [8192][320] bf16, pads 0
    const u16* __restrict__ tproj,            // [8192][320] bf16, pads 0
    const uint4* __restrict__ Gmf,            // [128][57][2][64] frags
    const u16* __restrict__ hp,               // [8192][900] bf16 (bias folded)
    const uint4* __restrict__ Wf,             // [19][10][64] frags
    const void* __restrict__ w_e,             // [300] input dtype
    const int* __restrict__ premise_len,
    const int* __restrict__ hypothesis_len,
    float* __restrict__ hfin,                 // [128][320] fp32
    const int* __restrict__ flag)
{
    __shared__ __align__(16) uint4 wlds[3 * 10 * 64];   // W tiles 16-18 (30720 B)
    __shared__ __align__(16) float we2[320];            // 2*w_e (pads 0)
    __shared__ __align__(16) float tpm[320];            // 2*(t_k + m_proj); [304,320) stay 0
    __shared__ __align__(16) unsigned int hmhi[160];    // hm hi bf16 pairs (pads 0)
    __shared__ __align__(16) unsigned int hmlo[160];    // hm lo residual pairs
    __shared__ __align__(16) u16 aw[8][128];            // per-wave alpha hi[0:64] lo[64:128]
    __shared__ float evals[64];
    __shared__ __align__(16) float gates[912];

    const int b = blockIdx.x, t = threadIdx.x;
    const int lane = t & 63, w = t >> 6;
    const int lr = lane & 15, qr = lane >> 4;
    const int plen = premise_len[b], hlen = hypothesis_len[b];
    const int isbf = *flag;

    // ---- stage leftover W tiles (16-18) into LDS ----
    for (int i = t; i < 3 * 10 * 64; i += 512) wlds[i] = Wf[16 * 640 + i];
    if (t < 320) { we2[t] = (t < 300) ? 2.f * rdf(w_e, t, isbf) : 0.f; tpm[t] = 0.f; }
    if (t < 160) { hmhi[t] = 0; hmlo[t] = 0; }

    // ---- pin W tiles {w, w+8} in registers (iteration-invariant) ----
    uint4 wreg[20];
    #pragma unroll
    for (int ks = 0; ks < 10; ++ks) wreg[ks]      = Wf[(size_t)w * 640 + ks * 64 + lane];
    #pragma unroll
    for (int ks = 0; ks < 10; ++ks) wreg[10 + ks] = Wf[(size_t)(w + 8) * 640 + ks * 64 + lane];

    // ---- pin Gm frags (tiles T = w + 8i) in registers ----
    const int nt4 = (w == 0) ? 8 : 7;
    uint4 greg[16];
    {
        const uint4* gsrc = Gmf + (size_t)b * (NT4 * 2 * 64);
        #pragma unroll
        for (int i = 0; i < 8; ++i) {
            if (i < nt4) {
                int T = w + 8 * i;
                greg[2 * i]     = gsrc[(T * 2 + 0) * 64 + lane];
                greg[2 * i + 1] = gsrc[(T * 2 + 1) * 64 + lane];
            }
        }
    }

    // ---- pin s_proj slice: p = t>>3, contiguous h-slice [40s, 40s+40) ----
    const int p2p = t >> 3, p2s = t & 7;
    unsigned int spd[20];
    {
        const uint4* sprow = (const uint4*)(sproj + (size_t)(b * PP + p2p) * KPAD + 40 * p2s);
        #pragma unroll
        for (int q = 0; q < 5; ++q) {
            uint4 v = sprow[q];
            spd[4 * q] = v.x; spd[4 * q + 1] = v.y; spd[4 * q + 2] = v.z; spd[4 * q + 3] = v.w;
        }
    }
    __syncthreads();   // we2 visible

    float wsum = 0.f;
    #pragma unroll
    for (int q = 0; q < 10; ++q) {
        float4 v = ((const float4*)we2)[10 * p2s + q];
        wsum += 0.5f * ((v.x + v.y) + (v.z + v.w));
    }

    for (int k = 0; k < hlen; ++k) {
        const u16* tprow = tproj + (size_t)(b * KK + k) * KPAD;
        const u16* hprow = hp + (size_t)(b * KK + k) * 900;

        // iter-start prefetches (consumed later in the iteration)
        u16 hpv[8];
        #pragma unroll
        for (int i = 0; i < 8; ++i) {
            hpv[i] = 0;
            if (i < nt4 && lane < 16) hpv[i] = hprow[(w + 8 * i) * 16 + lane];
        }
        u16 tk0 = 0, tk1 = 0, tk2 = 0;
        if (lane < 16) {
            tk0 = tprow[w * 16 + lane];
            tk1 = tprow[(w + 8) * 16 + lane];
            if (w < 3) tk2 = tprow[(w + 16) * 16 + lane];
        }

        // ---- phase 1: tpm = 2*(t_k + hm . W_m^T) via MFMA, W register-resident ----
        bf16x8 a1[10];
        {
            const unsigned int* abase = (lr == 1) ? hmlo : hmhi;
            uint4 z; z.x = 0; z.y = 0; z.z = 0; z.w = 0;
            #pragma unroll
            for (int ks = 0; ks < 10; ++ks) {
                uint4 u = *(const uint4*)(abase + 16 * ks + 4 * qr);
                a1[ks] = as_bf8((lr < 2) ? u : z);
            }
        }
        {   // tile w (even/odd split accumulators for ILP)
            f32x4 ac0 = {}, ac1 = {};
            #pragma unroll
            for (int ks = 0; ks < 10; ks += 2) {
                ac0 = __builtin_amdgcn_mfma_f32_16x16x32_bf16(a1[ks], as_bf8(wreg[ks]), ac0, 0, 0, 0);
                ac1 = __builtin_amdgcn_mfma_f32_16x16x32_bf16(a1[ks + 1], as_bf8(wreg[ks + 1]), ac1, 0, 0, 0);
            }
            if (lane < 16) tpm[w * 16 + lane] = 2.f * (bf2f(tk0) + ((ac0[0] + ac0[1]) + (ac1[0] + ac1[1])));
        }
        {   // tile w+8
            f32x4 ac0 = {}, ac1 = {};
            #pragma unroll
            for (int ks = 0; ks < 10; ks += 2) {
                ac0 = __builtin_amdgcn_mfma_f32_16x16x32_bf16(a1[ks], as_bf8(wreg[10 + ks]), ac0, 0, 0, 0);
                ac1 = __builtin_amdgcn_mfma_f32_16x16x32_bf16(a1[ks + 1], as_bf8(wreg[11 + ks]), ac1, 0, 0, 0);
            }
            if (lane < 16) tpm[(w + 8) * 16 + lane] = 2.f * (bf2f(tk1) + ((ac0[0] + ac0[1]) + (ac1[0] + ac1[1])));
        }
        if (w < 3) {   // tile w+16 from LDS
            f32x4 ac0 = {}, ac1 = {};
            #pragma unroll
            for (int ks = 0; ks < 10; ks += 2) {
                bf16x8 b0 = as_bf8(wlds[w * 640 + ks * 64 + lane]);
                bf16x8 b1 = as_bf8(wlds[w * 640 + (ks + 1) * 64 + lane]);
                ac0 = __builtin_amdgcn_mfma_f32_16x16x32_bf16(a1[ks], b0, ac0, 0, 0, 0);
                ac1 = __builtin_amdgcn_mfma_f32_16x16x32_bf16(a1[ks + 1], b1, ac1, 0, 0, 0);
            }
            if (lane < 16) tpm[(w + 16) * 16 + lane] = 2.f * (bf2f(tk2) + ((ac0[0] + ac0[1]) + (ac1[0] + ac1[1])));
        }
        __syncthreads();   // A: tpm final

        // ---- phase 2 (all 512): e[p] = wsum - sum we2*rcp(e^{2x}+1); slice [40s,40s+40) ----
        {
            float accn = 0.f;
            bool act = p2p < plen;
            if (act) {
                #pragma unroll
                for (int q = 0; q < 10; ++q) {
                    float4 tv = ((const float4*)tpm)[10 * p2s + q];
                    float4 wv = ((const float4*)we2)[10 * p2s + q];
                    float x0 = fmaf(2.f, bf2f_lo(spd[2 * q]), tv.x);
                    float x1 = fmaf(2.f, bf2f_hi(spd[2 * q]), tv.y);
                    float x2 = fmaf(2.f, bf2f_lo(spd[2 * q + 1]), tv.z);
                    float x3 = fmaf(2.f, bf2f_hi(spd[2 * q + 1]), tv.w);
                    accn = fmaf(wv.x, __builtin_amdgcn_rcpf(__expf(x0) + 1.f), accn);
                    accn = fmaf(wv.y, __builtin_amdgcn_rcpf(__expf(x1) + 1.f), accn);
                    accn = fmaf(wv.z, __builtin_amdgcn_rcpf(__expf(x2) + 1.f), accn);
                    accn = fmaf(wv.w, __builtin_amdgcn_rcpf(__expf(x3) + 1.f), accn);
                }
            }
            float val = act ? (wsum - accn) : 0.f;
            val += __shfl_down(val, 4);
            val += __shfl_down(val, 2);
            val += __shfl_down(val, 1);
            if (p2s == 0) evals[p2p] = act ? val : -1e30f;
        }
        __syncthreads();   // B: evals ready

        // ---- phase 3 (per-wave, redundant): softmax -> private hi/lo slot, no barrier ----
        {
            float v = evals[lane];
            float mx = v;
            #pragma unroll
            for (int d = 32; d; d >>= 1) mx = fmaxf(mx, __shfl_xor(mx, d));
            float ex = (lane < plen) ? __expf(v - mx) : 0.f;
            float sm = ex;
            #pragma unroll
            for (int d = 32; d; d >>= 1) sm += __shfl_xor(sm, d);
            float al = ex * __builtin_amdgcn_rcpf(sm);
            u16 ah = f2bf(al);
            aw[w][lane] = ah;
            aw[w][64 + lane] = f2bf(al - bf2f(ah));
        }
        // same-wave LDS write->read: ordered via lgkmcnt, no __syncthreads needed

        // ---- phase 4: gates = alpha . Gm via MFMA (Gm register-resident) ----
        bf16x8 a4[2];
        {
            const u16* abase = aw[w] + ((lr == 1) ? 64 : 0);
            uint4 z; z.x = 0; z.y = 0; z.z = 0; z.w = 0;
            #pragma unroll
            for (int ks = 0; ks < 2; ++ks) {
                uint4 u = *(const uint4*)(abase + 32 * ks + 8 * qr);
                a4[ks] = as_bf8((lr < 2) ? u : z);
            }
        }
        #pragma unroll
        for (int i = 0; i < 8; ++i) {
            if (i < nt4) {
                int T = w + 8 * i;
                f32x4 ac0 = {}, ac1 = {};
                ac0 = __builtin_amdgcn_mfma_f32_16x16x32_bf16(a4[0], as_bf8(greg[2 * i]), ac0, 0, 0, 0);
                ac1 = __builtin_amdgcn_mfma_f32_16x16x32_bf16(a4[1], as_bf8(greg[2 * i + 1]), ac1, 0, 0, 0);
                if (lane < 16) gates[T * 16 + lane] = ((ac0[0] + ac0[1]) + (ac1[0] + ac1[1])) + bf2f(hpv[i]);
            }
        }
        __syncthreads();   // C: gates final

        // ---- phase 5 (t<300): h_m = sig(o)*tanh(sig(i)*tanh(g)); pack hi/lo pairs ----
        if (t < 300) {
            float gi = gates[t], gg = gates[300 + t], go = gates[600 + t];
            float cc = fast_sigmoid(gi) * fast_tanh(gg);
            float h = fast_sigmoid(go) * fast_tanh(cc);
            if (k == hlen - 1) hfin[(size_t)b * KPAD + t] = h;
            u16 hh = f2bf(h);
            float res = h - bf2f(hh);
            float hn = __shfl_down(h, 1);     // partner t+1 (same wave, active)
            float rn2 = __shfl_down(res, 1);
            if ((t & 1) == 0) {
                hmhi[t >> 1] = (unsigned int)hh | ((unsigned int)f2bf(hn) << 16);
                hmlo[t >> 1] = (unsigned int)f2bf(res) | ((unsigned int)f2bf(rn2) << 16);
            }
        }
        __syncthreads();   // D: hm ready for next phase 1
    }
}

// ---------- final FC + softmax over 3 classes (dual-dtype in AND out) ----------
__global__ void fc_softmax(const float* __restrict__ hfin, const void* __restrict__ fcw,
                           const void* __restrict__ fcb, void* __restrict__ out,
                           const int* __restrict__ flag) {
    int b = threadIdx.x;     // 128 threads, 1 block
    int isbf = *flag;
    float l[3];
    #pragma unroll
    for (int c = 0; c < 3; ++c) {
        float acc = rdf(fcb, c, isbf);
        const float* hr = hfin + (size_t)b * KPAD;
        for (int h = 0; h < HH; ++h) acc += hr[h] * rdf(fcw, (size_t)c * HH + h, isbf);
        l[c] = acc;
    }
    float mx = fmaxf(l[0], fmaxf(l[1], l[2]));
    float e0 = __expf(l[0] - mx), e1 = __expf(l[1] - mx), e2 = __expf(l[2] - mx);
    float inv = __builtin_amdgcn_rcpf(e0 + e1 + e2);
    if (isbf) {
        u16* o = (u16*)out;
        o[b * 3 + 0] = f2bf(e0 * inv);
        o[b * 3 + 1] = f2bf(e1 * inv);
        o[b * 3 + 2] = f2bf(e2 * inv);
    } else {
        float* o = (float*)out;
        o[b * 3 + 0] = e0 * inv;
        o[b * 3 + 1] = e1 * inv;
        o[b * 3 + 2] = e2 * inv;
    }
}

extern "C" void kernel_launch(void* const* d_in, const int* in_sizes, int n_in,
                              void* d_out, int out_size, void* d_ws, size_t ws_size,
                              hipStream_t stream) {
    const int* premise        = (const int*)d_in[0];
    const int* premise_len    = (const int*)d_in[1];
    const int* hypothesis     = (const int*)d_in[2];
    const int* hypothesis_len = (const int*)d_in[3];
    const void* embed = d_in[4];
    const void* w_e   = d_in[5];
    const void* W_s   = d_in[6];
    const void* W_t   = d_in[7];
    const void* W_m   = d_in[8];
    const void* fc_w  = d_in[9];
    const void* fc_b  = d_in[10];
    const void* Wih_p = d_in[11];
    const void* bih_p = d_in[13];
    const void* bhh_p = d_in[14];
    const void* Wih_h = d_in[15];
    const void* bih_h = d_in[17];
    const void* bhh_h = d_in[18];
    const void* Wih_m = d_in[19];
    const void* bih_m = d_in[21];
    const void* bhh_m = d_in[22];
    (void)in_sizes; (void)n_in; (void)out_size;

    // ---- lifetime-overlapped workspace arena ----
    char* w = (char*)d_ws;
    auto alloc = [&](size_t bytes) -> char* {
        char* r = (char*)(((uintptr_t)w + 255) & ~(uintptr_t)255);
        w = r + bytes;
        return r;
    };
    char* regA = alloc((size_t)MROWS * KPAD * 2);   // Xbuf -> s_proj
    char* regB = alloc((size_t)MROWS * GLD * 2);    // gates_p -> Gm frags (14.94 MB)
    char* regC = alloc((size_t)MROWS * N3H * 2);    // gates_h -> hproj
    char* regD = alloc((size_t)MROWS * KPAD * 2);   // h_s -> t_proj
    char* regE = alloc((size_t)MROWS * KPAD * 2);   // h_t -> h_fin
    u16* Wp_pad  = (u16*)alloc((size_t)1024 * KPAD * 2);
    u16* Wh_pad  = (u16*)alloc((size_t)1024 * KPAD * 2);
    u16* Wa_pad  = (u16*)alloc((size_t)1024 * KPAD * 2);
    u16* Whm_pad = (u16*)alloc((size_t)1024 * KPAD * 2);
    u16* Ws_pad  = (u16*)alloc((size_t)384 * KPAD * 2);
    u16* Wt_pad  = (u16*)alloc((size_t)384 * KPAD * 2);
    uint4* Wf    = (uint4*)alloc((size_t)NT1 * 10 * 64 * 16);
    float* bsum_p = (float*)alloc(N3H * 4);
    float* bsum_h = (float*)alloc(N3H * 4);
    float* bsum_m = (float*)alloc(N3H * 4);
    int* dflag   = (int*)alloc(256);
    size_t needed = (size_t)(w - (char*)d_ws);
    if (needed > ws_size) {
        zero_out<<<1, 384, 0, stream>>>((u16*)d_out);
        return;
    }
    u16* Xbuf   = (u16*)regA;
    u16* s_proj = (u16*)regA;                       // after Xbuf dead
    u16* h_s    = (u16*)regD;
    u16* t_proj = (u16*)regD;                       // after h_s dead
    u16* h_t    = (u16*)regE;
    float* h_fin = (float*)regE;                    // after h_t dead (scan time)

    // dtype detect, then prepack
    detect_dtype<<<1, 320, 0, stream>>>((const u16*)w_e, dflag);
    pack_w<<<1280, 256, 0, stream>>>(Wih_p, Wp_pad, 1024, N3H, HH, 0, 1, dflag);
    pack_w<<<1280, 256, 0, stream>>>(Wih_h, Wh_pad, 1024, N3H, HH, 0, 1, dflag);
    pack_w<<<1280, 256, 0, stream>>>(Wih_m, Wa_pad, 1024, N3H, 600, 0, 1, dflag);
    pack_w<<<1280, 256, 0, stream>>>(Wih_m, Whm_pad, 1024, N3H, 600, HH, 1, dflag);
    pack_w<<<480, 256, 0, stream>>>(W_s, Ws_pad, 384, HH, HH, 0, 0, dflag);
    pack_w<<<480, 256, 0, stream>>>(W_t, Wt_pad, 384, HH, HH, 0, 0, dflag);
    pack_wf<<<48, 256, 0, stream>>>(W_m, Wf, dflag);
    pack_bias<<<11, 256, 0, stream>>>(bih_p, bhh_p, bih_h, bhh_h, bih_m, bhh_m,
                                      bsum_p, bsum_h, bsum_m, dflag);

    // premise: gather -> gates (bias folded) -> h_s
    gather_embed<<<10240, 256, 0, stream>>>(premise, embed, Xbuf, dflag);
    gemm_bt<<<dim3(64, 8), 256, 0, stream>>>(Xbuf, Wp_pad, (u16*)regB, bsum_p, N3H, N3H, 0);
    lstm_act<<<10240, 256, 0, stream>>>((u16*)regB, h_s);
    // hypothesis: reuse Xbuf
    gather_embed<<<10240, 256, 0, stream>>>(hypothesis, embed, Xbuf, dflag);
    gemm_bt<<<dim3(64, 8), 256, 0, stream>>>(Xbuf, Wh_pad, (u16*)regC, bsum_h, N3H, N3H, 0);
    lstm_act<<<10240, 256, 0, stream>>>((u16*)regC, h_t);

    // projections (ordering chosen so region reuse is safe)
    gemm_bt<<<dim3(64, 3), 256, 0, stream>>>(h_s, Ws_pad, s_proj, nullptr, HH, KPAD, 0);   // into A (Xbuf dead)
    gemm_bt<<<dim3(64, 8), 256, 0, stream>>>(h_s, Wa_pad, (u16*)regB, nullptr, N3H, 0, 1); // Gm FRAGS into B
    gemm_bt<<<dim3(64, 3), 256, 0, stream>>>(h_t, Wt_pad, t_proj, nullptr, HH, KPAD, 0);   // into D (h_s dead)
    gemm_bt<<<dim3(64, 8), 256, 0, stream>>>(h_t, Whm_pad, (u16*)regC, bsum_m, N3H, N3H, 0); // hproj into C

    // sequential match-LSTM scan, one WG per batch, 512 threads
    scan_kernel<<<BB, 512, 0, stream>>>(s_proj, t_proj, (const uint4*)regB,
                                        (const u16*)regC, Wf, w_e,
                                        premise_len, hypothesis_len, h_fin, dflag);
    // classifier
    fc_softmax<<<1, 128, 0, stream>>>(h_fin, fc_w, fc_b, d_out, dflag);
}

// Round 5
// 672.002 us; speedup vs baseline: 24.8562x; 1.0250x over previous
//
#include <hip/hip_runtime.h>
#include <stdint.h>

typedef unsigned short u16;
typedef __attribute__((ext_vector_type(8))) __bf16 bf16x8;
typedef __attribute__((ext_vector_type(4))) float f32x4;

// ---------- bf16 helpers (raw-bit, exact bf16 semantics) ----------
__device__ __forceinline__ float bf2f(u16 u) {
    union { unsigned int i; float f; } v; v.i = ((unsigned int)u) << 16; return v.f;
}
__device__ __forceinline__ float bf2f_lo(unsigned int u) {
    union { unsigned int i; float f; } v; v.i = u << 16; return v.f;
}
__device__ __forceinline__ float bf2f_hi(unsigned int u) {
    union { unsigned int i; float f; } v; v.i = u & 0xffff0000u; return v.f;
}
__device__ __forceinline__ u16 f2bf(float f) {
    union { float f; unsigned int i; } v; v.f = f;
    unsigned int x = v.i;
    unsigned int r = (x + 0x7fffu + ((x >> 16) & 1u)) >> 16;
    return (u16)r;
}
__device__ __forceinline__ float rdf(const void* p, size_t i, int isbf) {
    return isbf ? bf2f(((const u16*)p)[i]) : ((const float*)p)[i];
}
__device__ __forceinline__ float fast_sigmoid(float x) {
    return __builtin_amdgcn_rcpf(1.f + __expf(-x));
}
__device__ __forceinline__ float fast_tanh(float x) {
    float u = __expf(x + x);
    return 1.f - 2.f * __builtin_amdgcn_rcpf(u + 1.f);
}
__device__ __forceinline__ bf16x8 as_bf8(uint4 u) {
    union { uint4 a; bf16x8 b; } c; c.a = u; return c.b;
}

// Problem dims
#define BB 128
#define PP 64
#define KK 64
#define HH 300
#define MROWS 8192     // B*P = B*K
#define KPAD 320       // K padded; row stride for s_proj/t_proj/h_fin
#define N3H 900        // i,g,o gates only (f-gate unused: c_prev=0)
#define GLD 912        // Gm frag-padded col count (57 tiles x 16)
#define NT1 19         // phase-1 N-tiles (304 cols)
#define NT4 57         // phase-4 N-tiles (912 cols)

// ---------- dtype detector ----------
__global__ void detect_dtype(const u16* __restrict__ raw, int* __restrict__ flag) {
    __shared__ int cnt;
    if (threadIdx.x == 0) cnt = 0;
    __syncthreads();
    if (threadIdx.x < 300 && (raw[threadIdx.x] & 0x8000u)) atomicAdd(&cnt, 1);
    __syncthreads();
    if (threadIdx.x == 0) *flag = (cnt < 8) ? 1 : 0;   // 1 = bf16, 0 = fp32
}

// ---------- prepack kernels ----------
__global__ void pack_w(const void* __restrict__ src, u16* __restrict__ dst,
                       int dstRowsPad, int nsrcRows, int srcld, int colOff, int igo,
                       const int* __restrict__ flag) {
    int i = blockIdx.x * 256 + threadIdx.x;
    if (i >= dstRowsPad * KPAD) return;
    int isbf = *flag;
    int r = i / KPAD, c = i % KPAD;
    u16 v = 0;
    if (r < nsrcRows && c < HH) {
        int sr = igo ? (r < HH ? r : r + HH) : r;
        v = f2bf(rdf(src, (size_t)sr * srcld + colOff + c, isbf));
    }
    dst[i] = v;
}

// W_m packed to MFMA B-fragment layout: Wf[T][ks][lane] = bf16x8 of
// W_m[j = T*16 + (lane&15)][k = 32*ks + 8*(lane>>4) + e], e<8; zeros outside 300x300.
__global__ void pack_wf(const void* __restrict__ Wm, uint4* __restrict__ dst,
                        const int* __restrict__ flag) {
    int i = blockIdx.x * 256 + threadIdx.x;
    if (i >= NT1 * 10 * 64) return;
    int isbf = *flag;
    int lane = i & 63, ks = (i >> 6) % 10, T = i / 640;
    int j = T * 16 + (lane & 15);
    int k0 = 32 * ks + 8 * (lane >> 4);
    unsigned int d[4];
    #pragma unroll
    for (int q = 0; q < 4; ++q) {
        int ka = k0 + 2 * q, kb = k0 + 2 * q + 1;
        unsigned int lo = (j < 300 && ka < 300) ? f2bf(rdf(Wm, (size_t)j * HH + ka, isbf)) : 0;
        unsigned int hi = (j < 300 && kb < 300) ? f2bf(rdf(Wm, (size_t)j * HH + kb, isbf)) : 0;
        d[q] = lo | (hi << 16);
    }
    uint4 v; v.x = d[0]; v.y = d[1]; v.z = d[2]; v.w = d[3];
    dst[i] = v;
}

__global__ void pack_bias(const void* bip, const void* bhp, const void* bih_, const void* bhh_,
                          const void* bim, const void* bhm,
                          float* bp, float* bh, float* bm, const int* __restrict__ flag) {
    int i = blockIdx.x * 256 + threadIdx.x;
    if (i >= 3 * N3H) return;
    int isbf = *flag;
    int which = i / N3H, r = i % N3H;
    int sr = (r < HH) ? r : r + HH;
    if (which == 0)      bp[r] = rdf(bip, sr, isbf) + rdf(bhp, sr, isbf);
    else if (which == 1) bh[r] = rdf(bih_, sr, isbf) + rdf(bhh_, sr, isbf);
    else                 bm[r] = rdf(bim, sr, isbf) + rdf(bhm, sr, isbf);
}

__global__ void gather_embed(const int* __restrict__ idx, const void* __restrict__ embed,
                             u16* __restrict__ X, const int* __restrict__ flag) {
    int i = blockIdx.x * 256 + threadIdx.x;   // 8192*320 exact
    int isbf = *flag;
    int r = i / KPAD, c = i % KPAD;
    X[i] = (c < HH) ? f2bf(rdf(embed, (size_t)idx[r] * HH + c, isbf)) : (u16)0;
}

__global__ void zero_out(u16* out) { out[threadIdx.x] = 0; }

// ---------- MFMA GEMM:  C[M x N] = A[M x 320] * B[Npad x 320]^T (+bias) ----------
// frag=0: bf16 row-major out, cols [N, ldc) zero-padded.
// frag=1: write MFMA B-fragment layout for the scan's phase-4.
__global__ __launch_bounds__(256) void gemm_bt(
    const u16* __restrict__ A, const u16* __restrict__ B,
    u16* __restrict__ Cb, const float* __restrict__ bias, int N, int ldc, int frag)
{
    __shared__ __align__(16) u16 At[128 * 32];
    __shared__ __align__(16) u16 Bt[128 * 32];
    const int tid = threadIdx.x;
    const int m0 = blockIdx.x * 128;
    const int n0 = blockIdx.y * 128;
    const int lane = tid & 63;
    const int wave = tid >> 6;
    const int rm = (wave & 1) * 64;
    const int rn = (wave >> 1) * 64;
    const int qr = lane >> 4;
    const int lr = lane & 15;

    f32x4 acc[4][4] = {};

    const int c0 = tid, c1 = tid + 256;
    const int r0 = c0 >> 2, o0 = (c0 & 3) * 8;
    const int r1 = c1 >> 2, o1 = (c1 & 3) * 8;

    for (int k0 = 0; k0 < KPAD; k0 += 32) {
        uint4 a0v = *(const uint4*)(A + (size_t)(m0 + r0) * KPAD + k0 + o0);
        uint4 a1v = *(const uint4*)(A + (size_t)(m0 + r1) * KPAD + k0 + o1);
        uint4 b0v = *(const uint4*)(B + (size_t)(n0 + r0) * KPAD + k0 + o0);
        uint4 b1v = *(const uint4*)(B + (size_t)(n0 + r1) * KPAD + k0 + o1);
        __syncthreads();
        *(uint4*)(At + c0 * 8) = a0v;
        *(uint4*)(At + c1 * 8) = a1v;
        *(uint4*)(Bt + c0 * 8) = b0v;
        *(uint4*)(Bt + c1 * 8) = b1v;
        __syncthreads();
        bf16x8 af[4], bfr[4];
        #pragma unroll
        for (int i = 0; i < 4; ++i) {
            af[i]  = *(const bf16x8*)(At + (rm + i * 16 + lr) * 32 + qr * 8);
            bfr[i] = *(const bf16x8*)(Bt + (rn + i * 16 + lr) * 32 + qr * 8);
        }
        #pragma unroll
        for (int mi = 0; mi < 4; ++mi)
            #pragma unroll
            for (int ni = 0; ni < 4; ++ni)
                acc[mi][ni] = __builtin_amdgcn_mfma_f32_16x16x32_bf16(
                    af[mi], bfr[ni], acc[mi][ni], 0, 0, 0);
    }
    // C/D layout: col(n)=lane&15, row(m)=quad*4+reg   [verified m89/m91]
    #pragma unroll
    for (int mi = 0; mi < 4; ++mi) {
        #pragma unroll
        for (int ni = 0; ni < 4; ++ni) {
            int n = n0 + rn + ni * 16 + lr;
            int mb = m0 + rm + mi * 16 + qr * 4;
            if (!frag) {
                if (n >= ldc) continue;
                if (n < N) {
                    float bv = bias ? bias[n] : 0.f;
                    #pragma unroll
                    for (int r = 0; r < 4; ++r)
                        Cb[(size_t)(mb + r) * ldc + n] = f2bf(acc[mi][ni][r] + bv);
                } else {
                    #pragma unroll
                    for (int r = 0; r < 4; ++r)
                        Cb[(size_t)(mb + r) * ldc + n] = 0;
                }
            } else {
                if (n >= GLD) continue;
                int bb = mb >> 6, p0 = mb & 63;
                size_t base = ((((size_t)bb * NT4 + (n >> 4)) * 2 + (p0 >> 5)) * 64
                               + ((p0 >> 3) & 3) * 16 + (n & 15)) * 8 + (p0 & 7);
                u16 wv[4];
                if (n < N) {
                    float bv = bias ? bias[n] : 0.f;
                    #pragma unroll
                    for (int r = 0; r < 4; ++r) wv[r] = f2bf(acc[mi][ni][r] + bv);
                } else {
                    #pragma unroll
                    for (int r = 0; r < 4; ++r) wv[r] = 0;
                }
                uint2 st;
                st.x = (unsigned int)wv[0] | ((unsigned int)wv[1] << 16);
                st.y = (unsigned int)wv[2] | ((unsigned int)wv[3] << 16);
                *(uint2*)(Cb + base) = st;
            }
        }
    }
}

// ---------- LSTM0 activation ----------
__global__ void lstm_act(const u16* __restrict__ gates, u16* __restrict__ hout) {
    int idx = blockIdx.x * 256 + threadIdx.x;   // 8192*320 exact
    int r = idx / KPAD, c = idx % KPAD;
    float h = 0.f;
    if (c < HH) {
        const u16* g = gates + (size_t)r * N3H;
        float gi = bf2f(g[c]);
        float gg = bf2f(g[c + HH]);
        float go = bf2f(g[c + 2 * HH]);
        float cc = fast_sigmoid(gi) * fast_tanh(gg);
        h = fast_sigmoid(go) * fast_tanh(cc);
    }
    hout[idx] = f2bf(h);
}

// ---------- sequential scan: 512 thr/WG, MFMA matvecs ----------
// v6: register plan that actually fits. W_m tiles {w, w+8} pinned in regs (80);
// leftover tiles 16-18 + all Gm frags in LDS (157 KB total). Explicit
// amdgpu_waves_per_eu(2,2): one 8-wave block/CU = 2 waves/SIMD is the hardware
// floor, so license the allocator for 256 regs/wave instead of its 4-wave/128 default.
__global__ __launch_bounds__(512)
__attribute__((amdgpu_waves_per_eu(2, 2)))
void scan_kernel(
    const u16* __restrict__ sproj,            // [8192][320] bf16, pads 0
    const u16* __restrict__ tproj,            // [8192][320] bf16, pads 0
    const uint4* __restrict__ Gmf,            // [128][57][2][64] frags
    const u16* __restrict__ hp,               // [8192][900] bf16 (bias folded)
    const uint4* __restrict__ Wf,             // [19][10][64] frags
    const void* __restrict__ w_e,             // [300] input dtype
    const int* __restrict__ premise_len,
    const int* __restrict__ hypothesis_len,
    float* __restrict__ hfin,                 // [128][320] fp32
    const int* __restrict__ flag)
{
    __shared__ __align__(16) uint4 gml[NT4 * 2 * 64];   // 116736 B (Gm frags)
    __shared__ __align__(16) uint4 wlds[3 * 10 * 64];   // 30720 B (W tiles 16-18)
    __shared__ __align__(16) float we2[320];            // 2*w_e (pads 0)
    __shared__ __align__(16) float tpm[320];            // 2*(t_k + m_proj); [304,320) stay 0
    __shared__ __align__(16) unsigned int hmhi[160];    // hm hi bf16 pairs (pads 0)
    __shared__ __align__(16) unsigned int hmlo[160];    // hm lo residual pairs
    __shared__ __align__(16) u16 aw[8][128];            // per-wave alpha hi[0:64] lo[64:128]
    __shared__ float evals[64];
    __shared__ __align__(16) float gates[912];
    // total LDS = 157248 B < 160 KiB

    const int b = blockIdx.x, t = threadIdx.x;
    const int lane = t & 63, w = t >> 6;
    const int lr = lane & 15, qr = lane >> 4;
    const int plen = premise_len[b], hlen = hypothesis_len[b];
    const int isbf = *flag;

    // ---- stage leftover W tiles (16-18) and Gm frags into LDS ----
    for (int i = t; i < 3 * 10 * 64; i += 512) wlds[i] = Wf[16 * 640 + i];
    {
        const uint4* gsrc = Gmf + (size_t)b * (NT4 * 2 * 64);
        for (int i = t; i < NT4 * 2 * 64; i += 512) gml[i] = gsrc[i];
    }
    if (t < 320) { we2[t] = (t < 300) ? 2.f * rdf(w_e, t, isbf) : 0.f; tpm[t] = 0.f; }
    if (t < 160) { hmhi[t] = 0; hmlo[t] = 0; }

    // ---- pin W tiles {w, w+8} in registers (iteration-invariant, 80 regs) ----
    uint4 wreg[20];
    #pragma unroll
    for (int ks = 0; ks < 10; ++ks) wreg[ks]      = Wf[(size_t)w * 640 + ks * 64 + lane];
    #pragma unroll
    for (int ks = 0; ks < 10; ++ks) wreg[10 + ks] = Wf[(size_t)(w + 8) * 640 + ks * 64 + lane];

    // ---- pin s_proj slice: p = t>>3, contiguous h-slice [40s, 40s+40) (20 regs) ----
    const int p2p = t >> 3, p2s = t & 7;
    unsigned int spd[20];
    {
        const uint4* sprow = (const uint4*)(sproj + (size_t)(b * PP + p2p) * KPAD + 40 * p2s);
        #pragma unroll
        for (int q = 0; q < 5; ++q) {
            uint4 v = sprow[q];
            spd[4 * q] = v.x; spd[4 * q + 1] = v.y; spd[4 * q + 2] = v.z; spd[4 * q + 3] = v.w;
        }
    }
    __syncthreads();   // we2 / gml / wlds visible

    float wsum = 0.f;
    #pragma unroll
    for (int q = 0; q < 10; ++q) {
        float4 v = ((const float4*)we2)[10 * p2s + q];
        wsum += 0.5f * ((v.x + v.y) + (v.z + v.w));
    }

    const int nt4 = (w == 0) ? 8 : 7;   // phase-4 tiles: T = w + 8i (57 total)

    for (int k = 0; k < hlen; ++k) {
        const u16* tprow = tproj + (size_t)(b * KK + k) * KPAD;
        const u16* hprow = hp + (size_t)(b * KK + k) * 900;

        // iter-start prefetches (consumed later in the iteration)
        u16 hpv[8];
        #pragma unroll
        for (int i = 0; i < 8; ++i) {
            hpv[i] = 0;
            if (i < nt4 && lane < 16) hpv[i] = hprow[(w + 8 * i) * 16 + lane];
        }
        u16 tk0 = 0, tk1 = 0, tk2 = 0;
        if (lane < 16) {
            tk0 = tprow[w * 16 + lane];
            tk1 = tprow[(w + 8) * 16 + lane];
            if (w < 3) tk2 = tprow[(w + 16) * 16 + lane];
        }

        // ---- phase 1: tpm = 2*(t_k + hm . W_m^T) via MFMA, W register-resident ----
        bf16x8 a1[10];
        {
            const unsigned int* abase = (lr == 1) ? hmlo : hmhi;
            uint4 z; z.x = 0; z.y = 0; z.z = 0; z.w = 0;
            #pragma unroll
            for (int ks = 0; ks < 10; ++ks) {
                uint4 u = *(const uint4*)(abase + 16 * ks + 4 * qr);
                a1[ks] = as_bf8((lr < 2) ? u : z);
            }
        }
        {   // tiles w and w+8 interleaved: 4 independent MFMA chains
            f32x4 aW0 = {}, aW1 = {}, aV0 = {}, aV1 = {};
            #pragma unroll
            for (int ks = 0; ks < 10; ks += 2) {
                aW0 = __builtin_amdgcn_mfma_f32_16x16x32_bf16(a1[ks], as_bf8(wreg[ks]), aW0, 0, 0, 0);
                aV0 = __builtin_amdgcn_mfma_f32_16x16x32_bf16(a1[ks], as_bf8(wreg[10 + ks]), aV0, 0, 0, 0);
                aW1 = __builtin_amdgcn_mfma_f32_16x16x32_bf16(a1[ks + 1], as_bf8(wreg[ks + 1]), aW1, 0, 0, 0);
                aV1 = __builtin_amdgcn_mfma_f32_16x16x32_bf16(a1[ks + 1], as_bf8(wreg[11 + ks]), aV1, 0, 0, 0);
            }
            if (lane < 16) {
                tpm[w * 16 + lane]       = 2.f * (bf2f(tk0) + ((aW0[0] + aW0[1]) + (aW1[0] + aW1[1])));
                tpm[(w + 8) * 16 + lane] = 2.f * (bf2f(tk1) + ((aV0[0] + aV0[1]) + (aV1[0] + aV1[1])));
            }
        }
        if (w < 3) {   // tile w+16 from LDS
            f32x4 ac0 = {}, ac1 = {};
            #pragma unroll
            for (int ks = 0; ks < 10; ks += 2) {
                bf16x8 b0 = as_bf8(wlds[w * 640 + ks * 64 + lane]);
                bf16x8 b1 = as_bf8(wlds[w * 640 + (ks + 1) * 64 + lane]);
                ac0 = __builtin_amdgcn_mfma_f32_16x16x32_bf16(a1[ks], b0, ac0, 0, 0, 0);
                ac1 = __builtin_amdgcn_mfma_f32_16x16x32_bf16(a1[ks + 1], b1, ac1, 0, 0, 0);
            }
            if (lane < 16) tpm[(w + 16) * 16 + lane] = 2.f * (bf2f(tk2) + ((ac0[0] + ac0[1]) + (ac1[0] + ac1[1])));
        }
        __syncthreads();   // A: tpm final

        // ---- phase 2 (all 512): e[p] = wsum - sum we2*rcp(e^{2x}+1); slice [40s,40s+40) ----
        {
            float accn = 0.f;
            bool act = p2p < plen;
            if (act) {
                #pragma unroll
                for (int q = 0; q < 10; ++q) {
                    float4 tv = ((const float4*)tpm)[10 * p2s + q];
                    float4 wv = ((const float4*)we2)[10 * p2s + q];
                    float x0 = fmaf(2.f, bf2f_lo(spd[2 * q]), tv.x);
                    float x1 = fmaf(2.f, bf2f_hi(spd[2 * q]), tv.y);
                    float x2 = fmaf(2.f, bf2f_lo(spd[2 * q + 1]), tv.z);
                    float x3 = fmaf(2.f, bf2f_hi(spd[2 * q + 1]), tv.w);
                    accn = fmaf(wv.x, __builtin_amdgcn_rcpf(__expf(x0) + 1.f), accn);
                    accn = fmaf(wv.y, __builtin_amdgcn_rcpf(__expf(x1) + 1.f), accn);
                    accn = fmaf(wv.z, __builtin_amdgcn_rcpf(__expf(x2) + 1.f), accn);
                    accn = fmaf(wv.w, __builtin_amdgcn_rcpf(__expf(x3) + 1.f), accn);
                }
            }
            float val = act ? (wsum - accn) : 0.f;
            val += __shfl_down(val, 4);
            val += __shfl_down(val, 2);
            val += __shfl_down(val, 1);
            if (p2s == 0) evals[p2p] = act ? val : -1e30f;
        }
        __syncthreads();   // B: evals ready

        // ---- phase 3 (per-wave, redundant): softmax -> private hi/lo slot, no barrier ----
        {
            float v = evals[lane];
            float mx = v;
            #pragma unroll
            for (int d = 32; d; d >>= 1) mx = fmaxf(mx, __shfl_xor(mx, d));
            float ex = (lane < plen) ? __expf(v - mx) : 0.f;
            float sm = ex;
            #pragma unroll
            for (int d = 32; d; d >>= 1) sm += __shfl_xor(sm, d);
            float al = ex * __builtin_amdgcn_rcpf(sm);
            u16 ah = f2bf(al);
            aw[w][lane] = ah;
            aw[w][64 + lane] = f2bf(al - bf2f(ah));
        }
        // same-wave LDS write->read: ordered via lgkmcnt, no __syncthreads needed

        // ---- phase 4: gates = alpha . Gm via MFMA (Gm frags LDS-resident) ----
        bf16x8 a4[2];
        {
            const u16* abase = aw[w] + ((lr == 1) ? 64 : 0);
            uint4 z; z.x = 0; z.y = 0; z.z = 0; z.w = 0;
            #pragma unroll
            for (int ks = 0; ks < 2; ++ks) {
                uint4 u = *(const uint4*)(abase + 32 * ks + 8 * qr);
                a4[ks] = as_bf8((lr < 2) ? u : z);
            }
        }
        #pragma unroll
        for (int i = 0; i < 8; ++i) {
            if (i < nt4) {
                int T = w + 8 * i;
                f32x4 ac0 = {}, ac1 = {};
                ac0 = __builtin_amdgcn_mfma_f32_16x16x32_bf16(a4[0], as_bf8(gml[(T * 2 + 0) * 64 + lane]), ac0, 0, 0, 0);
                ac1 = __builtin_amdgcn_mfma_f32_16x16x32_bf16(a4[1], as_bf8(gml[(T * 2 + 1) * 64 + lane]), ac1, 0, 0, 0);
                if (lane < 16) gates[T * 16 + lane] = ((ac0[0] + ac0[1]) + (ac1[0] + ac1[1])) + bf2f(hpv[i]);
            }
        }
        __syncthreads();   // C: gates final

        // ---- phase 5 (t<300): h_m = sig(o)*tanh(sig(i)*tanh(g)); pack hi/lo pairs ----
        if (t < 300) {
            float gi = gates[t], gg = gates[300 + t], go = gates[600 + t];
            float cc = fast_sigmoid(gi) * fast_tanh(gg);
            float h = fast_sigmoid(go) * fast_tanh(cc);
            if (k == hlen - 1) hfin[(size_t)b * KPAD + t] = h;
            u16 hh = f2bf(h);
            float res = h - bf2f(hh);
            float hn = __shfl_down(h, 1);     // partner t+1 (same wave, active)
            float rn2 = __shfl_down(res, 1);
            if ((t & 1) == 0) {
                hmhi[t >> 1] = (unsigned int)hh | ((unsigned int)f2bf(hn) << 16);
                hmlo[t >> 1] = (unsigned int)f2bf(res) | ((unsigned int)f2bf(rn2) << 16);
            }
        }
        __syncthreads();   // D: hm ready for next phase 1
    }
}

// ---------- final FC + softmax over 3 classes (dual-dtype in AND out) ----------
__global__ void fc_softmax(const float* __restrict__ hfin, const void* __restrict__ fcw,
                           const void* __restrict__ fcb, void* __restrict__ out,
                           const int* __restrict__ flag) {
    int b = threadIdx.x;     // 128 threads, 1 block
    int isbf = *flag;
    float l[3];
    #pragma unroll
    for (int c = 0; c < 3; ++c) {
        float acc = rdf(fcb, c, isbf);
        const float* hr = hfin + (size_t)b * KPAD;
        for (int h = 0; h < HH; ++h) acc += hr[h] * rdf(fcw, (size_t)c * HH + h, isbf);
        l[c] = acc;
    }
    float mx = fmaxf(l[0], fmaxf(l[1], l[2]));
    float e0 = __expf(l[0] - mx), e1 = __expf(l[1] - mx), e2 = __expf(l[2] - mx);
    float inv = __builtin_amdgcn_rcpf(e0 + e1 + e2);
    if (isbf) {
        u16* o = (u16*)out;
        o[b * 3 + 0] = f2bf(e0 * inv);
        o[b * 3 + 1] = f2bf(e1 * inv);
        o[b * 3 + 2] = f2bf(e2 * inv);
    } else {
        float* o = (float*)out;
        o[b * 3 + 0] = e0 * inv;
        o[b * 3 + 1] = e1 * inv;
        o[b * 3 + 2] = e2 * inv;
    }
}

extern "C" void kernel_launch(void* const* d_in, const int* in_sizes, int n_in,
                              void* d_out, int out_size, void* d_ws, size_t ws_size,
                              hipStream_t stream) {
    const int* premise        = (const int*)d_in[0];
    const int* premise_len    = (const int*)d_in[1];
    const int* hypothesis     = (const int*)d_in[2];
    const int* hypothesis_len = (const int*)d_in[3];
    const void* embed = d_in[4];
    const void* w_e   = d_in[5];
    const void* W_s   = d_in[6];
    const void* W_t   = d_in[7];
    const void* W_m   = d_in[8];
    const void* fc_w  = d_in[9];
    const void* fc_b  = d_in[10];
    const void* Wih_p = d_in[11];
    const void* bih_p = d_in[13];
    const void* bhh_p = d_in[14];
    const void* Wih_h = d_in[15];
    const void* bih_h = d_in[17];
    const void* bhh_h = d_in[18];
    const void* Wih_m = d_in[19];
    const void* bih_m = d_in[21];
    const void* bhh_m = d_in[22];
    (void)in_sizes; (void)n_in; (void)out_size;

    // ---- lifetime-overlapped workspace arena ----
    char* w = (char*)d_ws;
    auto alloc = [&](size_t bytes) -> char* {
        char* r = (char*)(((uintptr_t)w + 255) & ~(uintptr_t)255);
        w = r + bytes;
        return r;
    };
    char* regA = alloc((size_t)MROWS * KPAD * 2);   // Xbuf -> s_proj
    char* regB = alloc((size_t)MROWS * GLD * 2);    // gates_p -> Gm frags (14.94 MB)
    char* regC = alloc((size_t)MROWS * N3H * 2);    // gates_h -> hproj
    char* regD = alloc((size_t)MROWS * KPAD * 2);   // h_s -> t_proj
    char* regE = alloc((size_t)MROWS * KPAD * 2);   // h_t -> h_fin
    u16* Wp_pad  = (u16*)alloc((size_t)1024 * KPAD * 2);
    u16* Wh_pad  = (u16*)alloc((size_t)1024 * KPAD * 2);
    u16* Wa_pad  = (u16*)alloc((size_t)1024 * KPAD * 2);
    u16* Whm_pad = (u16*)alloc((size_t)1024 * KPAD * 2);
    u16* Ws_pad  = (u16*)alloc((size_t)384 * KPAD * 2);
    u16* Wt_pad  = (u16*)alloc((size_t)384 * KPAD * 2);
    uint4* Wf    = (uint4*)alloc((size_t)NT1 * 10 * 64 * 16);
    float* bsum_p = (float*)alloc(N3H * 4);
    float* bsum_h = (float*)alloc(N3H * 4);
    float* bsum_m = (float*)alloc(N3H * 4);
    int* dflag   = (int*)alloc(256);
    size_t needed = (size_t)(w - (char*)d_ws);
    if (needed > ws_size) {
        zero_out<<<1, 384, 0, stream>>>((u16*)d_out);
        return;
    }
    u16* Xbuf   = (u16*)regA;
    u16* s_proj = (u16*)regA;                       // after Xbuf dead
    u16* h_s    = (u16*)regD;
    u16* t_proj = (u16*)regD;                       // after h_s dead
    u16* h_t    = (u16*)regE;
    float* h_fin = (float*)regE;                    // after h_t dead (scan time)

    // dtype detect, then prepack
    detect_dtype<<<1, 320, 0, stream>>>((const u16*)w_e, dflag);
    pack_w<<<1280, 256, 0, stream>>>(Wih_p, Wp_pad, 1024, N3H, HH, 0, 1, dflag);
    pack_w<<<1280, 256, 0, stream>>>(Wih_h, Wh_pad, 1024, N3H, HH, 0, 1, dflag);
    pack_w<<<1280, 256, 0, stream>>>(Wih_m, Wa_pad, 1024, N3H, 600, 0, 1, dflag);
    pack_w<<<1280, 256, 0, stream>>>(Wih_m, Whm_pad, 1024, N3H, 600, HH, 1, dflag);
    pack_w<<<480, 256, 0, stream>>>(W_s, Ws_pad, 384, HH, HH, 0, 0, dflag);
    pack_w<<<480, 256, 0, stream>>>(W_t, Wt_pad, 384, HH, HH, 0, 0, dflag);
    pack_wf<<<48, 256, 0, stream>>>(W_m, Wf, dflag);
    pack_bias<<<11, 256, 0, stream>>>(bih_p, bhh_p, bih_h, bhh_h, bih_m, bhh_m,
                                      bsum_p, bsum_h, bsum_m, dflag);

    // premise: gather -> gates (bias folded) -> h_s
    gather_embed<<<10240, 256, 0, stream>>>(premise, embed, Xbuf, dflag);
    gemm_bt<<<dim3(64, 8), 256, 0, stream>>>(Xbuf, Wp_pad, (u16*)regB, bsum_p, N3H, N3H, 0);
    lstm_act<<<10240, 256, 0, stream>>>((u16*)regB, h_s);
    // hypothesis: reuse Xbuf
    gather_embed<<<10240, 256, 0, stream>>>(hypothesis, embed, Xbuf, dflag);
    gemm_bt<<<dim3(64, 8), 256, 0, stream>>>(Xbuf, Wh_pad, (u16*)regC, bsum_h, N3H, N3H, 0);
    lstm_act<<<10240, 256, 0, stream>>>((u16*)regC, h_t);

    // projections (ordering chosen so region reuse is safe)
    gemm_bt<<<dim3(64, 3), 256, 0, stream>>>(h_s, Ws_pad, s_proj, nullptr, HH, KPAD, 0);   // into A (Xbuf dead)
    gemm_bt<<<dim3(64, 8), 256, 0, stream>>>(h_s, Wa_pad, (u16*)regB, nullptr, N3H, 0, 1); // Gm FRAGS into B
    gemm_bt<<<dim3(64, 3), 256, 0, stream>>>(h_t, Wt_pad, t_proj, nullptr, HH, KPAD, 0);   // into D (h_s dead)
    gemm_bt<<<dim3(64, 8), 256, 0, stream>>>(h_t, Whm_pad, (u16*)regC, bsum_m, N3H, N3H, 0); // hproj into C

    // sequential match-LSTM scan, one WG per batch, 512 threads
    scan_kernel<<<BB, 512, 0, stream>>>(s_proj, t_proj, (const uint4*)regB,
                                        (const u16*)regC, Wf, w_e,
                                        premise_len, hypothesis_len, h_fin, dflag);
    // classifier
    fc_softmax<<<1, 128, 0, stream>>>(h_fin, fc_w, fc_b, d_out, dflag);
}

// Round 6
// 642.344 us; speedup vs baseline: 26.0039x; 1.0462x over previous
//
#include <hip/hip_runtime.h>
#include <stdint.h>

typedef unsigned short u16;
typedef __attribute__((ext_vector_type(8))) __bf16 bf16x8;
typedef __attribute__((ext_vector_type(4))) float f32x4;

// ---------- bf16 helpers (raw-bit, exact bf16 semantics) ----------
__device__ __forceinline__ float bf2f(u16 u) {
    union { unsigned int i; float f; } v; v.i = ((unsigned int)u) << 16; return v.f;
}
__device__ __forceinline__ float bf2f_lo(unsigned int u) {
    union { unsigned int i; float f; } v; v.i = u << 16; return v.f;
}
__device__ __forceinline__ float bf2f_hi(unsigned int u) {
    union { unsigned int i; float f; } v; v.i = u & 0xffff0000u; return v.f;
}
__device__ __forceinline__ u16 f2bf(float f) {
    union { float f; unsigned int i; } v; v.f = f;
    unsigned int x = v.i;
    unsigned int r = (x + 0x7fffu + ((x >> 16) & 1u)) >> 16;
    return (u16)r;
}
__device__ __forceinline__ float rdf(const void* p, size_t i, int isbf) {
    return isbf ? bf2f(((const u16*)p)[i]) : ((const float*)p)[i];
}
__device__ __forceinline__ float fast_sigmoid(float x) {
    return __builtin_amdgcn_rcpf(1.f + __expf(-x));
}
__device__ __forceinline__ float fast_tanh(float x) {
    float u = __expf(x + x);
    return 1.f - 2.f * __builtin_amdgcn_rcpf(u + 1.f);
}
__device__ __forceinline__ bf16x8 as_bf8(uint4 u) {
    union { uint4 a; bf16x8 b; } c; c.a = u; return c.b;
}

// Problem dims
#define BB 128
#define PP 64
#define KK 64
#define HH 300
#define MROWS 8192     // B*P = B*K
#define KPAD 320       // K padded; row stride for s_proj/t_proj/h_fin
#define N3H 900        // i,g,o gates only (f-gate unused: c_prev=0)
#define GLD 912        // Gm frag-padded col count (57 tiles x 16)
#define NT1 19         // phase-1 N-tiles (304 cols)
#define NT4 57         // phase-4 N-tiles (912 cols)
#define NW 16          // scan waves per block

// ---------- dtype detector ----------
__global__ void detect_dtype(const u16* __restrict__ raw, int* __restrict__ flag) {
    __shared__ int cnt;
    if (threadIdx.x == 0) cnt = 0;
    __syncthreads();
    if (threadIdx.x < 300 && (raw[threadIdx.x] & 0x8000u)) atomicAdd(&cnt, 1);
    __syncthreads();
    if (threadIdx.x == 0) *flag = (cnt < 8) ? 1 : 0;   // 1 = bf16, 0 = fp32
}

// ---------- prepack kernels ----------
__global__ void pack_w(const void* __restrict__ src, u16* __restrict__ dst,
                       int dstRowsPad, int nsrcRows, int srcld, int colOff, int igo,
                       const int* __restrict__ flag) {
    int i = blockIdx.x * 256 + threadIdx.x;
    if (i >= dstRowsPad * KPAD) return;
    int isbf = *flag;
    int r = i / KPAD, c = i % KPAD;
    u16 v = 0;
    if (r < nsrcRows && c < HH) {
        int sr = igo ? (r < HH ? r : r + HH) : r;
        v = f2bf(rdf(src, (size_t)sr * srcld + colOff + c, isbf));
    }
    dst[i] = v;
}

// W_m packed to MFMA B-fragment layout: Wf[T][ks][lane] = bf16x8 of
// W_m[j = T*16 + (lane&15)][k = 32*ks + 8*(lane>>4) + e], e<8; zeros outside 300x300.
__global__ void pack_wf(const void* __restrict__ Wm, uint4* __restrict__ dst,
                        const int* __restrict__ flag) {
    int i = blockIdx.x * 256 + threadIdx.x;
    if (i >= NT1 * 10 * 64) return;
    int isbf = *flag;
    int lane = i & 63, ks = (i >> 6) % 10, T = i / 640;
    int j = T * 16 + (lane & 15);
    int k0 = 32 * ks + 8 * (lane >> 4);
    unsigned int d[4];
    #pragma unroll
    for (int q = 0; q < 4; ++q) {
        int ka = k0 + 2 * q, kb = k0 + 2 * q + 1;
        unsigned int lo = (j < 300 && ka < 300) ? f2bf(rdf(Wm, (size_t)j * HH + ka, isbf)) : 0;
        unsigned int hi = (j < 300 && kb < 300) ? f2bf(rdf(Wm, (size_t)j * HH + kb, isbf)) : 0;
        d[q] = lo | (hi << 16);
    }
    uint4 v; v.x = d[0]; v.y = d[1]; v.z = d[2]; v.w = d[3];
    dst[i] = v;
}

__global__ void pack_bias(const void* bip, const void* bhp, const void* bih_, const void* bhh_,
                          const void* bim, const void* bhm,
                          float* bp, float* bh, float* bm, const int* __restrict__ flag) {
    int i = blockIdx.x * 256 + threadIdx.x;
    if (i >= 3 * N3H) return;
    int isbf = *flag;
    int which = i / N3H, r = i % N3H;
    int sr = (r < HH) ? r : r + HH;
    if (which == 0)      bp[r] = rdf(bip, sr, isbf) + rdf(bhp, sr, isbf);
    else if (which == 1) bh[r] = rdf(bih_, sr, isbf) + rdf(bhh_, sr, isbf);
    else                 bm[r] = rdf(bim, sr, isbf) + rdf(bhm, sr, isbf);
}

// 2*w_e as float[320] (pads 0) for the scan's SGPR path
__global__ void pack_we(const void* __restrict__ we, float* __restrict__ dst,
                        const int* __restrict__ flag) {
    int i = threadIdx.x;   // 320
    dst[i] = (i < 300) ? 2.f * rdf(we, i, *flag) : 0.f;
}

__global__ void gather_embed(const int* __restrict__ idx, const void* __restrict__ embed,
                             u16* __restrict__ X, const int* __restrict__ flag) {
    int i = blockIdx.x * 256 + threadIdx.x;   // 8192*320 exact
    int isbf = *flag;
    int r = i / KPAD, c = i % KPAD;
    X[i] = (c < HH) ? f2bf(rdf(embed, (size_t)idx[r] * HH + c, isbf)) : (u16)0;
}

__global__ void zero_out(u16* out) { out[threadIdx.x] = 0; }

// ---------- MFMA GEMM:  C[M x N] = A[M x 320] * B[Npad x 320]^T (+bias) ----------
// frag=0: bf16 row-major out, cols [N, ldc) zero-padded.
// frag=1: write MFMA B-fragment layout for the scan's phase-4.
__global__ __launch_bounds__(256) void gemm_bt(
    const u16* __restrict__ A, const u16* __restrict__ B,
    u16* __restrict__ Cb, const float* __restrict__ bias, int N, int ldc, int frag)
{
    __shared__ __align__(16) u16 At[128 * 32];
    __shared__ __align__(16) u16 Bt[128 * 32];
    const int tid = threadIdx.x;
    const int m0 = blockIdx.x * 128;
    const int n0 = blockIdx.y * 128;
    const int lane = tid & 63;
    const int wave = tid >> 6;
    const int rm = (wave & 1) * 64;
    const int rn = (wave >> 1) * 64;
    const int qr = lane >> 4;
    const int lr = lane & 15;

    f32x4 acc[4][4] = {};

    const int c0 = tid, c1 = tid + 256;
    const int r0 = c0 >> 2, o0 = (c0 & 3) * 8;
    const int r1 = c1 >> 2, o1 = (c1 & 3) * 8;

    for (int k0 = 0; k0 < KPAD; k0 += 32) {
        uint4 a0v = *(const uint4*)(A + (size_t)(m0 + r0) * KPAD + k0 + o0);
        uint4 a1v = *(const uint4*)(A + (size_t)(m0 + r1) * KPAD + k0 + o1);
        uint4 b0v = *(const uint4*)(B + (size_t)(n0 + r0) * KPAD + k0 + o0);
        uint4 b1v = *(const uint4*)(B + (size_t)(n0 + r1) * KPAD + k0 + o1);
        __syncthreads();
        *(uint4*)(At + c0 * 8) = a0v;
        *(uint4*)(At + c1 * 8) = a1v;
        *(uint4*)(Bt + c0 * 8) = b0v;
        *(uint4*)(Bt + c1 * 8) = b1v;
        __syncthreads();
        bf16x8 af[4], bfr[4];
        #pragma unroll
        for (int i = 0; i < 4; ++i) {
            af[i]  = *(const bf16x8*)(At + (rm + i * 16 + lr) * 32 + qr * 8);
            bfr[i] = *(const bf16x8*)(Bt + (rn + i * 16 + lr) * 32 + qr * 8);
        }
        #pragma unroll
        for (int mi = 0; mi < 4; ++mi)
            #pragma unroll
            for (int ni = 0; ni < 4; ++ni)
                acc[mi][ni] = __builtin_amdgcn_mfma_f32_16x16x32_bf16(
                    af[mi], bfr[ni], acc[mi][ni], 0, 0, 0);
    }
    // C/D layout: col(n)=lane&15, row(m)=quad*4+reg   [verified m89/m91]
    #pragma unroll
    for (int mi = 0; mi < 4; ++mi) {
        #pragma unroll
        for (int ni = 0; ni < 4; ++ni) {
            int n = n0 + rn + ni * 16 + lr;
            int mb = m0 + rm + mi * 16 + qr * 4;
            if (!frag) {
                if (n >= ldc) continue;
                if (n < N) {
                    float bv = bias ? bias[n] : 0.f;
                    #pragma unroll
                    for (int r = 0; r < 4; ++r)
                        Cb[(size_t)(mb + r) * ldc + n] = f2bf(acc[mi][ni][r] + bv);
                } else {
                    #pragma unroll
                    for (int r = 0; r < 4; ++r)
                        Cb[(size_t)(mb + r) * ldc + n] = 0;
                }
            } else {
                if (n >= GLD) continue;
                int bb = mb >> 6, p0 = mb & 63;
                size_t base = ((((size_t)bb * NT4 + (n >> 4)) * 2 + (p0 >> 5)) * 64
                               + ((p0 >> 3) & 3) * 16 + (n & 15)) * 8 + (p0 & 7);
                u16 wv[4];
                if (n < N) {
                    float bv = bias ? bias[n] : 0.f;
                    #pragma unroll
                    for (int r = 0; r < 4; ++r) wv[r] = f2bf(acc[mi][ni][r] + bv);
                } else {
                    #pragma unroll
                    for (int r = 0; r < 4; ++r) wv[r] = 0;
                }
                uint2 st;
                st.x = (unsigned int)wv[0] | ((unsigned int)wv[1] << 16);
                st.y = (unsigned int)wv[2] | ((unsigned int)wv[3] << 16);
                *(uint2*)(Cb + base) = st;
            }
        }
    }
}

// ---------- LSTM0 activation ----------
__global__ void lstm_act(const u16* __restrict__ gates, u16* __restrict__ hout) {
    int idx = blockIdx.x * 256 + threadIdx.x;   // 8192*320 exact
    int r = idx / KPAD, c = idx % KPAD;
    float h = 0.f;
    if (c < HH) {
        const u16* g = gates + (size_t)r * N3H;
        float gi = bf2f(g[c]);
        float gg = bf2f(g[c + HH]);
        float go = bf2f(g[c + 2 * HH]);
        float cc = fast_sigmoid(gi) * fast_tanh(gg);
        h = fast_sigmoid(go) * fast_tanh(cc);
    }
    hout[idx] = f2bf(h);
}

// ---------- sequential scan: 1024 thr/WG (16 waves), MFMA matvecs ----------
// v7: occupancy 2->4 waves/SIMD (1 block/CU either way); phase-2 slice=wave so
// the we2 slice lives in SGPRs (s_load) and the cross-wave reduce uses a
// conflict-free part[16][64] buffer; softmax computed once (wave 0) into a
// shared alpha slot. Per-lane exp chain halves (20 terms).
__global__ __launch_bounds__(1024) void scan_kernel(
    const u16* __restrict__ sproj,            // [8192][320] bf16, pads 0
    const u16* __restrict__ tproj,            // [8192][320] bf16, pads 0
    const uint4* __restrict__ Gmf,            // [128][57][2][64] frags
    const u16* __restrict__ hp,               // [8192][900] bf16 (bias folded)
    const uint4* __restrict__ Wf,             // [19][10][64] frags
    const float* __restrict__ we2g,           // [320] 2*w_e, f32, pads 0
    const int* __restrict__ premise_len,
    const int* __restrict__ hypothesis_len,
    float* __restrict__ hfin)                 // [128][320] fp32
{
    __shared__ __align__(16) uint4 gml[NT4 * 2 * 64];   // 116736 B (Gm frags)
    __shared__ __align__(16) uint4 wlds[3 * 10 * 64];   // 30720 B (W tiles 16-18)
    __shared__ __align__(16) float tpm[320];            // 2*(t_k + m_proj); [304,320) stay 0
    __shared__ __align__(16) unsigned int hmhi[160];    // hm hi bf16 pairs (pads 0)
    __shared__ __align__(16) unsigned int hmlo[160];    // hm lo residual pairs
    __shared__ __align__(16) float part[NW][64];        // phase-2 partials (4096 B)
    __shared__ __align__(16) u16 aw_sh[128];            // alpha hi[0:64] lo[64:128]
    __shared__ __align__(16) float gates[912];
    // total LDS = 116736+30720+1280+640+640+4096+256+3648 = 158016 B < 160 KiB

    const int b = blockIdx.x, t = threadIdx.x;
    const int lane = t & 63, w = t >> 6;
    const int lr = lane & 15, qr = lane >> 4;
    const int plen = premise_len[b], hlen = hypothesis_len[b];

    // ---- stage Gm frags + leftover W tiles (16-18) into LDS ----
    {
        const uint4* gsrc = Gmf + (size_t)b * (NT4 * 2 * 64);
        for (int i = t; i < NT4 * 2 * 64; i += 1024) gml[i] = gsrc[i];
    }
    for (int i = t; i < 3 * 10 * 64; i += 1024) wlds[i] = Wf[16 * 640 + i];
    if (t < 320) tpm[t] = 0.f;
    if (t < 160) { hmhi[t] = 0; hmlo[t] = 0; }

    // ---- pin W tile w in registers (40 regs) ----
    uint4 wreg[10];
    #pragma unroll
    for (int ks = 0; ks < 10; ++ks) wreg[ks] = Wf[(size_t)w * 640 + ks * 64 + lane];

    // ---- phase-2 per-lane state: row p = lane, h-slice [20w, 20w+20) ----
    unsigned int spd[10];    // s_proj[lane][20w..20w+20) bf16 pairs
    {
        const u16* srow = sproj + (size_t)(b * PP + lane) * KPAD + 20 * w;
        #pragma unroll
        for (int q = 0; q < 5; ++q) {
            uint2 v = *(const uint2*)(srow + 4 * q);
            spd[2 * q] = v.x; spd[2 * q + 1] = v.y;
        }
    }
    // we2 slice is wave-uniform -> scalar loads (SGPRs)
    const int wu = __builtin_amdgcn_readfirstlane(w);
    const float* wep = we2g + 20 * wu;
    float we_s[20];
    #pragma unroll
    for (int j = 0; j < 20; ++j) we_s[j] = wep[j];

    // wave 0: full wsum (Σ w_e) for the energy formula
    float wsumf = 0.f;
    if (w == 0) {
        float s = 0.f;
        #pragma unroll
        for (int q = 0; q < 5; ++q) s += we2g[lane + 64 * q];
        #pragma unroll
        for (int d = 32; d; d >>= 1) s += __shfl_xor(s, d);
        wsumf = 0.5f * s;
    }
    __syncthreads();

    const int nt4 = (w < 9) ? 4 : 3;   // phase-4 tiles: T = w + 16i (57 total)
    const bool act2 = lane < plen;

    for (int k = 0; k < hlen; ++k) {
        const u16* tprow = tproj + (size_t)(b * KK + k) * KPAD;
        const u16* hprow = hp + (size_t)(b * KK + k) * 900;

        // iter-start prefetches (consumed later in the iteration)
        u16 hpv[4];
        #pragma unroll
        for (int i = 0; i < 4; ++i) {
            hpv[i] = 0;
            if (i < nt4 && lane < 16) {
                int j = (w + 16 * i) * 16 + lane;
                if (j < 900) hpv[i] = hprow[j];
            }
        }
        u16 tk0 = 0, tk1 = 0;
        if (lane < 16) {
            tk0 = tprow[w * 16 + lane];
            if (w < 3) tk1 = tprow[(16 + w) * 16 + lane];
        }

        // ---- phase 1: tpm = 2*(t_k + hm . W_m^T) via MFMA ----
        bf16x8 a1[10];
        {
            const unsigned int* abase = (lr == 1) ? hmlo : hmhi;
            uint4 z; z.x = 0; z.y = 0; z.z = 0; z.w = 0;
            #pragma unroll
            for (int ks = 0; ks < 10; ++ks) {
                uint4 u = *(const uint4*)(abase + 16 * ks + 4 * qr);
                a1[ks] = as_bf8((lr < 2) ? u : z);
            }
        }
        {   // tile w (register-resident W)
            f32x4 ac0 = {}, ac1 = {};
            #pragma unroll
            for (int ks = 0; ks < 10; ks += 2) {
                ac0 = __builtin_amdgcn_mfma_f32_16x16x32_bf16(a1[ks], as_bf8(wreg[ks]), ac0, 0, 0, 0);
                ac1 = __builtin_amdgcn_mfma_f32_16x16x32_bf16(a1[ks + 1], as_bf8(wreg[ks + 1]), ac1, 0, 0, 0);
            }
            if (lane < 16) tpm[w * 16 + lane] = 2.f * (bf2f(tk0) + ((ac0[0] + ac0[1]) + (ac1[0] + ac1[1])));
        }
        if (w < 3) {   // tile 16+w from LDS
            f32x4 ac0 = {}, ac1 = {};
            #pragma unroll
            for (int ks = 0; ks < 10; ks += 2) {
                bf16x8 b0 = as_bf8(wlds[w * 640 + ks * 64 + lane]);
                bf16x8 b1 = as_bf8(wlds[w * 640 + (ks + 1) * 64 + lane]);
                ac0 = __builtin_amdgcn_mfma_f32_16x16x32_bf16(a1[ks], b0, ac0, 0, 0, 0);
                ac1 = __builtin_amdgcn_mfma_f32_16x16x32_bf16(a1[ks + 1], b1, ac1, 0, 0, 0);
            }
            if (lane < 16) tpm[(16 + w) * 16 + lane] = 2.f * (bf2f(tk1) + ((ac0[0] + ac0[1]) + (ac1[0] + ac1[1])));
        }
        __syncthreads();   // A: tpm final

        // ---- phase 2: partial energies; row p=lane, slice [20w,20w+20) ----
        {
            float accn0 = 0.f, accn1 = 0.f;
            if (act2) {
                #pragma unroll
                for (int q = 0; q < 5; ++q) {
                    float4 tv = ((const float4*)tpm)[5 * w + q];   // wave-uniform broadcast
                    float x0 = fmaf(2.f, bf2f_lo(spd[2 * q]), tv.x);
                    float x1 = fmaf(2.f, bf2f_hi(spd[2 * q]), tv.y);
                    float x2 = fmaf(2.f, bf2f_lo(spd[2 * q + 1]), tv.z);
                    float x3 = fmaf(2.f, bf2f_hi(spd[2 * q + 1]), tv.w);
                    accn0 = fmaf(we_s[4 * q],     __builtin_amdgcn_rcpf(__expf(x0) + 1.f), accn0);
                    accn1 = fmaf(we_s[4 * q + 1], __builtin_amdgcn_rcpf(__expf(x1) + 1.f), accn1);
                    accn0 = fmaf(we_s[4 * q + 2], __builtin_amdgcn_rcpf(__expf(x2) + 1.f), accn0);
                    accn1 = fmaf(we_s[4 * q + 3], __builtin_amdgcn_rcpf(__expf(x3) + 1.f), accn1);
                }
            }
            part[w][lane] = act2 ? (accn0 + accn1) : 0.f;
        }
        __syncthreads();   // B: partials ready

        // ---- phase 3 (wave 0 only): reduce + softmax -> shared alpha hi/lo ----
        if (w == 0) {
            float s = 0.f;
            #pragma unroll
            for (int q = 0; q < NW; ++q) s += part[q][lane];
            float e = act2 ? (wsumf - s) : -1e30f;
            float mx = e;
            #pragma unroll
            for (int d = 32; d; d >>= 1) mx = fmaxf(mx, __shfl_xor(mx, d));
            float ex = act2 ? __expf(e - mx) : 0.f;
            float sm = ex;
            #pragma unroll
            for (int d = 32; d; d >>= 1) sm += __shfl_xor(sm, d);
            float al = ex * __builtin_amdgcn_rcpf(sm);
            u16 ah = f2bf(al);
            aw_sh[lane] = ah;
            aw_sh[64 + lane] = f2bf(al - bf2f(ah));
        }
        __syncthreads();   // B2: alpha visible

        // ---- phase 4: gates = alpha . Gm via MFMA (Gm frags LDS-resident) ----
        bf16x8 a4[2];
        {
            const u16* abase = aw_sh + ((lr == 1) ? 64 : 0);
            uint4 z; z.x = 0; z.y = 0; z.z = 0; z.w = 0;
            #pragma unroll
            for (int ks = 0; ks < 2; ++ks) {
                uint4 u = *(const uint4*)(abase + 32 * ks + 8 * qr);
                a4[ks] = as_bf8((lr < 2) ? u : z);
            }
        }
        #pragma unroll
        for (int i = 0; i < 4; ++i) {
            if (i < nt4) {
                int T = w + 16 * i;
                f32x4 ac0 = {}, ac1 = {};
                ac0 = __builtin_amdgcn_mfma_f32_16x16x32_bf16(a4[0], as_bf8(gml[(T * 2 + 0) * 64 + lane]), ac0, 0, 0, 0);
                ac1 = __builtin_amdgcn_mfma_f32_16x16x32_bf16(a4[1], as_bf8(gml[(T * 2 + 1) * 64 + lane]), ac1, 0, 0, 0);
                if (lane < 16) gates[T * 16 + lane] = ((ac0[0] + ac0[1]) + (ac1[0] + ac1[1])) + bf2f(hpv[i]);
            }
        }
        __syncthreads();   // C: gates final

        // ---- phase 5 (t<300): h_m = sig(o)*tanh(sig(i)*tanh(g)); pack hi/lo pairs ----
        if (t < 300) {
            float gi = gates[t], gg = gates[300 + t], go = gates[600 + t];
            float cc = fast_sigmoid(gi) * fast_tanh(gg);
            float h = fast_sigmoid(go) * fast_tanh(cc);
            if (k == hlen - 1) hfin[(size_t)b * KPAD + t] = h;
            u16 hh = f2bf(h);
            float res = h - bf2f(hh);
            float hn = __shfl_down(h, 1);     // partner t+1 (same wave: pairs never cross 64)
            float rn2 = __shfl_down(res, 1);
            if ((t & 1) == 0) {
                hmhi[t >> 1] = (unsigned int)hh | ((unsigned int)f2bf(hn) << 16);
                hmlo[t >> 1] = (unsigned int)f2bf(res) | ((unsigned int)f2bf(rn2) << 16);
            }
        }
        __syncthreads();   // D: hm ready for next phase 1
    }
}

// ---------- final FC + softmax over 3 classes (dual-dtype in AND out) ----------
__global__ void fc_softmax(const float* __restrict__ hfin, const void* __restrict__ fcw,
                           const void* __restrict__ fcb, void* __restrict__ out,
                           const int* __restrict__ flag) {
    int b = threadIdx.x;     // 128 threads, 1 block
    int isbf = *flag;
    float l[3];
    #pragma unroll
    for (int c = 0; c < 3; ++c) {
        float acc = rdf(fcb, c, isbf);
        const float* hr = hfin + (size_t)b * KPAD;
        for (int h = 0; h < HH; ++h) acc += hr[h] * rdf(fcw, (size_t)c * HH + h, isbf);
        l[c] = acc;
    }
    float mx = fmaxf(l[0], fmaxf(l[1], l[2]));
    float e0 = __expf(l[0] - mx), e1 = __expf(l[1] - mx), e2 = __expf(l[2] - mx);
    float inv = __builtin_amdgcn_rcpf(e0 + e1 + e2);
    if (isbf) {
        u16* o = (u16*)out;
        o[b * 3 + 0] = f2bf(e0 * inv);
        o[b * 3 + 1] = f2bf(e1 * inv);
        o[b * 3 + 2] = f2bf(e2 * inv);
    } else {
        float* o = (float*)out;
        o[b * 3 + 0] = e0 * inv;
        o[b * 3 + 1] = e1 * inv;
        o[b * 3 + 2] = e2 * inv;
    }
}

extern "C" void kernel_launch(void* const* d_in, const int* in_sizes, int n_in,
                              void* d_out, int out_size, void* d_ws, size_t ws_size,
                              hipStream_t stream) {
    const int* premise        = (const int*)d_in[0];
    const int* premise_len    = (const int*)d_in[1];
    const int* hypothesis     = (const int*)d_in[2];
    const int* hypothesis_len = (const int*)d_in[3];
    const void* embed = d_in[4];
    const void* w_e   = d_in[5];
    const void* W_s   = d_in[6];
    const void* W_t   = d_in[7];
    const void* W_m   = d_in[8];
    const void* fc_w  = d_in[9];
    const void* fc_b  = d_in[10];
    const void* Wih_p = d_in[11];
    const void* bih_p = d_in[13];
    const void* bhh_p = d_in[14];
    const void* Wih_h = d_in[15];
    const void* bih_h = d_in[17];
    const void* bhh_h = d_in[18];
    const void* Wih_m = d_in[19];
    const void* bih_m = d_in[21];
    const void* bhh_m = d_in[22];
    (void)in_sizes; (void)n_in; (void)out_size;

    // ---- lifetime-overlapped workspace arena ----
    char* w = (char*)d_ws;
    auto alloc = [&](size_t bytes) -> char* {
        char* r = (char*)(((uintptr_t)w + 255) & ~(uintptr_t)255);
        w = r + bytes;
        return r;
    };
    char* regA = alloc((size_t)MROWS * KPAD * 2);   // Xbuf -> s_proj
    char* regB = alloc((size_t)MROWS * GLD * 2);    // gates_p -> Gm frags (14.94 MB)
    char* regC = alloc((size_t)MROWS * N3H * 2);    // gates_h -> hproj
    char* regD = alloc((size_t)MROWS * KPAD * 2);   // h_s -> t_proj
    char* regE = alloc((size_t)MROWS * KPAD * 2);   // h_t -> h_fin
    u16* Wp_pad  = (u16*)alloc((size_t)1024 * KPAD * 2);
    u16* Wh_pad  = (u16*)alloc((size_t)1024 * KPAD * 2);
    u16* Wa_pad  = (u16*)alloc((size_t)1024 * KPAD * 2);
    u16* Whm_pad = (u16*)alloc((size_t)1024 * KPAD * 2);
    u16* Ws_pad  = (u16*)alloc((size_t)384 * KPAD * 2);
    u16* Wt_pad  = (u16*)alloc((size_t)384 * KPAD * 2);
    uint4* Wf    = (uint4*)alloc((size_t)NT1 * 10 * 64 * 16);
    float* we2g  = (float*)alloc(320 * 4);
    float* bsum_p = (float*)alloc(N3H * 4);
    float* bsum_h = (float*)alloc(N3H * 4);
    float* bsum_m = (float*)alloc(N3H * 4);
    int* dflag   = (int*)alloc(256);
    size_t needed = (size_t)(w - (char*)d_ws);
    if (needed > ws_size) {
        zero_out<<<1, 384, 0, stream>>>((u16*)d_out);
        return;
    }
    u16* Xbuf   = (u16*)regA;
    u16* s_proj = (u16*)regA;                       // after Xbuf dead
    u16* h_s    = (u16*)regD;
    u16* t_proj = (u16*)regD;                       // after h_s dead
    u16* h_t    = (u16*)regE;
    float* h_fin = (float*)regE;                    // after h_t dead (scan time)

    // dtype detect, then prepack
    detect_dtype<<<1, 320, 0, stream>>>((const u16*)w_e, dflag);
    pack_w<<<1280, 256, 0, stream>>>(Wih_p, Wp_pad, 1024, N3H, HH, 0, 1, dflag);
    pack_w<<<1280, 256, 0, stream>>>(Wih_h, Wh_pad, 1024, N3H, HH, 0, 1, dflag);
    pack_w<<<1280, 256, 0, stream>>>(Wih_m, Wa_pad, 1024, N3H, 600, 0, 1, dflag);
    pack_w<<<1280, 256, 0, stream>>>(Wih_m, Whm_pad, 1024, N3H, 600, HH, 1, dflag);
    pack_w<<<480, 256, 0, stream>>>(W_s, Ws_pad, 384, HH, HH, 0, 0, dflag);
    pack_w<<<480, 256, 0, stream>>>(W_t, Wt_pad, 384, HH, HH, 0, 0, dflag);
    pack_wf<<<48, 256, 0, stream>>>(W_m, Wf, dflag);
    pack_we<<<1, 320, 0, stream>>>(w_e, we2g, dflag);
    pack_bias<<<11, 256, 0, stream>>>(bih_p, bhh_p, bih_h, bhh_h, bih_m, bhh_m,
                                      bsum_p, bsum_h, bsum_m, dflag);

    // premise: gather -> gates (bias folded) -> h_s
    gather_embed<<<10240, 256, 0, stream>>>(premise, embed, Xbuf, dflag);
    gemm_bt<<<dim3(64, 8), 256, 0, stream>>>(Xbuf, Wp_pad, (u16*)regB, bsum_p, N3H, N3H, 0);
    lstm_act<<<10240, 256, 0, stream>>>((u16*)regB, h_s);
    // hypothesis: reuse Xbuf
    gather_embed<<<10240, 256, 0, stream>>>(hypothesis, embed, Xbuf, dflag);
    gemm_bt<<<dim3(64, 8), 256, 0, stream>>>(Xbuf, Wh_pad, (u16*)regC, bsum_h, N3H, N3H, 0);
    lstm_act<<<10240, 256, 0, stream>>>((u16*)regC, h_t);

    // projections (ordering chosen so region reuse is safe)
    gemm_bt<<<dim3(64, 3), 256, 0, stream>>>(h_s, Ws_pad, s_proj, nullptr, HH, KPAD, 0);   // into A (Xbuf dead)
    gemm_bt<<<dim3(64, 8), 256, 0, stream>>>(h_s, Wa_pad, (u16*)regB, nullptr, N3H, 0, 1); // Gm FRAGS into B
    gemm_bt<<<dim3(64, 3), 256, 0, stream>>>(h_t, Wt_pad, t_proj, nullptr, HH, KPAD, 0);   // into D (h_s dead)
    gemm_bt<<<dim3(64, 8), 256, 0, stream>>>(h_t, Whm_pad, (u16*)regC, bsum_m, N3H, N3H, 0); // hproj into C

    // sequential match-LSTM scan, one WG per batch, 1024 threads (16 waves)
    scan_kernel<<<BB, 1024, 0, stream>>>(s_proj, t_proj, (const uint4*)regB,
                                         (const u16*)regC, Wf, we2g,
                                         premise_len, hypothesis_len, h_fin);
    // classifier
    fc_softmax<<<1, 128, 0, stream>>>(h_fin, fc_w, fc_b, d_out, dflag);
}

// Round 7
// 623.338 us; speedup vs baseline: 26.7967x; 1.0305x over previous
//
#include <hip/hip_runtime.h>
#include <stdint.h>

typedef unsigned short u16;
typedef __attribute__((ext_vector_type(8))) __bf16 bf16x8;
typedef __attribute__((ext_vector_type(4))) float f32x4;

// ---------- bf16 helpers (raw-bit, exact bf16 semantics) ----------
__device__ __forceinline__ float bf2f(u16 u) {
    union { unsigned int i; float f; } v; v.i = ((unsigned int)u) << 16; return v.f;
}
__device__ __forceinline__ float bf2f_lo(unsigned int u) {
    union { unsigned int i; float f; } v; v.i = u << 16; return v.f;
}
__device__ __forceinline__ float bf2f_hi(unsigned int u) {
    union { unsigned int i; float f; } v; v.i = u & 0xffff0000u; return v.f;
}
__device__ __forceinline__ u16 f2bf(float f) {
    union { float f; unsigned int i; } v; v.f = f;
    unsigned int x = v.i;
    unsigned int r = (x + 0x7fffu + ((x >> 16) & 1u)) >> 16;
    return (u16)r;
}
__device__ __forceinline__ float rdf(const void* p, size_t i, int isbf) {
    return isbf ? bf2f(((const u16*)p)[i]) : ((const float*)p)[i];
}
__device__ __forceinline__ float fast_sigmoid(float x) {
    return __builtin_amdgcn_rcpf(1.f + __expf(-x));
}
__device__ __forceinline__ float fast_tanh(float x) {
    float u = __expf(x + x);
    return 1.f - 2.f * __builtin_amdgcn_rcpf(u + 1.f);
}
__device__ __forceinline__ bf16x8 as_bf8(uint4 u) {
    union { uint4 a; bf16x8 b; } c; c.a = u; return c.b;
}

// Problem dims
#define BB 128
#define PP 64
#define KK 64
#define HH 300
#define MROWS 8192     // B*P = B*K
#define KPAD 320       // K padded; row stride for s_proj/t_proj/h_fin
#define N3H 900        // i,g,o gates only (f-gate unused: c_prev=0)
#define GLD 912        // Gm frag-padded col count (57 tiles x 16)
#define NT1 19         // phase-1 N-tiles (304 cols)
#define NT4 57         // phase-4 N-tiles (912 cols)
#define NW 16          // scan waves per block

// ---------- dtype detector ----------
__global__ void detect_dtype(const u16* __restrict__ raw, int* __restrict__ flag) {
    __shared__ int cnt;
    if (threadIdx.x == 0) cnt = 0;
    __syncthreads();
    if (threadIdx.x < 300 && (raw[threadIdx.x] & 0x8000u)) atomicAdd(&cnt, 1);
    __syncthreads();
    if (threadIdx.x == 0) *flag = (cnt < 8) ? 1 : 0;   // 1 = bf16, 0 = fp32
}

// ---------- prepack kernels ----------
__global__ void pack_w(const void* __restrict__ src, u16* __restrict__ dst,
                       int dstRowsPad, int nsrcRows, int srcld, int colOff, int igo,
                       const int* __restrict__ flag) {
    int i = blockIdx.x * 256 + threadIdx.x;
    if (i >= dstRowsPad * KPAD) return;
    int isbf = *flag;
    int r = i / KPAD, c = i % KPAD;
    u16 v = 0;
    if (r < nsrcRows && c < HH) {
        int sr = igo ? (r < HH ? r : r + HH) : r;
        v = f2bf(rdf(src, (size_t)sr * srcld + colOff + c, isbf));
    }
    dst[i] = v;
}

// W_m packed to MFMA B-fragment layout: Wf[T][ks][lane] = bf16x8 of
// W_m[j = T*16 + (lane&15)][k = 32*ks + 8*(lane>>4) + e], e<8; zeros outside 300x300.
__global__ void pack_wf(const void* __restrict__ Wm, uint4* __restrict__ dst,
                        const int* __restrict__ flag) {
    int i = blockIdx.x * 256 + threadIdx.x;
    if (i >= NT1 * 10 * 64) return;
    int isbf = *flag;
    int lane = i & 63, ks = (i >> 6) % 10, T = i / 640;
    int j = T * 16 + (lane & 15);
    int k0 = 32 * ks + 8 * (lane >> 4);
    unsigned int d[4];
    #pragma unroll
    for (int q = 0; q < 4; ++q) {
        int ka = k0 + 2 * q, kb = k0 + 2 * q + 1;
        unsigned int lo = (j < 300 && ka < 300) ? f2bf(rdf(Wm, (size_t)j * HH + ka, isbf)) : 0;
        unsigned int hi = (j < 300 && kb < 300) ? f2bf(rdf(Wm, (size_t)j * HH + kb, isbf)) : 0;
        d[q] = lo | (hi << 16);
    }
    uint4 v; v.x = d[0]; v.y = d[1]; v.z = d[2]; v.w = d[3];
    dst[i] = v;
}

__global__ void pack_bias(const void* bip, const void* bhp, const void* bih_, const void* bhh_,
                          const void* bim, const void* bhm,
                          float* bp, float* bh, float* bm, const int* __restrict__ flag) {
    int i = blockIdx.x * 256 + threadIdx.x;
    if (i >= 3 * N3H) return;
    int isbf = *flag;
    int which = i / N3H, r = i % N3H;
    int sr = (r < HH) ? r : r + HH;
    if (which == 0)      bp[r] = rdf(bip, sr, isbf) + rdf(bhp, sr, isbf);
    else if (which == 1) bh[r] = rdf(bih_, sr, isbf) + rdf(bhh_, sr, isbf);
    else                 bm[r] = rdf(bim, sr, isbf) + rdf(bhm, sr, isbf);
}

// 2*w_e as float[320] (pads 0) for the scan's SGPR path
__global__ void pack_we(const void* __restrict__ we, float* __restrict__ dst,
                        const int* __restrict__ flag) {
    int i = threadIdx.x;   // 320
    dst[i] = (i < 300) ? 2.f * rdf(we, i, *flag) : 0.f;
}

__global__ void gather_embed(const int* __restrict__ idx, const void* __restrict__ embed,
                             u16* __restrict__ X, const int* __restrict__ flag) {
    int i = blockIdx.x * 256 + threadIdx.x;   // 8192*320 exact
    int isbf = *flag;
    int r = i / KPAD, c = i % KPAD;
    X[i] = (c < HH) ? f2bf(rdf(embed, (size_t)idx[r] * HH + c, isbf)) : (u16)0;
}

__global__ void zero_out(u16* out) { out[threadIdx.x] = 0; }

// ---------- MFMA GEMM:  C[M x N] = A[M x 320] * B[Npad x 320]^T (+bias) ----------
// frag=0: bf16 row-major out, cols [N, ldc) zero-padded.
// frag=1: write MFMA B-fragment layout for the scan's phase-4.
__global__ __launch_bounds__(256) void gemm_bt(
    const u16* __restrict__ A, const u16* __restrict__ B,
    u16* __restrict__ Cb, const float* __restrict__ bias, int N, int ldc, int frag)
{
    __shared__ __align__(16) u16 At[128 * 32];
    __shared__ __align__(16) u16 Bt[128 * 32];
    const int tid = threadIdx.x;
    const int m0 = blockIdx.x * 128;
    const int n0 = blockIdx.y * 128;
    const int lane = tid & 63;
    const int wave = tid >> 6;
    const int rm = (wave & 1) * 64;
    const int rn = (wave >> 1) * 64;
    const int qr = lane >> 4;
    const int lr = lane & 15;

    f32x4 acc[4][4] = {};

    const int c0 = tid, c1 = tid + 256;
    const int r0 = c0 >> 2, o0 = (c0 & 3) * 8;
    const int r1 = c1 >> 2, o1 = (c1 & 3) * 8;

    for (int k0 = 0; k0 < KPAD; k0 += 32) {
        uint4 a0v = *(const uint4*)(A + (size_t)(m0 + r0) * KPAD + k0 + o0);
        uint4 a1v = *(const uint4*)(A + (size_t)(m0 + r1) * KPAD + k0 + o1);
        uint4 b0v = *(const uint4*)(B + (size_t)(n0 + r0) * KPAD + k0 + o0);
        uint4 b1v = *(const uint4*)(B + (size_t)(n0 + r1) * KPAD + k0 + o1);
        __syncthreads();
        *(uint4*)(At + c0 * 8) = a0v;
        *(uint4*)(At + c1 * 8) = a1v;
        *(uint4*)(Bt + c0 * 8) = b0v;
        *(uint4*)(Bt + c1 * 8) = b1v;
        __syncthreads();
        bf16x8 af[4], bfr[4];
        #pragma unroll
        for (int i = 0; i < 4; ++i) {
            af[i]  = *(const bf16x8*)(At + (rm + i * 16 + lr) * 32 + qr * 8);
            bfr[i] = *(const bf16x8*)(Bt + (rn + i * 16 + lr) * 32 + qr * 8);
        }
        #pragma unroll
        for (int mi = 0; mi < 4; ++mi)
            #pragma unroll
            for (int ni = 0; ni < 4; ++ni)
                acc[mi][ni] = __builtin_amdgcn_mfma_f32_16x16x32_bf16(
                    af[mi], bfr[ni], acc[mi][ni], 0, 0, 0);
    }
    // C/D layout: col(n)=lane&15, row(m)=quad*4+reg   [verified m89/m91]
    #pragma unroll
    for (int mi = 0; mi < 4; ++mi) {
        #pragma unroll
        for (int ni = 0; ni < 4; ++ni) {
            int n = n0 + rn + ni * 16 + lr;
            int mb = m0 + rm + mi * 16 + qr * 4;
            if (!frag) {
                if (n >= ldc) continue;
                if (n < N) {
                    float bv = bias ? bias[n] : 0.f;
                    #pragma unroll
                    for (int r = 0; r < 4; ++r)
                        Cb[(size_t)(mb + r) * ldc + n] = f2bf(acc[mi][ni][r] + bv);
                } else {
                    #pragma unroll
                    for (int r = 0; r < 4; ++r)
                        Cb[(size_t)(mb + r) * ldc + n] = 0;
                }
            } else {
                if (n >= GLD) continue;
                int bb = mb >> 6, p0 = mb & 63;
                size_t base = ((((size_t)bb * NT4 + (n >> 4)) * 2 + (p0 >> 5)) * 64
                               + ((p0 >> 3) & 3) * 16 + (n & 15)) * 8 + (p0 & 7);
                u16 wv[4];
                if (n < N) {
                    float bv = bias ? bias[n] : 0.f;
                    #pragma unroll
                    for (int r = 0; r < 4; ++r) wv[r] = f2bf(acc[mi][ni][r] + bv);
                } else {
                    #pragma unroll
                    for (int r = 0; r < 4; ++r) wv[r] = 0;
                }
                uint2 st;
                st.x = (unsigned int)wv[0] | ((unsigned int)wv[1] << 16);
                st.y = (unsigned int)wv[2] | ((unsigned int)wv[3] << 16);
                *(uint2*)(Cb + base) = st;
            }
        }
    }
}

// ---------- LSTM0 activation ----------
__global__ void lstm_act(const u16* __restrict__ gates, u16* __restrict__ hout) {
    int idx = blockIdx.x * 256 + threadIdx.x;   // 8192*320 exact
    int r = idx / KPAD, c = idx % KPAD;
    float h = 0.f;
    if (c < HH) {
        const u16* g = gates + (size_t)r * N3H;
        float gi = bf2f(g[c]);
        float gg = bf2f(g[c + HH]);
        float go = bf2f(g[c + 2 * HH]);
        float cc = fast_sigmoid(gi) * fast_tanh(gg);
        h = fast_sigmoid(go) * fast_tanh(cc);
    }
    hout[idx] = f2bf(h);
}

// ---------- sequential scan: 1024 thr/WG (16 waves), MFMA matvecs ----------
// v8: v7 + honest register contract. amdgpu_waves_per_eu(4,4): 16 waves/block and
// 1 block/CU (LDS-limited) means 4 waves/SIMD is the hard ceiling, so license the
// 128-VGPR tier instead of the compiler's 64-VGPR/8-wave default (v7 spilled 6.3 MB
// of scratch per dispatch). Phase-1 a1 frags built in two halves of 5 (20 transient
// regs, not 40), reg-tile and LDS-tile MFMAs interleaved within each half.
__global__ __launch_bounds__(1024)
__attribute__((amdgpu_waves_per_eu(4, 4)))
void scan_kernel(
    const u16* __restrict__ sproj,            // [8192][320] bf16, pads 0
    const u16* __restrict__ tproj,            // [8192][320] bf16, pads 0
    const uint4* __restrict__ Gmf,            // [128][57][2][64] frags
    const u16* __restrict__ hp,               // [8192][900] bf16 (bias folded)
    const uint4* __restrict__ Wf,             // [19][10][64] frags
    const float* __restrict__ we2g,           // [320] 2*w_e, f32, pads 0
    const int* __restrict__ premise_len,
    const int* __restrict__ hypothesis_len,
    float* __restrict__ hfin)                 // [128][320] fp32
{
    __shared__ __align__(16) uint4 gml[NT4 * 2 * 64];   // 116736 B (Gm frags)
    __shared__ __align__(16) uint4 wlds[3 * 10 * 64];   // 30720 B (W tiles 16-18)
    __shared__ __align__(16) float tpm[320];            // 2*(t_k + m_proj); [304,320) stay 0
    __shared__ __align__(16) unsigned int hmhi[160];    // hm hi bf16 pairs (pads 0)
    __shared__ __align__(16) unsigned int hmlo[160];    // hm lo residual pairs
    __shared__ __align__(16) float part[NW][64];        // phase-2 partials (4096 B)
    __shared__ __align__(16) u16 aw_sh[128];            // alpha hi[0:64] lo[64:128]
    __shared__ __align__(16) float gates[912];
    // total LDS = 158016 B < 160 KiB

    const int b = blockIdx.x, t = threadIdx.x;
    const int lane = t & 63, w = t >> 6;
    const int lr = lane & 15, qr = lane >> 4;
    const int plen = premise_len[b], hlen = hypothesis_len[b];

    // ---- stage Gm frags + leftover W tiles (16-18) into LDS ----
    {
        const uint4* gsrc = Gmf + (size_t)b * (NT4 * 2 * 64);
        for (int i = t; i < NT4 * 2 * 64; i += 1024) gml[i] = gsrc[i];
    }
    for (int i = t; i < 3 * 10 * 64; i += 1024) wlds[i] = Wf[16 * 640 + i];
    if (t < 320) tpm[t] = 0.f;
    if (t < 160) { hmhi[t] = 0; hmlo[t] = 0; }

    // ---- pin W tile w in registers (40 regs) ----
    uint4 wreg[10];
    #pragma unroll
    for (int ks = 0; ks < 10; ++ks) wreg[ks] = Wf[(size_t)w * 640 + ks * 64 + lane];

    // ---- phase-2 per-lane state: row p = lane, h-slice [20w, 20w+20) ----
    unsigned int spd[10];    // s_proj[lane][20w..20w+20) bf16 pairs
    {
        const u16* srow = sproj + (size_t)(b * PP + lane) * KPAD + 20 * w;
        #pragma unroll
        for (int q = 0; q < 5; ++q) {
            uint2 v = *(const uint2*)(srow + 4 * q);
            spd[2 * q] = v.x; spd[2 * q + 1] = v.y;
        }
    }
    // we2 slice is wave-uniform -> scalar loads (SGPRs)
    const int wu = __builtin_amdgcn_readfirstlane(w);
    const float* wep = we2g + 20 * wu;
    float we_s[20];
    #pragma unroll
    for (int j = 0; j < 20; ++j) we_s[j] = wep[j];

    // wave 0: full wsum (Σ w_e) for the energy formula
    float wsumf = 0.f;
    if (w == 0) {
        float s = 0.f;
        #pragma unroll
        for (int q = 0; q < 5; ++q) s += we2g[lane + 64 * q];
        #pragma unroll
        for (int d = 32; d; d >>= 1) s += __shfl_xor(s, d);
        wsumf = 0.5f * s;
    }
    __syncthreads();

    const int nt4 = (w < 9) ? 4 : 3;   // phase-4 tiles: T = w + 16i (57 total)
    const bool act2 = lane < plen;

    for (int k = 0; k < hlen; ++k) {
        const u16* tprow = tproj + (size_t)(b * KK + k) * KPAD;
        const u16* hprow = hp + (size_t)(b * KK + k) * 900;

        // iter-start prefetches (consumed later in the iteration)
        u16 hpv[4];
        #pragma unroll
        for (int i = 0; i < 4; ++i) {
            hpv[i] = 0;
            if (i < nt4 && lane < 16) {
                int j = (w + 16 * i) * 16 + lane;
                if (j < 900) hpv[i] = hprow[j];
            }
        }
        u16 tk0 = 0, tk1 = 0;
        if (lane < 16) {
            tk0 = tprow[w * 16 + lane];
            if (w < 3) tk1 = tprow[(16 + w) * 16 + lane];
        }

        // ---- phase 1: tpm = 2*(t_k + hm . W_m^T) via MFMA; a1 built in 2 halves,
        //      reg-tile (w) and LDS-tile (16+w, waves 0-2) interleaved per half ----
        {
            const unsigned int* abase = (lr == 1) ? hmlo : hmhi;
            uint4 z; z.x = 0; z.y = 0; z.z = 0; z.w = 0;
            f32x4 r0 = {}, r1 = {}, l0 = {}, l1 = {};
            #pragma unroll
            for (int h = 0; h < 2; ++h) {
                bf16x8 a1[5];
                #pragma unroll
                for (int j = 0; j < 5; ++j) {
                    int ks = 5 * h + j;
                    uint4 u = *(const uint4*)(abase + 16 * ks + 4 * qr);
                    a1[j] = as_bf8((lr < 2) ? u : z);
                }
                #pragma unroll
                for (int j = 0; j < 5; ++j) {
                    int ks = 5 * h + j;
                    if (j & 1) r1 = __builtin_amdgcn_mfma_f32_16x16x32_bf16(a1[j], as_bf8(wreg[ks]), r1, 0, 0, 0);
                    else       r0 = __builtin_amdgcn_mfma_f32_16x16x32_bf16(a1[j], as_bf8(wreg[ks]), r0, 0, 0, 0);
                }
                if (w < 3) {
                    #pragma unroll
                    for (int j = 0; j < 5; ++j) {
                        int ks = 5 * h + j;
                        bf16x8 bb = as_bf8(wlds[w * 640 + ks * 64 + lane]);
                        if (j & 1) l1 = __builtin_amdgcn_mfma_f32_16x16x32_bf16(a1[j], bb, l1, 0, 0, 0);
                        else       l0 = __builtin_amdgcn_mfma_f32_16x16x32_bf16(a1[j], bb, l0, 0, 0, 0);
                    }
                }
            }
            if (lane < 16) {
                tpm[w * 16 + lane] = 2.f * (bf2f(tk0) + ((r0[0] + r0[1]) + (r1[0] + r1[1])));
                if (w < 3)
                    tpm[(16 + w) * 16 + lane] = 2.f * (bf2f(tk1) + ((l0[0] + l0[1]) + (l1[0] + l1[1])));
            }
        }
        __syncthreads();   // A: tpm final

        // ---- phase 2: partial energies; row p=lane, slice [20w,20w+20) ----
        {
            float accn0 = 0.f, accn1 = 0.f;
            if (act2) {
                #pragma unroll
                for (int q = 0; q < 5; ++q) {
                    float4 tv = ((const float4*)tpm)[5 * w + q];   // wave-uniform broadcast
                    float x0 = fmaf(2.f, bf2f_lo(spd[2 * q]), tv.x);
                    float x1 = fmaf(2.f, bf2f_hi(spd[2 * q]), tv.y);
                    float x2 = fmaf(2.f, bf2f_lo(spd[2 * q + 1]), tv.z);
                    float x3 = fmaf(2.f, bf2f_hi(spd[2 * q + 1]), tv.w);
                    accn0 = fmaf(we_s[4 * q],     __builtin_amdgcn_rcpf(__expf(x0) + 1.f), accn0);
                    accn1 = fmaf(we_s[4 * q + 1], __builtin_amdgcn_rcpf(__expf(x1) + 1.f), accn1);
                    accn0 = fmaf(we_s[4 * q + 2], __builtin_amdgcn_rcpf(__expf(x2) + 1.f), accn0);
                    accn1 = fmaf(we_s[4 * q + 3], __builtin_amdgcn_rcpf(__expf(x3) + 1.f), accn1);
                }
            }
            part[w][lane] = act2 ? (accn0 + accn1) : 0.f;
        }
        __syncthreads();   // B: partials ready

        // ---- phase 3 (wave 0 only): reduce + softmax -> shared alpha hi/lo ----
        if (w == 0) {
            float s = 0.f;
            #pragma unroll
            for (int q = 0; q < NW; ++q) s += part[q][lane];
            float e = act2 ? (wsumf - s) : -1e30f;
            float mx = e;
            #pragma unroll
            for (int d = 32; d; d >>= 1) mx = fmaxf(mx, __shfl_xor(mx, d));
            float ex = act2 ? __expf(e - mx) : 0.f;
            float sm = ex;
            #pragma unroll
            for (int d = 32; d; d >>= 1) sm += __shfl_xor(sm, d);
            float al = ex * __builtin_amdgcn_rcpf(sm);
            u16 ah = f2bf(al);
            aw_sh[lane] = ah;
            aw_sh[64 + lane] = f2bf(al - bf2f(ah));
        }
        __syncthreads();   // B2: alpha visible

        // ---- phase 4: gates = alpha . Gm via MFMA (Gm frags LDS-resident) ----
        bf16x8 a4[2];
        {
            const u16* abase = aw_sh + ((lr == 1) ? 64 : 0);
            uint4 z; z.x = 0; z.y = 0; z.z = 0; z.w = 0;
            #pragma unroll
            for (int ks = 0; ks < 2; ++ks) {
                uint4 u = *(const uint4*)(abase + 32 * ks + 8 * qr);
                a4[ks] = as_bf8((lr < 2) ? u : z);
            }
        }
        #pragma unroll
        for (int i = 0; i < 4; ++i) {
            if (i < nt4) {
                int T = w + 16 * i;
                f32x4 ac0 = {}, ac1 = {};
                ac0 = __builtin_amdgcn_mfma_f32_16x16x32_bf16(a4[0], as_bf8(gml[(T * 2 + 0) * 64 + lane]), ac0, 0, 0, 0);
                ac1 = __builtin_amdgcn_mfma_f32_16x16x32_bf16(a4[1], as_bf8(gml[(T * 2 + 1) * 64 + lane]), ac1, 0, 0, 0);
                if (lane < 16) gates[T * 16 + lane] = ((ac0[0] + ac0[1]) + (ac1[0] + ac1[1])) + bf2f(hpv[i]);
            }
        }
        __syncthreads();   // C: gates final

        // ---- phase 5 (t<300): h_m = sig(o)*tanh(sig(i)*tanh(g)); pack hi/lo pairs ----
        if (t < 300) {
            float gi = gates[t], gg = gates[300 + t], go = gates[600 + t];
            float cc = fast_sigmoid(gi) * fast_tanh(gg);
            float h = fast_sigmoid(go) * fast_tanh(cc);
            if (k == hlen - 1) hfin[(size_t)b * KPAD + t] = h;
            u16 hh = f2bf(h);
            float res = h - bf2f(hh);
            float hn = __shfl_down(h, 1);     // partner t+1 (same wave: pairs never cross 64)
            float rn2 = __shfl_down(res, 1);
            if ((t & 1) == 0) {
                hmhi[t >> 1] = (unsigned int)hh | ((unsigned int)f2bf(hn) << 16);
                hmlo[t >> 1] = (unsigned int)f2bf(res) | ((unsigned int)f2bf(rn2) << 16);
            }
        }
        __syncthreads();   // D: hm ready for next phase 1
    }
}

// ---------- final FC + softmax over 3 classes (dual-dtype in AND out) ----------
__global__ void fc_softmax(const float* __restrict__ hfin, const void* __restrict__ fcw,
                           const void* __restrict__ fcb, void* __restrict__ out,
                           const int* __restrict__ flag) {
    int b = threadIdx.x;     // 128 threads, 1 block
    int isbf = *flag;
    float l[3];
    #pragma unroll
    for (int c = 0; c < 3; ++c) {
        float acc = rdf(fcb, c, isbf);
        const float* hr = hfin + (size_t)b * KPAD;
        for (int h = 0; h < HH; ++h) acc += hr[h] * rdf(fcw, (size_t)c * HH + h, isbf);
        l[c] = acc;
    }
    float mx = fmaxf(l[0], fmaxf(l[1], l[2]));
    float e0 = __expf(l[0] - mx), e1 = __expf(l[1] - mx), e2 = __expf(l[2] - mx);
    float inv = __builtin_amdgcn_rcpf(e0 + e1 + e2);
    if (isbf) {
        u16* o = (u16*)out;
        o[b * 3 + 0] = f2bf(e0 * inv);
        o[b * 3 + 1] = f2bf(e1 * inv);
        o[b * 3 + 2] = f2bf(e2 * inv);
    } else {
        float* o = (float*)out;
        o[b * 3 + 0] = e0 * inv;
        o[b * 3 + 1] = e1 * inv;
        o[b * 3 + 2] = e2 * inv;
    }
}

extern "C" void kernel_launch(void* const* d_in, const int* in_sizes, int n_in,
                              void* d_out, int out_size, void* d_ws, size_t ws_size,
                              hipStream_t stream) {
    const int* premise        = (const int*)d_in[0];
    const int* premise_len    = (const int*)d_in[1];
    const int* hypothesis     = (const int*)d_in[2];
    const int* hypothesis_len = (const int*)d_in[3];
    const void* embed = d_in[4];
    const void* w_e   = d_in[5];
    const void* W_s   = d_in[6];
    const void* W_t   = d_in[7];
    const void* W_m   = d_in[8];
    const void* fc_w  = d_in[9];
    const void* fc_b  = d_in[10];
    const void* Wih_p = d_in[11];
    const void* bih_p = d_in[13];
    const void* bhh_p = d_in[14];
    const void* Wih_h = d_in[15];
    const void* bih_h = d_in[17];
    const void* bhh_h = d_in[18];
    const void* Wih_m = d_in[19];
    const void* bih_m = d_in[21];
    const void* bhh_m = d_in[22];
    (void)in_sizes; (void)n_in; (void)out_size;

    // ---- lifetime-overlapped workspace arena ----
    char* w = (char*)d_ws;
    auto alloc = [&](size_t bytes) -> char* {
        char* r = (char*)(((uintptr_t)w + 255) & ~(uintptr_t)255);
        w = r + bytes;
        return r;
    };
    char* regA = alloc((size_t)MROWS * KPAD * 2);   // Xbuf -> s_proj
    char* regB = alloc((size_t)MROWS * GLD * 2);    // gates_p -> Gm frags (14.94 MB)
    char* regC = alloc((size_t)MROWS * N3H * 2);    // gates_h -> hproj
    char* regD = alloc((size_t)MROWS * KPAD * 2);   // h_s -> t_proj
    char* regE = alloc((size_t)MROWS * KPAD * 2);   // h_t -> h_fin
    u16* Wp_pad  = (u16*)alloc((size_t)1024 * KPAD * 2);
    u16* Wh_pad  = (u16*)alloc((size_t)1024 * KPAD * 2);
    u16* Wa_pad  = (u16*)alloc((size_t)1024 * KPAD * 2);
    u16* Whm_pad = (u16*)alloc((size_t)1024 * KPAD * 2);
    u16* Ws_pad  = (u16*)alloc((size_t)384 * KPAD * 2);
    u16* Wt_pad  = (u16*)alloc((size_t)384 * KPAD * 2);
    uint4* Wf    = (uint4*)alloc((size_t)NT1 * 10 * 64 * 16);
    float* we2g  = (float*)alloc(320 * 4);
    float* bsum_p = (float*)alloc(N3H * 4);
    float* bsum_h = (float*)alloc(N3H * 4);
    float* bsum_m = (float*)alloc(N3H * 4);
    int* dflag   = (int*)alloc(256);
    size_t needed = (size_t)(w - (char*)d_ws);
    if (needed > ws_size) {
        zero_out<<<1, 384, 0, stream>>>((u16*)d_out);
        return;
    }
    u16* Xbuf   = (u16*)regA;
    u16* s_proj = (u16*)regA;                       // after Xbuf dead
    u16* h_s    = (u16*)regD;
    u16* t_proj = (u16*)regD;                       // after h_s dead
    u16* h_t    = (u16*)regE;
    float* h_fin = (float*)regE;                    // after h_t dead (scan time)

    // dtype detect, then prepack
    detect_dtype<<<1, 320, 0, stream>>>((const u16*)w_e, dflag);
    pack_w<<<1280, 256, 0, stream>>>(Wih_p, Wp_pad, 1024, N3H, HH, 0, 1, dflag);
    pack_w<<<1280, 256, 0, stream>>>(Wih_h, Wh_pad, 1024, N3H, HH, 0, 1, dflag);
    pack_w<<<1280, 256, 0, stream>>>(Wih_m, Wa_pad, 1024, N3H, 600, 0, 1, dflag);
    pack_w<<<1280, 256, 0, stream>>>(Wih_m, Whm_pad, 1024, N3H, 600, HH, 1, dflag);
    pack_w<<<480, 256, 0, stream>>>(W_s, Ws_pad, 384, HH, HH, 0, 0, dflag);
    pack_w<<<480, 256, 0, stream>>>(W_t, Wt_pad, 384, HH, HH, 0, 0, dflag);
    pack_wf<<<48, 256, 0, stream>>>(W_m, Wf, dflag);
    pack_we<<<1, 320, 0, stream>>>(w_e, we2g, dflag);
    pack_bias<<<11, 256, 0, stream>>>(bih_p, bhh_p, bih_h, bhh_h, bih_m, bhh_m,
                                      bsum_p, bsum_h, bsum_m, dflag);

    // premise: gather -> gates (bias folded) -> h_s
    gather_embed<<<10240, 256, 0, stream>>>(premise, embed, Xbuf, dflag);
    gemm_bt<<<dim3(64, 8), 256, 0, stream>>>(Xbuf, Wp_pad, (u16*)regB, bsum_p, N3H, N3H, 0);
    lstm_act<<<10240, 256, 0, stream>>>((u16*)regB, h_s);
    // hypothesis: reuse Xbuf
    gather_embed<<<10240, 256, 0, stream>>>(hypothesis, embed, Xbuf, dflag);
    gemm_bt<<<dim3(64, 8), 256, 0, stream>>>(Xbuf, Wh_pad, (u16*)regC, bsum_h, N3H, N3H, 0);
    lstm_act<<<10240, 256, 0, stream>>>((u16*)regC, h_t);

    // projections (ordering chosen so region reuse is safe)
    gemm_bt<<<dim3(64, 3), 256, 0, stream>>>(h_s, Ws_pad, s_proj, nullptr, HH, KPAD, 0);   // into A (Xbuf dead)
    gemm_bt<<<dim3(64, 8), 256, 0, stream>>>(h_s, Wa_pad, (u16*)regB, nullptr, N3H, 0, 1); // Gm FRAGS into B
    gemm_bt<<<dim3(64, 3), 256, 0, stream>>>(h_t, Wt_pad, t_proj, nullptr, HH, KPAD, 0);   // into D (h_s dead)
    gemm_bt<<<dim3(64, 8), 256, 0, stream>>>(h_t, Whm_pad, (u16*)regC, bsum_m, N3H, N3H, 0); // hproj into C

    // sequential match-LSTM scan, one WG per batch, 1024 threads (16 waves)
    scan_kernel<<<BB, 1024, 0, stream>>>(s_proj, t_proj, (const uint4*)regB,
                                         (const u16*)regC, Wf, we2g,
                                         premise_len, hypothesis_len, h_fin);
    // classifier
    fc_softmax<<<1, 128, 0, stream>>>(h_fin, fc_w, fc_b, d_out, dflag);
}

// Round 8
// 593.693 us; speedup vs baseline: 28.1348x; 1.0499x over previous
//
#include <hip/hip_runtime.h>
#include <stdint.h>

typedef unsigned short u16;
typedef __attribute__((ext_vector_type(8))) __bf16 bf16x8;
typedef __attribute__((ext_vector_type(4))) float f32x4;

// ---------- bf16 helpers (raw-bit, exact bf16 semantics) ----------
__device__ __forceinline__ float bf2f(u16 u) {
    union { unsigned int i; float f; } v; v.i = ((unsigned int)u) << 16; return v.f;
}
__device__ __forceinline__ float bf2f_lo(unsigned int u) {
    union { unsigned int i; float f; } v; v.i = u << 16; return v.f;
}
__device__ __forceinline__ float bf2f_hi(unsigned int u) {
    union { unsigned int i; float f; } v; v.i = u & 0xffff0000u; return v.f;
}
__device__ __forceinline__ u16 f2bf(float f) {
    union { float f; unsigned int i; } v; v.f = f;
    unsigned int x = v.i;
    unsigned int r = (x + 0x7fffu + ((x >> 16) & 1u)) >> 16;
    return (u16)r;
}
__device__ __forceinline__ float rdf(const void* p, size_t i, int isbf) {
    return isbf ? bf2f(((const u16*)p)[i]) : ((const float*)p)[i];
}
__device__ __forceinline__ float fast_sigmoid(float x) {
    return __builtin_amdgcn_rcpf(1.f + __expf(-x));
}
__device__ __forceinline__ float fast_tanh(float x) {
    float u = __expf(x + x);
    return 1.f - 2.f * __builtin_amdgcn_rcpf(u + 1.f);
}
__device__ __forceinline__ bf16x8 as_bf8(uint4 u) {
    union { uint4 a; bf16x8 b; } c; c.a = u; return c.b;
}
__device__ __forceinline__ float rdlane_f(float v, int l) {
    return __int_as_float(__builtin_amdgcn_readlane(__float_as_int(v), l));
}

// Problem dims
#define BB 128
#define PP 64
#define KK 64
#define HH 300
#define MROWS 8192     // B*P = B*K
#define KPAD 320       // K padded; row stride for s_proj/t_proj/h_fin
#define N3H 900        // i,g,o gates only (f-gate unused: c_prev=0)
#define GLD 912        // Gm frag-padded col count (57 tiles x 16)
#define NT1 19         // phase-1 N-tiles (304 cols)
#define NT4 57         // phase-4 N-tiles (912 cols)
#define NW 16          // scan waves per block

// ---------- dtype detector ----------
__global__ void detect_dtype(const u16* __restrict__ raw, int* __restrict__ flag) {
    __shared__ int cnt;
    if (threadIdx.x == 0) cnt = 0;
    __syncthreads();
    if (threadIdx.x < 300 && (raw[threadIdx.x] & 0x8000u)) atomicAdd(&cnt, 1);
    __syncthreads();
    if (threadIdx.x == 0) *flag = (cnt < 8) ? 1 : 0;   // 1 = bf16, 0 = fp32
}

// ---------- prepack kernels ----------
__global__ void pack_w(const void* __restrict__ src, u16* __restrict__ dst,
                       int dstRowsPad, int nsrcRows, int srcld, int colOff, int igo,
                       const int* __restrict__ flag) {
    int i = blockIdx.x * 256 + threadIdx.x;
    if (i >= dstRowsPad * KPAD) return;
    int isbf = *flag;
    int r = i / KPAD, c = i % KPAD;
    u16 v = 0;
    if (r < nsrcRows && c < HH) {
        int sr = igo ? (r < HH ? r : r + HH) : r;
        v = f2bf(rdf(src, (size_t)sr * srcld + colOff + c, isbf));
    }
    dst[i] = v;
}

// fused pack of the 4 gate-weight matrices (blockIdx.y selects target)
__global__ void pack_w_gates(const void* __restrict__ Wp, const void* __restrict__ Wh,
                             const void* __restrict__ Wm,
                             u16* __restrict__ dp, u16* __restrict__ dh,
                             u16* __restrict__ da, u16* __restrict__ dm2,
                             const int* __restrict__ flag) {
    int i = blockIdx.x * 256 + threadIdx.x;
    if (i >= 1024 * KPAD) return;
    int y = blockIdx.y;
    int isbf = *flag;
    const void* src = (y == 0) ? Wp : (y == 1) ? Wh : Wm;
    u16* dst = (y == 0) ? dp : (y == 1) ? dh : (y == 2) ? da : dm2;
    int srcld = (y < 2) ? HH : 600;
    int colOff = (y == 3) ? HH : 0;
    int r = i / KPAD, c = i % KPAD;
    u16 v = 0;
    if (r < N3H && c < HH) {
        int sr = (r < HH) ? r : r + HH;   // igo row remap
        v = f2bf(rdf(src, (size_t)sr * srcld + colOff + c, isbf));
    }
    dst[i] = v;
}

// W_m packed to MFMA B-fragment layout: Wf[T][ks][lane] = bf16x8 of
// W_m[j = T*16 + (lane&15)][k = 32*ks + 8*(lane>>4) + e], e<8; zeros outside 300x300.
__global__ void pack_wf(const void* __restrict__ Wm, uint4* __restrict__ dst,
                        const int* __restrict__ flag) {
    int i = blockIdx.x * 256 + threadIdx.x;
    if (i >= NT1 * 10 * 64) return;
    int isbf = *flag;
    int lane = i & 63, ks = (i >> 6) % 10, T = i / 640;
    int j = T * 16 + (lane & 15);
    int k0 = 32 * ks + 8 * (lane >> 4);
    unsigned int d[4];
    #pragma unroll
    for (int q = 0; q < 4; ++q) {
        int ka = k0 + 2 * q, kb = k0 + 2 * q + 1;
        unsigned int lo = (j < 300 && ka < 300) ? f2bf(rdf(Wm, (size_t)j * HH + ka, isbf)) : 0;
        unsigned int hi = (j < 300 && kb < 300) ? f2bf(rdf(Wm, (size_t)j * HH + kb, isbf)) : 0;
        d[q] = lo | (hi << 16);
    }
    uint4 v; v.x = d[0]; v.y = d[1]; v.z = d[2]; v.w = d[3];
    dst[i] = v;
}

__global__ void pack_bias(const void* bip, const void* bhp, const void* bih_, const void* bhh_,
                          const void* bim, const void* bhm,
                          float* bp, float* bh, float* bm, const int* __restrict__ flag) {
    int i = blockIdx.x * 256 + threadIdx.x;
    if (i >= 3 * N3H) return;
    int isbf = *flag;
    int which = i / N3H, r = i % N3H;
    int sr = (r < HH) ? r : r + HH;
    if (which == 0)      bp[r] = rdf(bip, sr, isbf) + rdf(bhp, sr, isbf);
    else if (which == 1) bh[r] = rdf(bih_, sr, isbf) + rdf(bhh_, sr, isbf);
    else                 bm[r] = rdf(bim, sr, isbf) + rdf(bhm, sr, isbf);
}

// 2*w_e as float[320] (pads 0) for the scan
__global__ void pack_we(const void* __restrict__ we, float* __restrict__ dst,
                        const int* __restrict__ flag) {
    int i = threadIdx.x;   // 320
    dst[i] = (i < 300) ? 2.f * rdf(we, i, *flag) : 0.f;
}

__global__ void gather_embed(const int* __restrict__ idx, const void* __restrict__ embed,
                             u16* __restrict__ X, const int* __restrict__ flag) {
    int i = blockIdx.x * 256 + threadIdx.x;   // 8192*320 exact
    int isbf = *flag;
    int r = i / KPAD, c = i % KPAD;
    X[i] = (c < HH) ? f2bf(rdf(embed, (size_t)idx[r] * HH + c, isbf)) : (u16)0;
}

__global__ void zero_out(u16* out) { out[threadIdx.x] = 0; }

// ---------- MFMA GEMM:  C[M x N] = A[M x 320] * B[Npad x 320]^T (+bias) ----------
// frag=0: bf16 row-major out, cols [N, ldc) zero-padded.
// frag=1: write MFMA B-fragment layout for the scan's phase-4.
__global__ __launch_bounds__(256) void gemm_bt(
    const u16* __restrict__ A, const u16* __restrict__ B,
    u16* __restrict__ Cb, const float* __restrict__ bias, int N, int ldc, int frag)
{
    __shared__ __align__(16) u16 At[128 * 32];
    __shared__ __align__(16) u16 Bt[128 * 32];
    const int tid = threadIdx.x;
    const int m0 = blockIdx.x * 128;
    const int n0 = blockIdx.y * 128;
    const int lane = tid & 63;
    const int wave = tid >> 6;
    const int rm = (wave & 1) * 64;
    const int rn = (wave >> 1) * 64;
    const int qr = lane >> 4;
    const int lr = lane & 15;

    f32x4 acc[4][4] = {};

    const int c0 = tid, c1 = tid + 256;
    const int r0 = c0 >> 2, o0 = (c0 & 3) * 8;
    const int r1 = c1 >> 2, o1 = (c1 & 3) * 8;

    for (int k0 = 0; k0 < KPAD; k0 += 32) {
        uint4 a0v = *(const uint4*)(A + (size_t)(m0 + r0) * KPAD + k0 + o0);
        uint4 a1v = *(const uint4*)(A + (size_t)(m0 + r1) * KPAD + k0 + o1);
        uint4 b0v = *(const uint4*)(B + (size_t)(n0 + r0) * KPAD + k0 + o0);
        uint4 b1v = *(const uint4*)(B + (size_t)(n0 + r1) * KPAD + k0 + o1);
        __syncthreads();
        *(uint4*)(At + c0 * 8) = a0v;
        *(uint4*)(At + c1 * 8) = a1v;
        *(uint4*)(Bt + c0 * 8) = b0v;
        *(uint4*)(Bt + c1 * 8) = b1v;
        __syncthreads();
        bf16x8 af[4], bfr[4];
        #pragma unroll
        for (int i = 0; i < 4; ++i) {
            af[i]  = *(const bf16x8*)(At + (rm + i * 16 + lr) * 32 + qr * 8);
            bfr[i] = *(const bf16x8*)(Bt + (rn + i * 16 + lr) * 32 + qr * 8);
        }
        #pragma unroll
        for (int mi = 0; mi < 4; ++mi)
            #pragma unroll
            for (int ni = 0; ni < 4; ++ni)
                acc[mi][ni] = __builtin_amdgcn_mfma_f32_16x16x32_bf16(
                    af[mi], bfr[ni], acc[mi][ni], 0, 0, 0);
    }
    // C/D layout: col(n)=lane&15, row(m)=quad*4+reg   [verified m89/m91]
    #pragma unroll
    for (int mi = 0; mi < 4; ++mi) {
        #pragma unroll
        for (int ni = 0; ni < 4; ++ni) {
            int n = n0 + rn + ni * 16 + lr;
            int mb = m0 + rm + mi * 16 + qr * 4;
            if (!frag) {
                if (n >= ldc) continue;
                if (n < N) {
                    float bv = bias ? bias[n] : 0.f;
                    #pragma unroll
                    for (int r = 0; r < 4; ++r)
                        Cb[(size_t)(mb + r) * ldc + n] = f2bf(acc[mi][ni][r] + bv);
                } else {
                    #pragma unroll
                    for (int r = 0; r < 4; ++r)
                        Cb[(size_t)(mb + r) * ldc + n] = 0;
                }
            } else {
                if (n >= GLD) continue;
                int bb = mb >> 6, p0 = mb & 63;
                size_t base = ((((size_t)bb * NT4 + (n >> 4)) * 2 + (p0 >> 5)) * 64
                               + ((p0 >> 3) & 3) * 16 + (n & 15)) * 8 + (p0 & 7);
                u16 wv[4];
                if (n < N) {
                    float bv = bias ? bias[n] : 0.f;
                    #pragma unroll
                    for (int r = 0; r < 4; ++r) wv[r] = f2bf(acc[mi][ni][r] + bv);
                } else {
                    #pragma unroll
                    for (int r = 0; r < 4; ++r) wv[r] = 0;
                }
                uint2 st;
                st.x = (unsigned int)wv[0] | ((unsigned int)wv[1] << 16);
                st.y = (unsigned int)wv[2] | ((unsigned int)wv[3] << 16);
                *(uint2*)(Cb + base) = st;
            }
        }
    }
}

// ---------- LSTM0 activation ----------
__global__ void lstm_act(const u16* __restrict__ gates, u16* __restrict__ hout) {
    int idx = blockIdx.x * 256 + threadIdx.x;   // 8192*320 exact
    int r = idx / KPAD, c = idx % KPAD;
    float h = 0.f;
    if (c < HH) {
        const u16* g = gates + (size_t)r * N3H;
        float gi = bf2f(g[c]);
        float gg = bf2f(g[c + HH]);
        float go = bf2f(g[c + 2 * HH]);
        float cc = fast_sigmoid(gi) * fast_tanh(gg);
        h = fast_sigmoid(go) * fast_tanh(cc);
    }
    hout[idx] = f2bf(h);
}

// ---------- sequential scan: 1024 thr/WG (16 waves), MFMA matvecs ----------
// v9: __launch_bounds__(1024, 4) -- documented HIP path to the 128-VGPR tier
// (2nd arg = min waves/EU; 16 waves / 4 SIMDs = 4/EU is this kernel's floor).
// Phase 2 consumes exactly the columns its own wave produced in phase 1
// (tile w cols [16w,16w+16), plus tile 16+w for w<3): the tpm value for col
// 16T+c lives in lane c of the wave's accumulator -> v_readlane broadcast,
// no LDS round-trip, no barrier A. 4 barriers/iter instead of 5.
__global__ __launch_bounds__(1024, 4) void scan_kernel(
    const u16* __restrict__ sproj,            // [8192][320] bf16, pads 0
    const u16* __restrict__ tproj,            // [8192][320] bf16, pads 0
    const uint4* __restrict__ Gmf,            // [128][57][2][64] frags
    const u16* __restrict__ hp,               // [8192][900] bf16 (bias folded)
    const uint4* __restrict__ Wf,             // [19][10][64] frags
    const float* __restrict__ we2g,           // [320] 2*w_e, f32, pads 0
    const int* __restrict__ premise_len,
    const int* __restrict__ hypothesis_len,
    float* __restrict__ hfin)                 // [128][320] fp32
{
    __shared__ __align__(16) uint4 gml[NT4 * 2 * 64];   // 116736 B (Gm frags)
    __shared__ __align__(16) uint4 wlds[3 * 10 * 64];   // 30720 B (W tiles 16-18)
    __shared__ __align__(16) unsigned int hmhi[160];    // hm hi bf16 pairs (pads 0)
    __shared__ __align__(16) unsigned int hmlo[160];    // hm lo residual pairs
    __shared__ __align__(16) float part[NW][64];        // phase-2 partials (4096 B)
    __shared__ __align__(16) u16 aw_sh[128];            // alpha hi[0:64] lo[64:128]
    __shared__ __align__(16) float gates[912];
    // total LDS = 116736+30720+640+640+4096+256+3648 = 156736 B < 160 KiB

    const int b = blockIdx.x, t = threadIdx.x;
    const int lane = t & 63, w = t >> 6;
    const int lr = lane & 15, qr = lane >> 4;
    const int plen = premise_len[b], hlen = hypothesis_len[b];

    // ---- stage Gm frags + leftover W tiles (16-18) into LDS ----
    {
        const uint4* gsrc = Gmf + (size_t)b * (NT4 * 2 * 64);
        for (int i = t; i < NT4 * 2 * 64; i += 1024) gml[i] = gsrc[i];
    }
    for (int i = t; i < 3 * 10 * 64; i += 1024) wlds[i] = Wf[16 * 640 + i];
    if (t < 160) { hmhi[t] = 0; hmlo[t] = 0; }

    // ---- pin W tile w in registers (40 regs) ----
    uint4 wreg[10];
    #pragma unroll
    for (int ks = 0; ks < 10; ++ks) wreg[ks] = Wf[(size_t)w * 640 + ks * 64 + lane];

    // ---- phase-2 per-lane state: row p = lane; cols = this wave's P1 tiles ----
    const int wu = __builtin_amdgcn_readfirstlane(w);
    const bool hasB = (wu < 3);
    unsigned int spdA[8], spdB[8];        // sp[lane][16w..16w+16) and [256+16w..+16)
    {
        const u16* srow = sproj + (size_t)(b * PP + lane) * KPAD;
        uint4 v0 = *(const uint4*)(srow + 16 * wu);
        uint4 v1 = *(const uint4*)(srow + 16 * wu + 8);
        spdA[0] = v0.x; spdA[1] = v0.y; spdA[2] = v0.z; spdA[3] = v0.w;
        spdA[4] = v1.x; spdA[5] = v1.y; spdA[6] = v1.z; spdA[7] = v1.w;
        uint4 v2 = *(const uint4*)(srow + 256 + 16 * wu);
        uint4 v3 = *(const uint4*)(srow + 256 + 16 * wu + 8);
        spdB[0] = v2.x; spdB[1] = v2.y; spdB[2] = v2.z; spdB[3] = v2.w;
        spdB[4] = v3.x; spdB[5] = v3.y; spdB[6] = v3.z; spdB[7] = v3.w;
    }
    float weA[16], weB[16];               // 2*w_e slices (k-invariant)
    {
        const float* wA = we2g + 16 * wu;
        const float* wB = we2g + 256 + 16 * wu;
        #pragma unroll
        for (int j = 0; j < 16; ++j) { weA[j] = wA[j]; weB[j] = wB[j]; }
    }

    // wave 0: full wsum (Σ w_e) for the energy formula
    float wsumf = 0.f;
    if (w == 0) {
        float s = 0.f;
        #pragma unroll
        for (int q = 0; q < 5; ++q) s += we2g[lane + 64 * q];
        #pragma unroll
        for (int d = 32; d; d >>= 1) s += __shfl_xor(s, d);
        wsumf = 0.5f * s;
    }
    __syncthreads();

    const int nt4 = (w < 9) ? 4 : 3;   // phase-4 tiles: T = w + 16i (57 total)
    const bool act2 = lane < plen;

    for (int k = 0; k < hlen; ++k) {
        const u16* tprow = tproj + (size_t)(b * KK + k) * KPAD;
        const u16* hprow = hp + (size_t)(b * KK + k) * 900;

        // iter-start prefetches (consumed later in the iteration)
        u16 hpv[4];
        #pragma unroll
        for (int i = 0; i < 4; ++i) {
            hpv[i] = 0;
            if (i < nt4 && lane < 16) {
                int j = (w + 16 * i) * 16 + lane;
                if (j < 900) hpv[i] = hprow[j];
            }
        }
        u16 tk0 = 0, tk1 = 0;
        if (lane < 16) {
            tk0 = tprow[w * 16 + lane];
            if (hasB) tk1 = tprow[(16 + w) * 16 + lane];
        }

        // ---- phase 1: m_proj via MFMA; a1 built in 2 halves; reg tile (w) and
        //      LDS tile (16+w, waves 0-2) interleaved per half ----
        float vcolA, vcolB;
        {
            const unsigned int* abase = (lr == 1) ? hmlo : hmhi;
            uint4 z; z.x = 0; z.y = 0; z.z = 0; z.w = 0;
            f32x4 r0 = {}, r1 = {}, l0 = {}, l1 = {};
            #pragma unroll
            for (int h = 0; h < 2; ++h) {
                bf16x8 a1[5];
                #pragma unroll
                for (int j = 0; j < 5; ++j) {
                    int ks = 5 * h + j;
                    uint4 u = *(const uint4*)(abase + 16 * ks + 4 * qr);
                    a1[j] = as_bf8((lr < 2) ? u : z);
                }
                #pragma unroll
                for (int j = 0; j < 5; ++j) {
                    int ks = 5 * h + j;
                    if (j & 1) r1 = __builtin_amdgcn_mfma_f32_16x16x32_bf16(a1[j], as_bf8(wreg[ks]), r1, 0, 0, 0);
                    else       r0 = __builtin_amdgcn_mfma_f32_16x16x32_bf16(a1[j], as_bf8(wreg[ks]), r0, 0, 0, 0);
                }
                if (hasB) {
                    #pragma unroll
                    for (int j = 0; j < 5; ++j) {
                        int ks = 5 * h + j;
                        bf16x8 bb = as_bf8(wlds[wu * 640 + ks * 64 + lane]);
                        if (j & 1) l1 = __builtin_amdgcn_mfma_f32_16x16x32_bf16(a1[j], bb, l1, 0, 0, 0);
                        else       l0 = __builtin_amdgcn_mfma_f32_16x16x32_bf16(a1[j], bb, l0, 0, 0, 0);
                    }
                }
            }
            // lane c (c<16) holds tpm-col 16w+c in rows 0(hi)+1(lo) of the acc
            vcolA = 2.f * (bf2f(tk0) + ((r0[0] + r0[1]) + (r1[0] + r1[1])));
            vcolB = 2.f * (bf2f(tk1) + ((l0[0] + l0[1]) + (l1[0] + l1[1])));
        }

        // ---- phase 2 (no barrier: same-wave readlane broadcast of vcol) ----
        {
            float accn = 0.f;
            if (act2) {
                #pragma unroll
                for (int c = 0; c < 16; ++c) {
                    float xc = rdlane_f(vcolA, c);
                    float spv = (c & 1) ? bf2f_hi(spdA[c >> 1]) : bf2f_lo(spdA[c >> 1]);
                    float arg = fmaf(2.f, spv, xc);
                    accn = fmaf(weA[c], __builtin_amdgcn_rcpf(__expf(arg) + 1.f), accn);
                }
                if (hasB) {
                    #pragma unroll
                    for (int c = 0; c < 16; ++c) {
                        float xc = rdlane_f(vcolB, c);
                        float spv = (c & 1) ? bf2f_hi(spdB[c >> 1]) : bf2f_lo(spdB[c >> 1]);
                        float arg = fmaf(2.f, spv, xc);
                        accn = fmaf(weB[c], __builtin_amdgcn_rcpf(__expf(arg) + 1.f), accn);
                    }
                }
            }
            part[w][lane] = act2 ? accn : 0.f;
        }
        __syncthreads();   // B: partials ready

        // ---- phase 3 (wave 0 only): reduce + softmax -> shared alpha hi/lo ----
        if (w == 0) {
            float s = 0.f;
            #pragma unroll
            for (int q = 0; q < NW; ++q) s += part[q][lane];
            float e = act2 ? (wsumf - s) : -1e30f;
            float mx = e;
            #pragma unroll
            for (int d = 32; d; d >>= 1) mx = fmaxf(mx, __shfl_xor(mx, d));
            float ex = act2 ? __expf(e - mx) : 0.f;
            float sm = ex;
            #pragma unroll
            for (int d = 32; d; d >>= 1) sm += __shfl_xor(sm, d);
            float al = ex * __builtin_amdgcn_rcpf(sm);
            u16 ah = f2bf(al);
            aw_sh[lane] = ah;
            aw_sh[64 + lane] = f2bf(al - bf2f(ah));
        }
        __syncthreads();   // B2: alpha visible

        // ---- phase 4: gates = alpha . Gm via MFMA (Gm frags LDS-resident) ----
        bf16x8 a4[2];
        {
            const u16* abase = aw_sh + ((lr == 1) ? 64 : 0);
            uint4 z; z.x = 0; z.y = 0; z.z = 0; z.w = 0;
            #pragma unroll
            for (int ks = 0; ks < 2; ++ks) {
                uint4 u = *(const uint4*)(abase + 32 * ks + 8 * qr);
                a4[ks] = as_bf8((lr < 2) ? u : z);
            }
        }
        #pragma unroll
        for (int i = 0; i < 4; ++i) {
            if (i < nt4) {
                int T = w + 16 * i;
                f32x4 ac0 = {}, ac1 = {};
                ac0 = __builtin_amdgcn_mfma_f32_16x16x32_bf16(a4[0], as_bf8(gml[(T * 2 + 0) * 64 + lane]), ac0, 0, 0, 0);
                ac1 = __builtin_amdgcn_mfma_f32_16x16x32_bf16(a4[1], as_bf8(gml[(T * 2 + 1) * 64 + lane]), ac1, 0, 0, 0);
                if (lane < 16) gates[T * 16 + lane] = ((ac0[0] + ac0[1]) + (ac1[0] + ac1[1])) + bf2f(hpv[i]);
            }
        }
        __syncthreads();   // C: gates final

        // ---- phase 5 (t<300): h_m = sig(o)*tanh(sig(i)*tanh(g)); pack hi/lo pairs ----
        if (t < 300) {
            float gi = gates[t], gg = gates[300 + t], go = gates[600 + t];
            float cc = fast_sigmoid(gi) * fast_tanh(gg);
            float h = fast_sigmoid(go) * fast_tanh(cc);
            if (k == hlen - 1) hfin[(size_t)b * KPAD + t] = h;
            u16 hh = f2bf(h);
            float res = h - bf2f(hh);
            float hn = __shfl_down(h, 1);     // partner t+1 (same wave: pairs never cross 64)
            float rn2 = __shfl_down(res, 1);
            if ((t & 1) == 0) {
                hmhi[t >> 1] = (unsigned int)hh | ((unsigned int)f2bf(hn) << 16);
                hmlo[t >> 1] = (unsigned int)f2bf(res) | ((unsigned int)f2bf(rn2) << 16);
            }
        }
        __syncthreads();   // D: hm ready for next phase 1
    }
}

// ---------- final FC + softmax over 3 classes (dual-dtype in AND out) ----------
__global__ void fc_softmax(const float* __restrict__ hfin, const void* __restrict__ fcw,
                           const void* __restrict__ fcb, void* __restrict__ out,
                           const int* __restrict__ flag) {
    __shared__ float lg[128][3];
    int t = threadIdx.x;            // 384 threads: (b, c) = (t&127, t>>7)
    int b = t & 127, c = t >> 7;
    int isbf = *flag;
    {
        float acc = rdf(fcb, c, isbf);
        const float* hr = hfin + (size_t)b * KPAD;
        for (int h = 0; h < HH; ++h) acc += hr[h] * rdf(fcw, (size_t)c * HH + h, isbf);
        lg[b][c] = acc;
    }
    __syncthreads();
    if (t < 128) {
        float l0 = lg[t][0], l1 = lg[t][1], l2 = lg[t][2];
        float mx = fmaxf(l0, fmaxf(l1, l2));
        float e0 = __expf(l0 - mx), e1 = __expf(l1 - mx), e2 = __expf(l2 - mx);
        float inv = __builtin_amdgcn_rcpf(e0 + e1 + e2);
        if (isbf) {
            u16* o = (u16*)out;
            o[t * 3 + 0] = f2bf(e0 * inv);
            o[t * 3 + 1] = f2bf(e1 * inv);
            o[t * 3 + 2] = f2bf(e2 * inv);
        } else {
            float* o = (float*)out;
            o[t * 3 + 0] = e0 * inv;
            o[t * 3 + 1] = e1 * inv;
            o[t * 3 + 2] = e2 * inv;
        }
    }
}

extern "C" void kernel_launch(void* const* d_in, const int* in_sizes, int n_in,
                              void* d_out, int out_size, void* d_ws, size_t ws_size,
                              hipStream_t stream) {
    const int* premise        = (const int*)d_in[0];
    const int* premise_len    = (const int*)d_in[1];
    const int* hypothesis     = (const int*)d_in[2];
    const int* hypothesis_len = (const int*)d_in[3];
    const void* embed = d_in[4];
    const void* w_e   = d_in[5];
    const void* W_s   = d_in[6];
    const void* W_t   = d_in[7];
    const void* W_m   = d_in[8];
    const void* fc_w  = d_in[9];
    const void* fc_b  = d_in[10];
    const void* Wih_p = d_in[11];
    const void* bih_p = d_in[13];
    const void* bhh_p = d_in[14];
    const void* Wih_h = d_in[15];
    const void* bih_h = d_in[17];
    const void* bhh_h = d_in[18];
    const void* Wih_m = d_in[19];
    const void* bih_m = d_in[21];
    const void* bhh_m = d_in[22];
    (void)in_sizes; (void)n_in; (void)out_size;

    // ---- lifetime-overlapped workspace arena ----
    char* w = (char*)d_ws;
    auto alloc = [&](size_t bytes) -> char* {
        char* r = (char*)(((uintptr_t)w + 255) & ~(uintptr_t)255);
        w = r + bytes;
        return r;
    };
    char* regA = alloc((size_t)MROWS * KPAD * 2);   // Xbuf -> s_proj
    char* regB = alloc((size_t)MROWS * GLD * 2);    // gates_p -> Gm frags (14.94 MB)
    char* regC = alloc((size_t)MROWS * N3H * 2);    // gates_h -> hproj
    char* regD = alloc((size_t)MROWS * KPAD * 2);   // h_s -> t_proj
    char* regE = alloc((size_t)MROWS * KPAD * 2);   // h_t -> h_fin
    u16* Wp_pad  = (u16*)alloc((size_t)1024 * KPAD * 2);
    u16* Wh_pad  = (u16*)alloc((size_t)1024 * KPAD * 2);
    u16* Wa_pad  = (u16*)alloc((size_t)1024 * KPAD * 2);
    u16* Whm_pad = (u16*)alloc((size_t)1024 * KPAD * 2);
    u16* Ws_pad  = (u16*)alloc((size_t)384 * KPAD * 2);
    u16* Wt_pad  = (u16*)alloc((size_t)384 * KPAD * 2);
    uint4* Wf    = (uint4*)alloc((size_t)NT1 * 10 * 64 * 16);
    float* we2g  = (float*)alloc(320 * 4);
    float* bsum_p = (float*)alloc(N3H * 4);
    float* bsum_h = (float*)alloc(N3H * 4);
    float* bsum_m = (float*)alloc(N3H * 4);
    int* dflag   = (int*)alloc(256);
    size_t needed = (size_t)(w - (char*)d_ws);
    if (needed > ws_size) {
        zero_out<<<1, 384, 0, stream>>>((u16*)d_out);
        return;
    }
    u16* Xbuf   = (u16*)regA;
    u16* s_proj = (u16*)regA;                       // after Xbuf dead
    u16* h_s    = (u16*)regD;
    u16* t_proj = (u16*)regD;                       // after h_s dead
    u16* h_t    = (u16*)regE;
    float* h_fin = (float*)regE;                    // after h_t dead (scan time)

    // dtype detect, then prepack
    detect_dtype<<<1, 320, 0, stream>>>((const u16*)w_e, dflag);
    pack_w_gates<<<dim3(1280, 4), 256, 0, stream>>>(Wih_p, Wih_h, Wih_m,
                                                    Wp_pad, Wh_pad, Wa_pad, Whm_pad, dflag);
    pack_w<<<480, 256, 0, stream>>>(W_s, Ws_pad, 384, HH, HH, 0, 0, dflag);
    pack_w<<<480, 256, 0, stream>>>(W_t, Wt_pad, 384, HH, HH, 0, 0, dflag);
    pack_wf<<<48, 256, 0, stream>>>(W_m, Wf, dflag);
    pack_we<<<1, 320, 0, stream>>>(w_e, we2g, dflag);
    pack_bias<<<11, 256, 0, stream>>>(bih_p, bhh_p, bih_h, bhh_h, bih_m, bhh_m,
                                      bsum_p, bsum_h, bsum_m, dflag);

    // premise: gather -> gates (bias folded) -> h_s
    gather_embed<<<10240, 256, 0, stream>>>(premise, embed, Xbuf, dflag);
    gemm_bt<<<dim3(64, 8), 256, 0, stream>>>(Xbuf, Wp_pad, (u16*)regB, bsum_p, N3H, N3H, 0);
    lstm_act<<<10240, 256, 0, stream>>>((u16*)regB, h_s);
    // hypothesis: reuse Xbuf
    gather_embed<<<10240, 256, 0, stream>>>(hypothesis, embed, Xbuf, dflag);
    gemm_bt<<<dim3(64, 8), 256, 0, stream>>>(Xbuf, Wh_pad, (u16*)regC, bsum_h, N3H, N3H, 0);
    lstm_act<<<10240, 256, 0, stream>>>((u16*)regC, h_t);

    // projections (ordering chosen so region reuse is safe)
    gemm_bt<<<dim3(64, 3), 256, 0, stream>>>(h_s, Ws_pad, s_proj, nullptr, HH, KPAD, 0);   // into A (Xbuf dead)
    gemm_bt<<<dim3(64, 8), 256, 0, stream>>>(h_s, Wa_pad, (u16*)regB, nullptr, N3H, 0, 1); // Gm FRAGS into B
    gemm_bt<<<dim3(64, 3), 256, 0, stream>>>(h_t, Wt_pad, t_proj, nullptr, HH, KPAD, 0);   // into D (h_s dead)
    gemm_bt<<<dim3(64, 8), 256, 0, stream>>>(h_t, Whm_pad, (u16*)regC, bsum_m, N3H, N3H, 0); // hproj into C

    // sequential match-LSTM scan, one WG per batch, 1024 threads (16 waves)
    scan_kernel<<<BB, 1024, 0, stream>>>(s_proj, t_proj, (const uint4*)regB,
                                         (const u16*)regC, Wf, we2g,
                                         premise_len, hypothesis_len, h_fin);
    // classifier
    fc_softmax<<<1, 384, 0, stream>>>(h_fin, fc_w, fc_b, d_out, dflag);
}

// Round 9
// 590.108 us; speedup vs baseline: 28.3057x; 1.0061x over previous
//
#include <hip/hip_runtime.h>
#include <stdint.h>

typedef unsigned short u16;
typedef __attribute__((ext_vector_type(8))) __bf16 bf16x8;
typedef __attribute__((ext_vector_type(4))) float f32x4;

// ---------- bf16 helpers (raw-bit, exact bf16 semantics) ----------
__device__ __forceinline__ float bf2f(u16 u) {
    union { unsigned int i; float f; } v; v.i = ((unsigned int)u) << 16; return v.f;
}
__device__ __forceinline__ float bf2f_lo(unsigned int u) {
    union { unsigned int i; float f; } v; v.i = u << 16; return v.f;
}
__device__ __forceinline__ float bf2f_hi(unsigned int u) {
    union { unsigned int i; float f; } v; v.i = u & 0xffff0000u; return v.f;
}
__device__ __forceinline__ u16 f2bf(float f) {
    union { float f; unsigned int i; } v; v.f = f;
    unsigned int x = v.i;
    unsigned int r = (x + 0x7fffu + ((x >> 16) & 1u)) >> 16;
    return (u16)r;
}
__device__ __forceinline__ float rdf(const void* p, size_t i, int isbf) {
    return isbf ? bf2f(((const u16*)p)[i]) : ((const float*)p)[i];
}
__device__ __forceinline__ float fast_sigmoid(float x) {
    return __builtin_amdgcn_rcpf(1.f + __expf(-x));
}
__device__ __forceinline__ float fast_tanh(float x) {
    float u = __expf(x + x);
    return 1.f - 2.f * __builtin_amdgcn_rcpf(u + 1.f);
}
__device__ __forceinline__ bf16x8 as_bf8(uint4 u) {
    union { uint4 a; bf16x8 b; } c; c.a = u; return c.b;
}
__device__ __forceinline__ float rdlane_f(float v, int l) {
    return __int_as_float(__builtin_amdgcn_readlane(__float_as_int(v), l));
}

// Problem dims
#define BB 128
#define PP 64
#define KK 64
#define HH 300
#define MROWS 8192     // B*P = B*K
#define KPAD 320       // K padded; row stride for s_proj/t_proj/h_fin
#define N3H 900        // i,g,o gates only (f-gate unused: c_prev=0)
#define GLD 912        // Gm frag-padded col count (57 tiles x 16)
#define NT1 19         // phase-1 N-tiles (304 cols)
#define NT4 57         // phase-4 N-tiles (912 cols)
#define NW 16          // scan waves per block

// ---------- dtype detector ----------
__global__ void detect_dtype(const u16* __restrict__ raw, int* __restrict__ flag) {
    __shared__ int cnt;
    if (threadIdx.x == 0) cnt = 0;
    __syncthreads();
    if (threadIdx.x < 300 && (raw[threadIdx.x] & 0x8000u)) atomicAdd(&cnt, 1);
    __syncthreads();
    if (threadIdx.x == 0) *flag = (cnt < 8) ? 1 : 0;   // 1 = bf16, 0 = fp32
}

// ---------- prepack kernels ----------
__global__ void pack_w(const void* __restrict__ src, u16* __restrict__ dst,
                       int dstRowsPad, int nsrcRows, int srcld, int colOff, int igo,
                       const int* __restrict__ flag) {
    int i = blockIdx.x * 256 + threadIdx.x;
    if (i >= dstRowsPad * KPAD) return;
    int isbf = *flag;
    int r = i / KPAD, c = i % KPAD;
    u16 v = 0;
    if (r < nsrcRows && c < HH) {
        int sr = igo ? (r < HH ? r : r + HH) : r;
        v = f2bf(rdf(src, (size_t)sr * srcld + colOff + c, isbf));
    }
    dst[i] = v;
}

// fused pack of the 4 gate-weight matrices (blockIdx.y selects target)
__global__ void pack_w_gates(const void* __restrict__ Wp, const void* __restrict__ Wh,
                             const void* __restrict__ Wm,
                             u16* __restrict__ dp, u16* __restrict__ dh,
                             u16* __restrict__ da, u16* __restrict__ dm2,
                             const int* __restrict__ flag) {
    int i = blockIdx.x * 256 + threadIdx.x;
    if (i >= 1024 * KPAD) return;
    int y = blockIdx.y;
    int isbf = *flag;
    const void* src = (y == 0) ? Wp : (y == 1) ? Wh : Wm;
    u16* dst = (y == 0) ? dp : (y == 1) ? dh : (y == 2) ? da : dm2;
    int srcld = (y < 2) ? HH : 600;
    int colOff = (y == 3) ? HH : 0;
    int r = i / KPAD, c = i % KPAD;
    u16 v = 0;
    if (r < N3H && c < HH) {
        int sr = (r < HH) ? r : r + HH;   // igo row remap
        v = f2bf(rdf(src, (size_t)sr * srcld + colOff + c, isbf));
    }
    dst[i] = v;
}

// W_m packed to MFMA B-fragment layout: Wf[T][ks][lane] = bf16x8 of
// W_m[j = T*16 + (lane&15)][k = 32*ks + 8*(lane>>4) + e], e<8; zeros outside 300x300.
__global__ void pack_wf(const void* __restrict__ Wm, uint4* __restrict__ dst,
                        const int* __restrict__ flag) {
    int i = blockIdx.x * 256 + threadIdx.x;
    if (i >= NT1 * 10 * 64) return;
    int isbf = *flag;
    int lane = i & 63, ks = (i >> 6) % 10, T = i / 640;
    int j = T * 16 + (lane & 15);
    int k0 = 32 * ks + 8 * (lane >> 4);
    unsigned int d[4];
    #pragma unroll
    for (int q = 0; q < 4; ++q) {
        int ka = k0 + 2 * q, kb = k0 + 2 * q + 1;
        unsigned int lo = (j < 300 && ka < 300) ? f2bf(rdf(Wm, (size_t)j * HH + ka, isbf)) : 0;
        unsigned int hi = (j < 300 && kb < 300) ? f2bf(rdf(Wm, (size_t)j * HH + kb, isbf)) : 0;
        d[q] = lo | (hi << 16);
    }
    uint4 v; v.x = d[0]; v.y = d[1]; v.z = d[2]; v.w = d[3];
    dst[i] = v;
}

__global__ void pack_bias(const void* bip, const void* bhp, const void* bih_, const void* bhh_,
                          const void* bim, const void* bhm,
                          float* bp, float* bh, float* bm, const int* __restrict__ flag) {
    int i = blockIdx.x * 256 + threadIdx.x;
    if (i >= 3 * N3H) return;
    int isbf = *flag;
    int which = i / N3H, r = i % N3H;
    int sr = (r < HH) ? r : r + HH;
    if (which == 0)      bp[r] = rdf(bip, sr, isbf) + rdf(bhp, sr, isbf);
    else if (which == 1) bh[r] = rdf(bih_, sr, isbf) + rdf(bhh_, sr, isbf);
    else                 bm[r] = rdf(bim, sr, isbf) + rdf(bhm, sr, isbf);
}

// 2*w_e as float[320] (pads 0) for the scan
__global__ void pack_we(const void* __restrict__ we, float* __restrict__ dst,
                        const int* __restrict__ flag) {
    int i = threadIdx.x;   // 320
    dst[i] = (i < 300) ? 2.f * rdf(we, i, *flag) : 0.f;
}

__global__ void gather_embed(const int* __restrict__ idx, const void* __restrict__ embed,
                             u16* __restrict__ X, const int* __restrict__ flag) {
    int i = blockIdx.x * 256 + threadIdx.x;   // 8192*320 exact
    int isbf = *flag;
    int r = i / KPAD, c = i % KPAD;
    X[i] = (c < HH) ? f2bf(rdf(embed, (size_t)idx[r] * HH + c, isbf)) : (u16)0;
}

__global__ void zero_out(u16* out) { out[threadIdx.x] = 0; }

// ---------- MFMA GEMM:  C[M x N] = A[M x 320] * B[Npad x 320]^T (+bias) ----------
// frag=0: bf16 row-major out, cols [N, ldc) zero-padded.
// frag=1: write MFMA B-fragment layout for the scan's phase-4.
__global__ __launch_bounds__(256) void gemm_bt(
    const u16* __restrict__ A, const u16* __restrict__ B,
    u16* __restrict__ Cb, const float* __restrict__ bias, int N, int ldc, int frag)
{
    __shared__ __align__(16) u16 At[128 * 32];
    __shared__ __align__(16) u16 Bt[128 * 32];
    const int tid = threadIdx.x;
    const int m0 = blockIdx.x * 128;
    const int n0 = blockIdx.y * 128;
    const int lane = tid & 63;
    const int wave = tid >> 6;
    const int rm = (wave & 1) * 64;
    const int rn = (wave >> 1) * 64;
    const int qr = lane >> 4;
    const int lr = lane & 15;

    f32x4 acc[4][4] = {};

    const int c0 = tid, c1 = tid + 256;
    const int r0 = c0 >> 2, o0 = (c0 & 3) * 8;
    const int r1 = c1 >> 2, o1 = (c1 & 3) * 8;

    for (int k0 = 0; k0 < KPAD; k0 += 32) {
        uint4 a0v = *(const uint4*)(A + (size_t)(m0 + r0) * KPAD + k0 + o0);
        uint4 a1v = *(const uint4*)(A + (size_t)(m0 + r1) * KPAD + k0 + o1);
        uint4 b0v = *(const uint4*)(B + (size_t)(n0 + r0) * KPAD + k0 + o0);
        uint4 b1v = *(const uint4*)(B + (size_t)(n0 + r1) * KPAD + k0 + o1);
        __syncthreads();
        *(uint4*)(At + c0 * 8) = a0v;
        *(uint4*)(At + c1 * 8) = a1v;
        *(uint4*)(Bt + c0 * 8) = b0v;
        *(uint4*)(Bt + c1 * 8) = b1v;
        __syncthreads();
        bf16x8 af[4], bfr[4];
        #pragma unroll
        for (int i = 0; i < 4; ++i) {
            af[i]  = *(const bf16x8*)(At + (rm + i * 16 + lr) * 32 + qr * 8);
            bfr[i] = *(const bf16x8*)(Bt + (rn + i * 16 + lr) * 32 + qr * 8);
        }
        #pragma unroll
        for (int mi = 0; mi < 4; ++mi)
            #pragma unroll
            for (int ni = 0; ni < 4; ++ni)
                acc[mi][ni] = __builtin_amdgcn_mfma_f32_16x16x32_bf16(
                    af[mi], bfr[ni], acc[mi][ni], 0, 0, 0);
    }
    // C/D layout: col(n)=lane&15, row(m)=quad*4+reg   [verified m89/m91]
    #pragma unroll
    for (int mi = 0; mi < 4; ++mi) {
        #pragma unroll
        for (int ni = 0; ni < 4; ++ni) {
            int n = n0 + rn + ni * 16 + lr;
            int mb = m0 + rm + mi * 16 + qr * 4;
            if (!frag) {
                if (n >= ldc) continue;
                if (n < N) {
                    float bv = bias ? bias[n] : 0.f;
                    #pragma unroll
                    for (int r = 0; r < 4; ++r)
                        Cb[(size_t)(mb + r) * ldc + n] = f2bf(acc[mi][ni][r] + bv);
                } else {
                    #pragma unroll
                    for (int r = 0; r < 4; ++r)
                        Cb[(size_t)(mb + r) * ldc + n] = 0;
                }
            } else {
                if (n >= GLD) continue;
                int bb = mb >> 6, p0 = mb & 63;
                size_t base = ((((size_t)bb * NT4 + (n >> 4)) * 2 + (p0 >> 5)) * 64
                               + ((p0 >> 3) & 3) * 16 + (n & 15)) * 8 + (p0 & 7);
                u16 wv[4];
                if (n < N) {
                    float bv = bias ? bias[n] : 0.f;
                    #pragma unroll
                    for (int r = 0; r < 4; ++r) wv[r] = f2bf(acc[mi][ni][r] + bv);
                } else {
                    #pragma unroll
                    for (int r = 0; r < 4; ++r) wv[r] = 0;
                }
                uint2 st;
                st.x = (unsigned int)wv[0] | ((unsigned int)wv[1] << 16);
                st.y = (unsigned int)wv[2] | ((unsigned int)wv[3] << 16);
                *(uint2*)(Cb + base) = st;
            }
        }
    }
}

// ---------- LSTM0 activation ----------
__global__ void lstm_act(const u16* __restrict__ gates, u16* __restrict__ hout) {
    int idx = blockIdx.x * 256 + threadIdx.x;   // 8192*320 exact
    int r = idx / KPAD, c = idx % KPAD;
    float h = 0.f;
    if (c < HH) {
        const u16* g = gates + (size_t)r * N3H;
        float gi = bf2f(g[c]);
        float gg = bf2f(g[c + HH]);
        float go = bf2f(g[c + 2 * HH]);
        float cc = fast_sigmoid(gi) * fast_tanh(gg);
        h = fast_sigmoid(go) * fast_tanh(cc);
    }
    hout[idx] = f2bf(h);
}

// ---------- sequential scan: 1024 thr/WG (16 waves), MFMA matvecs ----------
// v10: __launch_bounds__(1024, 1). hipcc's 2nd arg is CUDA-style min-BLOCKS/CU,
// mapped to waves_per_eu = B*(T/64)/4. Evidence: (512,2)->128 VGPR, (512,1)->128,
// (1024,4)->16 w/EU (clamped 8) -> 64 VGPR [v9]. (1024,1) -> 4 waves/EU -> 128
// VGPR tier; persistent demand ~88 + transients ~25 fits -> no scratch spill.
__global__ __launch_bounds__(1024, 1) void scan_kernel(
    const u16* __restrict__ sproj,            // [8192][320] bf16, pads 0
    const u16* __restrict__ tproj,            // [8192][320] bf16, pads 0
    const uint4* __restrict__ Gmf,            // [128][57][2][64] frags
    const u16* __restrict__ hp,               // [8192][900] bf16 (bias folded)
    const uint4* __restrict__ Wf,             // [19][10][64] frags
    const float* __restrict__ we2g,           // [320] 2*w_e, f32, pads 0
    const int* __restrict__ premise_len,
    const int* __restrict__ hypothesis_len,
    float* __restrict__ hfin)                 // [128][320] fp32
{
    __shared__ __align__(16) uint4 gml[NT4 * 2 * 64];   // 116736 B (Gm frags)
    __shared__ __align__(16) uint4 wlds[3 * 10 * 64];   // 30720 B (W tiles 16-18)
    __shared__ __align__(16) unsigned int hmhi[160];    // hm hi bf16 pairs (pads 0)
    __shared__ __align__(16) unsigned int hmlo[160];    // hm lo residual pairs
    __shared__ __align__(16) float part[NW][64];        // phase-2 partials (4096 B)
    __shared__ __align__(16) u16 aw_sh[128];            // alpha hi[0:64] lo[64:128]
    __shared__ __align__(16) float gates[912];
    // total LDS = 116736+30720+640+640+4096+256+3648 = 156736 B < 160 KiB

    const int b = blockIdx.x, t = threadIdx.x;
    const int lane = t & 63, w = t >> 6;
    const int lr = lane & 15, qr = lane >> 4;
    const int plen = premise_len[b], hlen = hypothesis_len[b];

    // ---- stage Gm frags + leftover W tiles (16-18) into LDS ----
    {
        const uint4* gsrc = Gmf + (size_t)b * (NT4 * 2 * 64);
        for (int i = t; i < NT4 * 2 * 64; i += 1024) gml[i] = gsrc[i];
    }
    for (int i = t; i < 3 * 10 * 64; i += 1024) wlds[i] = Wf[16 * 640 + i];
    if (t < 160) { hmhi[t] = 0; hmlo[t] = 0; }

    // ---- pin W tile w in registers (40 regs) ----
    uint4 wreg[10];
    #pragma unroll
    for (int ks = 0; ks < 10; ++ks) wreg[ks] = Wf[(size_t)w * 640 + ks * 64 + lane];

    // ---- phase-2 per-lane state: row p = lane; cols = this wave's P1 tiles ----
    const int wu = __builtin_amdgcn_readfirstlane(w);
    const bool hasB = (wu < 3);
    unsigned int spdA[8], spdB[8];        // sp[lane][16w..16w+16) and [256+16w..+16)
    {
        const u16* srow = sproj + (size_t)(b * PP + lane) * KPAD;
        uint4 v0 = *(const uint4*)(srow + 16 * wu);
        uint4 v1 = *(const uint4*)(srow + 16 * wu + 8);
        spdA[0] = v0.x; spdA[1] = v0.y; spdA[2] = v0.z; spdA[3] = v0.w;
        spdA[4] = v1.x; spdA[5] = v1.y; spdA[6] = v1.z; spdA[7] = v1.w;
        uint4 v2 = *(const uint4*)(srow + 256 + 16 * wu);
        uint4 v3 = *(const uint4*)(srow + 256 + 16 * wu + 8);
        spdB[0] = v2.x; spdB[1] = v2.y; spdB[2] = v2.z; spdB[3] = v2.w;
        spdB[4] = v3.x; spdB[5] = v3.y; spdB[6] = v3.z; spdB[7] = v3.w;
    }
    float weA[16], weB[16];               // 2*w_e slices (k-invariant)
    {
        const float* wA = we2g + 16 * wu;
        const float* wB = we2g + 256 + 16 * wu;
        #pragma unroll
        for (int j = 0; j < 16; ++j) { weA[j] = wA[j]; weB[j] = wB[j]; }
    }

    // wave 0: full wsum (Σ w_e) for the energy formula
    float wsumf = 0.f;
    if (w == 0) {
        float s = 0.f;
        #pragma unroll
        for (int q = 0; q < 5; ++q) s += we2g[lane + 64 * q];
        #pragma unroll
        for (int d = 32; d; d >>= 1) s += __shfl_xor(s, d);
        wsumf = 0.5f * s;
    }
    __syncthreads();

    const int nt4 = (w < 9) ? 4 : 3;   // phase-4 tiles: T = w + 16i (57 total)
    const bool act2 = lane < plen;

    for (int k = 0; k < hlen; ++k) {
        const u16* tprow = tproj + (size_t)(b * KK + k) * KPAD;
        const u16* hprow = hp + (size_t)(b * KK + k) * 900;

        // iter-start prefetches (consumed later in the iteration)
        u16 hpv[4];
        #pragma unroll
        for (int i = 0; i < 4; ++i) {
            hpv[i] = 0;
            if (i < nt4 && lane < 16) {
                int j = (w + 16 * i) * 16 + lane;
                if (j < 900) hpv[i] = hprow[j];
            }
        }
        u16 tk0 = 0, tk1 = 0;
        if (lane < 16) {
            tk0 = tprow[w * 16 + lane];
            if (hasB) tk1 = tprow[(16 + w) * 16 + lane];
        }

        // ---- phase 1: m_proj via MFMA; a1 built in 2 halves; reg tile (w) and
        //      LDS tile (16+w, waves 0-2) interleaved per half ----
        float vcolA, vcolB;
        {
            const unsigned int* abase = (lr == 1) ? hmlo : hmhi;
            uint4 z; z.x = 0; z.y = 0; z.z = 0; z.w = 0;
            f32x4 r0 = {}, r1 = {}, l0 = {}, l1 = {};
            #pragma unroll
            for (int h = 0; h < 2; ++h) {
                bf16x8 a1[5];
                #pragma unroll
                for (int j = 0; j < 5; ++j) {
                    int ks = 5 * h + j;
                    uint4 u = *(const uint4*)(abase + 16 * ks + 4 * qr);
                    a1[j] = as_bf8((lr < 2) ? u : z);
                }
                #pragma unroll
                for (int j = 0; j < 5; ++j) {
                    int ks = 5 * h + j;
                    if (j & 1) r1 = __builtin_amdgcn_mfma_f32_16x16x32_bf16(a1[j], as_bf8(wreg[ks]), r1, 0, 0, 0);
                    else       r0 = __builtin_amdgcn_mfma_f32_16x16x32_bf16(a1[j], as_bf8(wreg[ks]), r0, 0, 0, 0);
                }
                if (hasB) {
                    #pragma unroll
                    for (int j = 0; j < 5; ++j) {
                        int ks = 5 * h + j;
                        bf16x8 bb = as_bf8(wlds[wu * 640 + ks * 64 + lane]);
                        if (j & 1) l1 = __builtin_amdgcn_mfma_f32_16x16x32_bf16(a1[j], bb, l1, 0, 0, 0);
                        else       l0 = __builtin_amdgcn_mfma_f32_16x16x32_bf16(a1[j], bb, l0, 0, 0, 0);
                    }
                }
            }
            // lane c (c<16) holds tpm-col 16w+c in rows 0(hi)+1(lo) of the acc
            vcolA = 2.f * (bf2f(tk0) + ((r0[0] + r0[1]) + (r1[0] + r1[1])));
            vcolB = 2.f * (bf2f(tk1) + ((l0[0] + l0[1]) + (l1[0] + l1[1])));
        }

        // ---- phase 2 (no barrier: same-wave readlane broadcast of vcol) ----
        {
            float accn = 0.f;
            if (act2) {
                #pragma unroll
                for (int c = 0; c < 16; ++c) {
                    float xc = rdlane_f(vcolA, c);
                    float spv = (c & 1) ? bf2f_hi(spdA[c >> 1]) : bf2f_lo(spdA[c >> 1]);
                    float arg = fmaf(2.f, spv, xc);
                    accn = fmaf(weA[c], __builtin_amdgcn_rcpf(__expf(arg) + 1.f), accn);
                }
                if (hasB) {
                    #pragma unroll
                    for (int c = 0; c < 16; ++c) {
                        float xc = rdlane_f(vcolB, c);
                        float spv = (c & 1) ? bf2f_hi(spdB[c >> 1]) : bf2f_lo(spdB[c >> 1]);
                        float arg = fmaf(2.f, spv, xc);
                        accn = fmaf(weB[c], __builtin_amdgcn_rcpf(__expf(arg) + 1.f), accn);
                    }
                }
            }
            part[w][lane] = act2 ? accn : 0.f;
        }
        __syncthreads();   // B: partials ready

        // ---- phase 3 (wave 0 only): reduce + softmax -> shared alpha hi/lo ----
        if (w == 0) {
            float s = 0.f;
            #pragma unroll
            for (int q = 0; q < NW; ++q) s += part[q][lane];
            float e = act2 ? (wsumf - s) : -1e30f;
            float mx = e;
            #pragma unroll
            for (int d = 32; d; d >>= 1) mx = fmaxf(mx, __shfl_xor(mx, d));
            float ex = act2 ? __expf(e - mx) : 0.f;
            float sm = ex;
            #pragma unroll
            for (int d = 32; d; d >>= 1) sm += __shfl_xor(sm, d);
            float al = ex * __builtin_amdgcn_rcpf(sm);
            u16 ah = f2bf(al);
            aw_sh[lane] = ah;
            aw_sh[64 + lane] = f2bf(al - bf2f(ah));
        }
        __syncthreads();   // B2: alpha visible

        // ---- phase 4: gates = alpha . Gm via MFMA (Gm frags LDS-resident) ----
        bf16x8 a4[2];
        {
            const u16* abase = aw_sh + ((lr == 1) ? 64 : 0);
            uint4 z; z.x = 0; z.y = 0; z.z = 0; z.w = 0;
            #pragma unroll
            for (int ks = 0; ks < 2; ++ks) {
                uint4 u = *(const uint4*)(abase + 32 * ks + 8 * qr);
                a4[ks] = as_bf8((lr < 2) ? u : z);
            }
        }
        #pragma unroll
        for (int i = 0; i < 4; ++i) {
            if (i < nt4) {
                int T = w + 16 * i;
                f32x4 ac0 = {}, ac1 = {};
                ac0 = __builtin_amdgcn_mfma_f32_16x16x32_bf16(a4[0], as_bf8(gml[(T * 2 + 0) * 64 + lane]), ac0, 0, 0, 0);
                ac1 = __builtin_amdgcn_mfma_f32_16x16x32_bf16(a4[1], as_bf8(gml[(T * 2 + 1) * 64 + lane]), ac1, 0, 0, 0);
                if (lane < 16) gates[T * 16 + lane] = ((ac0[0] + ac0[1]) + (ac1[0] + ac1[1])) + bf2f(hpv[i]);
            }
        }
        __syncthreads();   // C: gates final

        // ---- phase 5 (t<300): h_m = sig(o)*tanh(sig(i)*tanh(g)); pack hi/lo pairs ----
        if (t < 300) {
            float gi = gates[t], gg = gates[300 + t], go = gates[600 + t];
            float cc = fast_sigmoid(gi) * fast_tanh(gg);
            float h = fast_sigmoid(go) * fast_tanh(cc);
            if (k == hlen - 1) hfin[(size_t)b * KPAD + t] = h;
            u16 hh = f2bf(h);
            float res = h - bf2f(hh);
            float hn = __shfl_down(h, 1);     // partner t+1 (same wave: pairs never cross 64)
            float rn2 = __shfl_down(res, 1);
            if ((t & 1) == 0) {
                hmhi[t >> 1] = (unsigned int)hh | ((unsigned int)f2bf(hn) << 16);
                hmlo[t >> 1] = (unsigned int)f2bf(res) | ((unsigned int)f2bf(rn2) << 16);
            }
        }
        __syncthreads();   // D: hm ready for next phase 1
    }
}

// ---------- final FC + softmax over 3 classes (dual-dtype in AND out) ----------
__global__ void fc_softmax(const float* __restrict__ hfin, const void* __restrict__ fcw,
                           const void* __restrict__ fcb, void* __restrict__ out,
                           const int* __restrict__ flag) {
    __shared__ float lg[128][3];
    int t = threadIdx.x;            // 384 threads: (b, c) = (t&127, t>>7)
    int b = t & 127, c = t >> 7;
    int isbf = *flag;
    {
        float acc = rdf(fcb, c, isbf);
        const float* hr = hfin + (size_t)b * KPAD;
        for (int h = 0; h < HH; ++h) acc += hr[h] * rdf(fcw, (size_t)c * HH + h, isbf);
        lg[b][c] = acc;
    }
    __syncthreads();
    if (t < 128) {
        float l0 = lg[t][0], l1 = lg[t][1], l2 = lg[t][2];
        float mx = fmaxf(l0, fmaxf(l1, l2));
        float e0 = __expf(l0 - mx), e1 = __expf(l1 - mx), e2 = __expf(l2 - mx);
        float inv = __builtin_amdgcn_rcpf(e0 + e1 + e2);
        if (isbf) {
            u16* o = (u16*)out;
            o[t * 3 + 0] = f2bf(e0 * inv);
            o[t * 3 + 1] = f2bf(e1 * inv);
            o[t * 3 + 2] = f2bf(e2 * inv);
        } else {
            float* o = (float*)out;
            o[t * 3 + 0] = e0 * inv;
            o[t * 3 + 1] = e1 * inv;
            o[t * 3 + 2] = e2 * inv;
        }
    }
}

extern "C" void kernel_launch(void* const* d_in, const int* in_sizes, int n_in,
                              void* d_out, int out_size, void* d_ws, size_t ws_size,
                              hipStream_t stream) {
    const int* premise        = (const int*)d_in[0];
    const int* premise_len    = (const int*)d_in[1];
    const int* hypothesis     = (const int*)d_in[2];
    const int* hypothesis_len = (const int*)d_in[3];
    const void* embed = d_in[4];
    const void* w_e   = d_in[5];
    const void* W_s   = d_in[6];
    const void* W_t   = d_in[7];
    const void* W_m   = d_in[8];
    const void* fc_w  = d_in[9];
    const void* fc_b  = d_in[10];
    const void* Wih_p = d_in[11];
    const void* bih_p = d_in[13];
    const void* bhh_p = d_in[14];
    const void* Wih_h = d_in[15];
    const void* bih_h = d_in[17];
    const void* bhh_h = d_in[18];
    const void* Wih_m = d_in[19];
    const void* bih_m = d_in[21];
    const void* bhh_m = d_in[22];
    (void)in_sizes; (void)n_in; (void)out_size;

    // ---- lifetime-overlapped workspace arena ----
    char* w = (char*)d_ws;
    auto alloc = [&](size_t bytes) -> char* {
        char* r = (char*)(((uintptr_t)w + 255) & ~(uintptr_t)255);
        w = r + bytes;
        return r;
    };
    char* regA = alloc((size_t)MROWS * KPAD * 2);   // Xbuf -> s_proj
    char* regB = alloc((size_t)MROWS * GLD * 2);    // gates_p -> Gm frags (14.94 MB)
    char* regC = alloc((size_t)MROWS * N3H * 2);    // gates_h -> hproj
    char* regD = alloc((size_t)MROWS * KPAD * 2);   // h_s -> t_proj
    char* regE = alloc((size_t)MROWS * KPAD * 2);   // h_t -> h_fin
    u16* Wp_pad  = (u16*)alloc((size_t)1024 * KPAD * 2);
    u16* Wh_pad  = (u16*)alloc((size_t)1024 * KPAD * 2);
    u16* Wa_pad  = (u16*)alloc((size_t)1024 * KPAD * 2);
    u16* Whm_pad = (u16*)alloc((size_t)1024 * KPAD * 2);
    u16* Ws_pad  = (u16*)alloc((size_t)384 * KPAD * 2);
    u16* Wt_pad  = (u16*)alloc((size_t)384 * KPAD * 2);
    uint4* Wf    = (uint4*)alloc((size_t)NT1 * 10 * 64 * 16);
    float* we2g  = (float*)alloc(320 * 4);
    float* bsum_p = (float*)alloc(N3H * 4);
    float* bsum_h = (float*)alloc(N3H * 4);
    float* bsum_m = (float*)alloc(N3H * 4);
    int* dflag   = (int*)alloc(256);
    size_t needed = (size_t)(w - (char*)d_ws);
    if (needed > ws_size) {
        zero_out<<<1, 384, 0, stream>>>((u16*)d_out);
        return;
    }
    u16* Xbuf   = (u16*)regA;
    u16* s_proj = (u16*)regA;                       // after Xbuf dead
    u16* h_s    = (u16*)regD;
    u16* t_proj = (u16*)regD;                       // after h_s dead
    u16* h_t    = (u16*)regE;
    float* h_fin = (float*)regE;                    // after h_t dead (scan time)

    // dtype detect, then prepack
    detect_dtype<<<1, 320, 0, stream>>>((const u16*)w_e, dflag);
    pack_w_gates<<<dim3(1280, 4), 256, 0, stream>>>(Wih_p, Wih_h, Wih_m,
                                                    Wp_pad, Wh_pad, Wa_pad, Whm_pad, dflag);
    pack_w<<<480, 256, 0, stream>>>(W_s, Ws_pad, 384, HH, HH, 0, 0, dflag);
    pack_w<<<480, 256, 0, stream>>>(W_t, Wt_pad, 384, HH, HH, 0, 0, dflag);
    pack_wf<<<48, 256, 0, stream>>>(W_m, Wf, dflag);
    pack_we<<<1, 320, 0, stream>>>(w_e, we2g, dflag);
    pack_bias<<<11, 256, 0, stream>>>(bih_p, bhh_p, bih_h, bhh_h, bih_m, bhh_m,
                                      bsum_p, bsum_h, bsum_m, dflag);

    // premise: gather -> gates (bias folded) -> h_s
    gather_embed<<<10240, 256, 0, stream>>>(premise, embed, Xbuf, dflag);
    gemm_bt<<<dim3(64, 8), 256, 0, stream>>>(Xbuf, Wp_pad, (u16*)regB, bsum_p, N3H, N3H, 0);
    lstm_act<<<10240, 256, 0, stream>>>((u16*)regB, h_s);
    // hypothesis: reuse Xbuf
    gather_embed<<<10240, 256, 0, stream>>>(hypothesis, embed, Xbuf, dflag);
    gemm_bt<<<dim3(64, 8), 256, 0, stream>>>(Xbuf, Wh_pad, (u16*)regC, bsum_h, N3H, N3H, 0);
    lstm_act<<<10240, 256, 0, stream>>>((u16*)regC, h_t);

    // projections (ordering chosen so region reuse is safe)
    gemm_bt<<<dim3(64, 3), 256, 0, stream>>>(h_s, Ws_pad, s_proj, nullptr, HH, KPAD, 0);   // into A (Xbuf dead)
    gemm_bt<<<dim3(64, 8), 256, 0, stream>>>(h_s, Wa_pad, (u16*)regB, nullptr, N3H, 0, 1); // Gm FRAGS into B
    gemm_bt<<<dim3(64, 3), 256, 0, stream>>>(h_t, Wt_pad, t_proj, nullptr, HH, KPAD, 0);   // into D (h_s dead)
    gemm_bt<<<dim3(64, 8), 256, 0, stream>>>(h_t, Whm_pad, (u16*)regC, bsum_m, N3H, N3H, 0); // hproj into C

    // sequential match-LSTM scan, one WG per batch, 1024 threads (16 waves)
    scan_kernel<<<BB, 1024, 0, stream>>>(s_proj, t_proj, (const uint4*)regB,
                                         (const u16*)regC, Wf, we2g,
                                         premise_len, hypothesis_len, h_fin);
    // classifier
    fc_softmax<<<1, 384, 0, stream>>>(h_fin, fc_w, fc_b, d_out, dflag);
}

// Round 10
// 586.640 us; speedup vs baseline: 28.4730x; 1.0059x over previous
//
#include <hip/hip_runtime.h>
#include <stdint.h>

typedef unsigned short u16;
typedef __attribute__((ext_vector_type(8))) __bf16 bf16x8;
typedef __attribute__((ext_vector_type(4))) float f32x4;

// ---------- bf16 helpers (raw-bit, exact bf16 semantics) ----------
__device__ __forceinline__ float bf2f(u16 u) {
    union { unsigned int i; float f; } v; v.i = ((unsigned int)u) << 16; return v.f;
}
__device__ __forceinline__ float bf2f_lo(unsigned int u) {
    union { unsigned int i; float f; } v; v.i = u << 16; return v.f;
}
__device__ __forceinline__ float bf2f_hi(unsigned int u) {
    union { unsigned int i; float f; } v; v.i = u & 0xffff0000u; return v.f;
}
__device__ __forceinline__ u16 f2bf(float f) {
    union { float f; unsigned int i; } v; v.f = f;
    unsigned int x = v.i;
    unsigned int r = (x + 0x7fffu + ((x >> 16) & 1u)) >> 16;
    return (u16)r;
}
__device__ __forceinline__ float rdf(const void* p, size_t i, int isbf) {
    return isbf ? bf2f(((const u16*)p)[i]) : ((const float*)p)[i];
}
__device__ __forceinline__ float fast_sigmoid(float x) {
    return __builtin_amdgcn_rcpf(1.f + __expf(-x));
}
__device__ __forceinline__ float fast_tanh(float x) {
    float u = __expf(x + x);
    return 1.f - 2.f * __builtin_amdgcn_rcpf(u + 1.f);
}
__device__ __forceinline__ bf16x8 as_bf8(uint4 u) {
    union { uint4 a; bf16x8 b; } c; c.a = u; return c.b;
}
__device__ __forceinline__ float rdlane_f(float v, int l) {
    return __int_as_float(__builtin_amdgcn_readlane(__float_as_int(v), l));
}

// Problem dims
#define BB 128
#define PP 64
#define KK 64
#define HH 300
#define MROWS 8192     // B*P = B*K
#define KPAD 320       // K padded; row stride for s_proj/t_proj/h_fin
#define N3H 900        // i,g,o gates only (f-gate unused: c_prev=0)
#define GLD 912        // Gm frag-padded col count (57 tiles x 16)
#define NT1 19         // phase-1 N-tiles (304 cols)
#define NT4 57         // phase-4 N-tiles (912 cols)
#define NW 16          // scan waves per block

// ---------- dtype detector ----------
__global__ void detect_dtype(const u16* __restrict__ raw, int* __restrict__ flag) {
    __shared__ int cnt;
    if (threadIdx.x == 0) cnt = 0;
    __syncthreads();
    if (threadIdx.x < 300 && (raw[threadIdx.x] & 0x8000u)) atomicAdd(&cnt, 1);
    __syncthreads();
    if (threadIdx.x == 0) *flag = (cnt < 8) ? 1 : 0;   // 1 = bf16, 0 = fp32
}

// ---------- prepack kernels ----------
__global__ void pack_w(const void* __restrict__ src, u16* __restrict__ dst,
                       int dstRowsPad, int nsrcRows, int srcld, int colOff, int igo,
                       const int* __restrict__ flag) {
    int i = blockIdx.x * 256 + threadIdx.x;
    if (i >= dstRowsPad * KPAD) return;
    int isbf = *flag;
    int r = i / KPAD, c = i % KPAD;
    u16 v = 0;
    if (r < nsrcRows && c < HH) {
        int sr = igo ? (r < HH ? r : r + HH) : r;
        v = f2bf(rdf(src, (size_t)sr * srcld + colOff + c, isbf));
    }
    dst[i] = v;
}

// fused pack of the 4 gate-weight matrices (blockIdx.y selects target)
__global__ void pack_w_gates(const void* __restrict__ Wp, const void* __restrict__ Wh,
                             const void* __restrict__ Wm,
                             u16* __restrict__ dp, u16* __restrict__ dh,
                             u16* __restrict__ da, u16* __restrict__ dm2,
                             const int* __restrict__ flag) {
    int i = blockIdx.x * 256 + threadIdx.x;
    if (i >= 1024 * KPAD) return;
    int y = blockIdx.y;
    int isbf = *flag;
    const void* src = (y == 0) ? Wp : (y == 1) ? Wh : Wm;
    u16* dst = (y == 0) ? dp : (y == 1) ? dh : (y == 2) ? da : dm2;
    int srcld = (y < 2) ? HH : 600;
    int colOff = (y == 3) ? HH : 0;
    int r = i / KPAD, c = i % KPAD;
    u16 v = 0;
    if (r < N3H && c < HH) {
        int sr = (r < HH) ? r : r + HH;   // igo row remap
        v = f2bf(rdf(src, (size_t)sr * srcld + colOff + c, isbf));
    }
    dst[i] = v;
}

// W_m packed to MFMA B-fragment layout: Wf[T][ks][lane] = bf16x8 of
// W_m[j = T*16 + (lane&15)][k = 32*ks + 8*(lane>>4) + e], e<8; zeros outside 300x300.
__global__ void pack_wf(const void* __restrict__ Wm, uint4* __restrict__ dst,
                        const int* __restrict__ flag) {
    int i = blockIdx.x * 256 + threadIdx.x;
    if (i >= NT1 * 10 * 64) return;
    int isbf = *flag;
    int lane = i & 63, ks = (i >> 6) % 10, T = i / 640;
    int j = T * 16 + (lane & 15);
    int k0 = 32 * ks + 8 * (lane >> 4);
    unsigned int d[4];
    #pragma unroll
    for (int q = 0; q < 4; ++q) {
        int ka = k0 + 2 * q, kb = k0 + 2 * q + 1;
        unsigned int lo = (j < 300 && ka < 300) ? f2bf(rdf(Wm, (size_t)j * HH + ka, isbf)) : 0;
        unsigned int hi = (j < 300 && kb < 300) ? f2bf(rdf(Wm, (size_t)j * HH + kb, isbf)) : 0;
        d[q] = lo | (hi << 16);
    }
    uint4 v; v.x = d[0]; v.y = d[1]; v.z = d[2]; v.w = d[3];
    dst[i] = v;
}

__global__ void pack_bias(const void* bip, const void* bhp, const void* bih_, const void* bhh_,
                          const void* bim, const void* bhm,
                          float* bp, float* bh, float* bm, const int* __restrict__ flag) {
    int i = blockIdx.x * 256 + threadIdx.x;
    if (i >= 3 * N3H) return;
    int isbf = *flag;
    int which = i / N3H, r = i % N3H;
    int sr = (r < HH) ? r : r + HH;
    if (which == 0)      bp[r] = rdf(bip, sr, isbf) + rdf(bhp, sr, isbf);
    else if (which == 1) bh[r] = rdf(bih_, sr, isbf) + rdf(bhh_, sr, isbf);
    else                 bm[r] = rdf(bim, sr, isbf) + rdf(bhm, sr, isbf);
}

// 2*w_e as float[320] (pads 0) for the scan
__global__ void pack_we(const void* __restrict__ we, float* __restrict__ dst,
                        const int* __restrict__ flag) {
    int i = threadIdx.x;   // 320
    dst[i] = (i < 300) ? 2.f * rdf(we, i, *flag) : 0.f;
}

// merged premise+hypothesis gather: 2*8192*320 elements
__global__ void gather_embed2(const int* __restrict__ idxP, const int* __restrict__ idxH,
                              const void* __restrict__ embed,
                              u16* __restrict__ XP, u16* __restrict__ XH,
                              const int* __restrict__ flag) {
    int i = blockIdx.x * 256 + threadIdx.x;
    int isbf = *flag;
    int r = i / KPAD, c = i % KPAD;
    const int* idx = idxP; u16* X = XP; int rr = r;
    if (r >= MROWS) { idx = idxH; X = XH; rr = r - MROWS; }
    u16 v = (c < HH) ? f2bf(rdf(embed, (size_t)idx[rr] * HH + c, isbf)) : (u16)0;
    X[(size_t)rr * KPAD + c] = v;
}

__global__ void zero_out(u16* out) { out[threadIdx.x] = 0; }

// ---------- MFMA GEMM:  C[M x N] = A[M x 320] * B[Npad x 320]^T (+bias) ----------
// v11: global_load_lds (width 16) staging -- m97 structure: per K-step
// { issue 4 gll ; sync (drains vmcnt) ; ds_read frags ; MFMA ; sync }.
// LDS dest is linear in thread order (wave-uniform base + lane*16); global src per-lane.
// frag=0: bf16 row-major out, cols [N, ldc) zero-padded.
// frag=1: MFMA B-fragment layout for the scan's phase-4.
// A2 != nullptr: split mode -- blocks x >= gridDim.x/2 use {A2, B2, C2, bias2}.
__global__ __launch_bounds__(256) void gemm_bt(
    const u16* __restrict__ A, const u16* __restrict__ B,
    u16* __restrict__ Cb, const float* __restrict__ bias, int N, int ldc, int frag,
    const u16* __restrict__ A2, const u16* __restrict__ B2,
    u16* __restrict__ Cb2, const float* __restrict__ bias2)
{
    __shared__ __align__(16) u16 At[128 * 32];
    __shared__ __align__(16) u16 Bt[128 * 32];
    const int tid = threadIdx.x;
    int bx = blockIdx.x;
    const u16* Ause = A; const u16* Buse = B; u16* Cuse = Cb; const float* buse = bias;
    if (A2 != nullptr) {
        int half = gridDim.x >> 1;
        if (bx >= half) { bx -= half; Ause = A2; Buse = B2; Cuse = Cb2; buse = bias2; }
    }
    const int m0 = bx * 128;
    const int n0 = blockIdx.y * 128;
    const int lane = tid & 63;
    const int wave = tid >> 6;
    const int wvb = wave * 64;          // wave-uniform lane base
    const int rm = (wave & 1) * 64;
    const int rn = (wave >> 1) * 64;
    const int qr = lane >> 4;
    const int lr = lane & 15;

    f32x4 acc[4][4] = {};

    for (int k0 = 0; k0 < KPAD; k0 += 32) {
        // stage: 2 chunks x (A,B); each lane contributes 16 B, LDS linear in tid order
        #pragma unroll
        for (int c = 0; c < 2; ++c) {
            int cc = c * 256 + tid;
            int r = cc >> 2, o = (cc & 3) * 8;
            __builtin_amdgcn_global_load_lds(
                (const __attribute__((address_space(1))) void*)(Ause + (size_t)(m0 + r) * KPAD + k0 + o),
                (__attribute__((address_space(3))) void*)(At + (size_t)(c * 256 + wvb) * 8),
                16, 0, 0);
            __builtin_amdgcn_global_load_lds(
                (const __attribute__((address_space(1))) void*)(Buse + (size_t)(n0 + r) * KPAD + k0 + o),
                (__attribute__((address_space(3))) void*)(Bt + (size_t)(c * 256 + wvb) * 8),
                16, 0, 0);
        }
        __syncthreads();   // drains vmcnt: tiles resident
        bf16x8 af[4], bfr[4];
        #pragma unroll
        for (int i = 0; i < 4; ++i) {
            af[i]  = *(const bf16x8*)(At + (rm + i * 16 + lr) * 32 + qr * 8);
            bfr[i] = *(const bf16x8*)(Bt + (rn + i * 16 + lr) * 32 + qr * 8);
        }
        #pragma unroll
        for (int mi = 0; mi < 4; ++mi)
            #pragma unroll
            for (int ni = 0; ni < 4; ++ni)
                acc[mi][ni] = __builtin_amdgcn_mfma_f32_16x16x32_bf16(
                    af[mi], bfr[ni], acc[mi][ni], 0, 0, 0);
        __syncthreads();   // protect LDS before next stage
    }
    // C/D layout: col(n)=lane&15, row(m)=quad*4+reg   [verified m89/m91]
    #pragma unroll
    for (int mi = 0; mi < 4; ++mi) {
        #pragma unroll
        for (int ni = 0; ni < 4; ++ni) {
            int n = n0 + rn + ni * 16 + lr;
            int mb = m0 + rm + mi * 16 + qr * 4;
            if (!frag) {
                if (n >= ldc) continue;
                if (n < N) {
                    float bv = buse ? buse[n] : 0.f;
                    #pragma unroll
                    for (int r = 0; r < 4; ++r)
                        Cuse[(size_t)(mb + r) * ldc + n] = f2bf(acc[mi][ni][r] + bv);
                } else {
                    #pragma unroll
                    for (int r = 0; r < 4; ++r)
                        Cuse[(size_t)(mb + r) * ldc + n] = 0;
                }
            } else {
                if (n >= GLD) continue;
                int bb = mb >> 6, p0 = mb & 63;
                size_t base = ((((size_t)bb * NT4 + (n >> 4)) * 2 + (p0 >> 5)) * 64
                               + ((p0 >> 3) & 3) * 16 + (n & 15)) * 8 + (p0 & 7);
                u16 wv[4];
                if (n < N) {
                    float bv = buse ? buse[n] : 0.f;
                    #pragma unroll
                    for (int r = 0; r < 4; ++r) wv[r] = f2bf(acc[mi][ni][r] + bv);
                } else {
                    #pragma unroll
                    for (int r = 0; r < 4; ++r) wv[r] = 0;
                }
                uint2 st;
                st.x = (unsigned int)wv[0] | ((unsigned int)wv[1] << 16);
                st.y = (unsigned int)wv[2] | ((unsigned int)wv[3] << 16);
                *(uint2*)(Cuse + base) = st;
            }
        }
    }
}

// ---------- LSTM0 activation (merged premise+hypothesis) ----------
__global__ void lstm_act2(const u16* __restrict__ g1, const u16* __restrict__ g2,
                          u16* __restrict__ h1, u16* __restrict__ h2) {
    int idx = blockIdx.x * 256 + threadIdx.x;   // 2*8192*320 exact
    int r = idx / KPAD, c = idx % KPAD;
    const u16* gsrc = g1; u16* ho = h1; int rr = r;
    if (r >= MROWS) { gsrc = g2; ho = h2; rr = r - MROWS; }
    float h = 0.f;
    if (c < HH) {
        const u16* g = gsrc + (size_t)rr * N3H;
        float gi = bf2f(g[c]);
        float gg = bf2f(g[c + HH]);
        float go = bf2f(g[c + 2 * HH]);
        float cc = fast_sigmoid(gi) * fast_tanh(gg);
        h = fast_sigmoid(go) * fast_tanh(cc);
    }
    ho[(size_t)rr * KPAD + c] = f2bf(h);
}

// ---------- sequential scan: 1024 thr/WG (16 waves), MFMA matvecs ----------
// (unchanged from v10; 283 us, 64-VGPR cap is a per-block-file contract at
// 1024 threads -- VGPR cap = 65536/blockSize empirically, 2nd launch_bounds
// arg cannot override it)
__global__ __launch_bounds__(1024, 1) void scan_kernel(
    const u16* __restrict__ sproj,            // [8192][320] bf16, pads 0
    const u16* __restrict__ tproj,            // [8192][320] bf16, pads 0
    const uint4* __restrict__ Gmf,            // [128][57][2][64] frags
    const u16* __restrict__ hp,               // [8192][900] bf16 (bias folded)
    const uint4* __restrict__ Wf,             // [19][10][64] frags
    const float* __restrict__ we2g,           // [320] 2*w_e, f32, pads 0
    const int* __restrict__ premise_len,
    const int* __restrict__ hypothesis_len,
    float* __restrict__ hfin)                 // [128][320] fp32
{
    __shared__ __align__(16) uint4 gml[NT4 * 2 * 64];   // 116736 B (Gm frags)
    __shared__ __align__(16) uint4 wlds[3 * 10 * 64];   // 30720 B (W tiles 16-18)
    __shared__ __align__(16) unsigned int hmhi[160];    // hm hi bf16 pairs (pads 0)
    __shared__ __align__(16) unsigned int hmlo[160];    // hm lo residual pairs
    __shared__ __align__(16) float part[NW][64];        // phase-2 partials (4096 B)
    __shared__ __align__(16) u16 aw_sh[128];            // alpha hi[0:64] lo[64:128]
    __shared__ __align__(16) float gates[912];
    // total LDS = 156736 B < 160 KiB

    const int b = blockIdx.x, t = threadIdx.x;
    const int lane = t & 63, w = t >> 6;
    const int lr = lane & 15, qr = lane >> 4;
    const int plen = premise_len[b], hlen = hypothesis_len[b];

    // ---- stage Gm frags + leftover W tiles (16-18) into LDS ----
    {
        const uint4* gsrc = Gmf + (size_t)b * (NT4 * 2 * 64);
        for (int i = t; i < NT4 * 2 * 64; i += 1024) gml[i] = gsrc[i];
    }
    for (int i = t; i < 3 * 10 * 64; i += 1024) wlds[i] = Wf[16 * 640 + i];
    if (t < 160) { hmhi[t] = 0; hmlo[t] = 0; }

    // ---- pin W tile w in registers (40 regs) ----
    uint4 wreg[10];
    #pragma unroll
    for (int ks = 0; ks < 10; ++ks) wreg[ks] = Wf[(size_t)w * 640 + ks * 64 + lane];

    // ---- phase-2 per-lane state: row p = lane; cols = this wave's P1 tiles ----
    const int wu = __builtin_amdgcn_readfirstlane(w);
    const bool hasB = (wu < 3);
    unsigned int spdA[8], spdB[8];        // sp[lane][16w..16w+16) and [256+16w..+16)
    {
        const u16* srow = sproj + (size_t)(b * PP + lane) * KPAD;
        uint4 v0 = *(const uint4*)(srow + 16 * wu);
        uint4 v1 = *(const uint4*)(srow + 16 * wu + 8);
        spdA[0] = v0.x; spdA[1] = v0.y; spdA[2] = v0.z; spdA[3] = v0.w;
        spdA[4] = v1.x; spdA[5] = v1.y; spdA[6] = v1.z; spdA[7] = v1.w;
        uint4 v2 = *(const uint4*)(srow + 256 + 16 * wu);
        uint4 v3 = *(const uint4*)(srow + 256 + 16 * wu + 8);
        spdB[0] = v2.x; spdB[1] = v2.y; spdB[2] = v2.z; spdB[3] = v2.w;
        spdB[4] = v3.x; spdB[5] = v3.y; spdB[6] = v3.z; spdB[7] = v3.w;
    }
    float weA[16], weB[16];               // 2*w_e slices (k-invariant)
    {
        const float* wA = we2g + 16 * wu;
        const float* wB = we2g + 256 + 16 * wu;
        #pragma unroll
        for (int j = 0; j < 16; ++j) { weA[j] = wA[j]; weB[j] = wB[j]; }
    }

    // wave 0: full wsum (Σ w_e) for the energy formula
    float wsumf = 0.f;
    if (w == 0) {
        float s = 0.f;
        #pragma unroll
        for (int q = 0; q < 5; ++q) s += we2g[lane + 64 * q];
        #pragma unroll
        for (int d = 32; d; d >>= 1) s += __shfl_xor(s, d);
        wsumf = 0.5f * s;
    }
    __syncthreads();

    const int nt4 = (w < 9) ? 4 : 3;   // phase-4 tiles: T = w + 16i (57 total)
    const bool act2 = lane < plen;

    for (int k = 0; k < hlen; ++k) {
        const u16* tprow = tproj + (size_t)(b * KK + k) * KPAD;
        const u16* hprow = hp + (size_t)(b * KK + k) * 900;

        // iter-start prefetches (consumed later in the iteration)
        u16 hpv[4];
        #pragma unroll
        for (int i = 0; i < 4; ++i) {
            hpv[i] = 0;
            if (i < nt4 && lane < 16) {
                int j = (w + 16 * i) * 16 + lane;
                if (j < 900) hpv[i] = hprow[j];
            }
        }
        u16 tk0 = 0, tk1 = 0;
        if (lane < 16) {
            tk0 = tprow[w * 16 + lane];
            if (hasB) tk1 = tprow[(16 + w) * 16 + lane];
        }

        // ---- phase 1: m_proj via MFMA; a1 built in 2 halves; reg tile (w) and
        //      LDS tile (16+w, waves 0-2) interleaved per half ----
        float vcolA, vcolB;
        {
            const unsigned int* abase = (lr == 1) ? hmlo : hmhi;
            uint4 z; z.x = 0; z.y = 0; z.z = 0; z.w = 0;
            f32x4 r0 = {}, r1 = {}, l0 = {}, l1 = {};
            #pragma unroll
            for (int h = 0; h < 2; ++h) {
                bf16x8 a1[5];
                #pragma unroll
                for (int j = 0; j < 5; ++j) {
                    int ks = 5 * h + j;
                    uint4 u = *(const uint4*)(abase + 16 * ks + 4 * qr);
                    a1[j] = as_bf8((lr < 2) ? u : z);
                }
                #pragma unroll
                for (int j = 0; j < 5; ++j) {
                    int ks = 5 * h + j;
                    if (j & 1) r1 = __builtin_amdgcn_mfma_f32_16x16x32_bf16(a1[j], as_bf8(wreg[ks]), r1, 0, 0, 0);
                    else       r0 = __builtin_amdgcn_mfma_f32_16x16x32_bf16(a1[j], as_bf8(wreg[ks]), r0, 0, 0, 0);
                }
                if (hasB) {
                    #pragma unroll
                    for (int j = 0; j < 5; ++j) {
                        int ks = 5 * h + j;
                        bf16x8 bb = as_bf8(wlds[wu * 640 + ks * 64 + lane]);
                        if (j & 1) l1 = __builtin_amdgcn_mfma_f32_16x16x32_bf16(a1[j], bb, l1, 0, 0, 0);
                        else       l0 = __builtin_amdgcn_mfma_f32_16x16x32_bf16(a1[j], bb, l0, 0, 0, 0);
                    }
                }
            }
            // lane c (c<16) holds tpm-col 16w+c in rows 0(hi)+1(lo) of the acc
            vcolA = 2.f * (bf2f(tk0) + ((r0[0] + r0[1]) + (r1[0] + r1[1])));
            vcolB = 2.f * (bf2f(tk1) + ((l0[0] + l0[1]) + (l1[0] + l1[1])));
        }

        // ---- phase 2 (no barrier: same-wave readlane broadcast of vcol) ----
        {
            float accn = 0.f;
            if (act2) {
                #pragma unroll
                for (int c = 0; c < 16; ++c) {
                    float xc = rdlane_f(vcolA, c);
                    float spv = (c & 1) ? bf2f_hi(spdA[c >> 1]) : bf2f_lo(spdA[c >> 1]);
                    float arg = fmaf(2.f, spv, xc);
                    accn = fmaf(weA[c], __builtin_amdgcn_rcpf(__expf(arg) + 1.f), accn);
                }
                if (hasB) {
                    #pragma unroll
                    for (int c = 0; c < 16; ++c) {
                        float xc = rdlane_f(vcolB, c);
                        float spv = (c & 1) ? bf2f_hi(spdB[c >> 1]) : bf2f_lo(spdB[c >> 1]);
                        float arg = fmaf(2.f, spv, xc);
                        accn = fmaf(weB[c], __builtin_amdgcn_rcpf(__expf(arg) + 1.f), accn);
                    }
                }
            }
            part[w][lane] = act2 ? accn : 0.f;
        }
        __syncthreads();   // B: partials ready

        // ---- phase 3 (wave 0 only): reduce + softmax -> shared alpha hi/lo ----
        if (w == 0) {
            float s = 0.f;
            #pragma unroll
            for (int q = 0; q < NW; ++q) s += part[q][lane];
            float e = act2 ? (wsumf - s) : -1e30f;
            float mx = e;
            #pragma unroll
            for (int d = 32; d; d >>= 1) mx = fmaxf(mx, __shfl_xor(mx, d));
            float ex = act2 ? __expf(e - mx) : 0.f;
            float sm = ex;
            #pragma unroll
            for (int d = 32; d; d >>= 1) sm += __shfl_xor(sm, d);
            float al = ex * __builtin_amdgcn_rcpf(sm);
            u16 ah = f2bf(al);
            aw_sh[lane] = ah;
            aw_sh[64 + lane] = f2bf(al - bf2f(ah));
        }
        __syncthreads();   // B2: alpha visible

        // ---- phase 4: gates = alpha . Gm via MFMA (Gm frags LDS-resident) ----
        bf16x8 a4[2];
        {
            const u16* abase = aw_sh + ((lr == 1) ? 64 : 0);
            uint4 z; z.x = 0; z.y = 0; z.z = 0; z.w = 0;
            #pragma unroll
            for (int ks = 0; ks < 2; ++ks) {
                uint4 u = *(const uint4*)(abase + 32 * ks + 8 * qr);
                a4[ks] = as_bf8((lr < 2) ? u : z);
            }
        }
        #pragma unroll
        for (int i = 0; i < 4; ++i) {
            if (i < nt4) {
                int T = w + 16 * i;
                f32x4 ac0 = {}, ac1 = {};
                ac0 = __builtin_amdgcn_mfma_f32_16x16x32_bf16(a4[0], as_bf8(gml[(T * 2 + 0) * 64 + lane]), ac0, 0, 0, 0);
                ac1 = __builtin_amdgcn_mfma_f32_16x16x32_bf16(a4[1], as_bf8(gml[(T * 2 + 1) * 64 + lane]), ac1, 0, 0, 0);
                if (lane < 16) gates[T * 16 + lane] = ((ac0[0] + ac0[1]) + (ac1[0] + ac1[1])) + bf2f(hpv[i]);
            }
        }
        __syncthreads();   // C: gates final

        // ---- phase 5 (t<300): h_m = sig(o)*tanh(sig(i)*tanh(g)); pack hi/lo pairs ----
        if (t < 300) {
            float gi = gates[t], gg = gates[300 + t], go = gates[600 + t];
            float cc = fast_sigmoid(gi) * fast_tanh(gg);
            float h = fast_sigmoid(go) * fast_tanh(cc);
            if (k == hlen - 1) hfin[(size_t)b * KPAD + t] = h;
            u16 hh = f2bf(h);
            float res = h - bf2f(hh);
            float hn = __shfl_down(h, 1);     // partner t+1 (same wave: pairs never cross 64)
            float rn2 = __shfl_down(res, 1);
            if ((t & 1) == 0) {
                hmhi[t >> 1] = (unsigned int)hh | ((unsigned int)f2bf(hn) << 16);
                hmlo[t >> 1] = (unsigned int)f2bf(res) | ((unsigned int)f2bf(rn2) << 16);
            }
        }
        __syncthreads();   // D: hm ready for next phase 1
    }
}

// ---------- final FC + softmax over 3 classes (dual-dtype in AND out) ----------
__global__ void fc_softmax(const float* __restrict__ hfin, const void* __restrict__ fcw,
                           const void* __restrict__ fcb, void* __restrict__ out,
                           const int* __restrict__ flag) {
    __shared__ float lg[128][3];
    int t = threadIdx.x;            // 384 threads: (b, c) = (t&127, t>>7)
    int b = t & 127, c = t >> 7;
    int isbf = *flag;
    {
        float acc = rdf(fcb, c, isbf);
        const float* hr = hfin + (size_t)b * KPAD;
        for (int h = 0; h < HH; ++h) acc += hr[h] * rdf(fcw, (size_t)c * HH + h, isbf);
        lg[b][c] = acc;
    }
    __syncthreads();
    if (t < 128) {
        float l0 = lg[t][0], l1 = lg[t][1], l2 = lg[t][2];
        float mx = fmaxf(l0, fmaxf(l1, l2));
        float e0 = __expf(l0 - mx), e1 = __expf(l1 - mx), e2 = __expf(l2 - mx);
        float inv = __builtin_amdgcn_rcpf(e0 + e1 + e2);
        if (isbf) {
            u16* o = (u16*)out;
            o[t * 3 + 0] = f2bf(e0 * inv);
            o[t * 3 + 1] = f2bf(e1 * inv);
            o[t * 3 + 2] = f2bf(e2 * inv);
        } else {
            float* o = (float*)out;
            o[t * 3 + 0] = e0 * inv;
            o[t * 3 + 1] = e1 * inv;
            o[t * 3 + 2] = e2 * inv;
        }
    }
}

extern "C" void kernel_launch(void* const* d_in, const int* in_sizes, int n_in,
                              void* d_out, int out_size, void* d_ws, size_t ws_size,
                              hipStream_t stream) {
    const int* premise        = (const int*)d_in[0];
    const int* premise_len    = (const int*)d_in[1];
    const int* hypothesis     = (const int*)d_in[2];
    const int* hypothesis_len = (const int*)d_in[3];
    const void* embed = d_in[4];
    const void* w_e   = d_in[5];
    const void* W_s   = d_in[6];
    const void* W_t   = d_in[7];
    const void* W_m   = d_in[8];
    const void* fc_w  = d_in[9];
    const void* fc_b  = d_in[10];
    const void* Wih_p = d_in[11];
    const void* bih_p = d_in[13];
    const void* bhh_p = d_in[14];
    const void* Wih_h = d_in[15];
    const void* bih_h = d_in[17];
    const void* bhh_h = d_in[18];
    const void* Wih_m = d_in[19];
    const void* bih_m = d_in[21];
    const void* bhh_m = d_in[22];
    (void)in_sizes; (void)n_in; (void)out_size;

    // ---- lifetime-overlapped workspace arena ----
    char* w = (char*)d_ws;
    auto alloc = [&](size_t bytes) -> char* {
        char* r = (char*)(((uintptr_t)w + 255) & ~(uintptr_t)255);
        w = r + bytes;
        return r;
    };
    char* regA = alloc((size_t)MROWS * KPAD * 2);   // XbufP -> s_proj
    char* regB = alloc((size_t)MROWS * GLD * 2);    // gates_p -> Gm frags (14.94 MB)
    char* regC = alloc((size_t)MROWS * N3H * 2);    // gates_h -> hproj
    char* regD = alloc((size_t)MROWS * KPAD * 2);   // XbufH -> h_s -> t_proj
    char* regE = alloc((size_t)MROWS * KPAD * 2);   // h_t -> h_fin
    u16* Wp_pad  = (u16*)alloc((size_t)1024 * KPAD * 2);
    u16* Wh_pad  = (u16*)alloc((size_t)1024 * KPAD * 2);
    u16* Wa_pad  = (u16*)alloc((size_t)1024 * KPAD * 2);
    u16* Whm_pad = (u16*)alloc((size_t)1024 * KPAD * 2);
    u16* Ws_pad  = (u16*)alloc((size_t)384 * KPAD * 2);
    u16* Wt_pad  = (u16*)alloc((size_t)384 * KPAD * 2);
    uint4* Wf    = (uint4*)alloc((size_t)NT1 * 10 * 64 * 16);
    float* we2g  = (float*)alloc(320 * 4);
    float* bsum_p = (float*)alloc(N3H * 4);
    float* bsum_h = (float*)alloc(N3H * 4);
    float* bsum_m = (float*)alloc(N3H * 4);
    int* dflag   = (int*)alloc(256);
    size_t needed = (size_t)(w - (char*)d_ws);
    if (needed > ws_size) {
        zero_out<<<1, 384, 0, stream>>>((u16*)d_out);
        return;
    }
    u16* XbufP  = (u16*)regA;
    u16* s_proj = (u16*)regA;                       // after XbufP dead
    u16* XbufH  = (u16*)regD;
    u16* h_s    = (u16*)regD;                       // after XbufH dead
    u16* t_proj = (u16*)regD;                       // after h_s dead
    u16* h_t    = (u16*)regE;
    float* h_fin = (float*)regE;                    // after h_t dead (scan time)

    // dtype detect, then prepack
    detect_dtype<<<1, 320, 0, stream>>>((const u16*)w_e, dflag);
    pack_w_gates<<<dim3(1280, 4), 256, 0, stream>>>(Wih_p, Wih_h, Wih_m,
                                                    Wp_pad, Wh_pad, Wa_pad, Whm_pad, dflag);
    pack_w<<<480, 256, 0, stream>>>(W_s, Ws_pad, 384, HH, HH, 0, 0, dflag);
    pack_w<<<480, 256, 0, stream>>>(W_t, Wt_pad, 384, HH, HH, 0, 0, dflag);
    pack_wf<<<48, 256, 0, stream>>>(W_m, Wf, dflag);
    pack_we<<<1, 320, 0, stream>>>(w_e, we2g, dflag);
    pack_bias<<<11, 256, 0, stream>>>(bih_p, bhh_p, bih_h, bhh_h, bih_m, bhh_m,
                                      bsum_p, bsum_h, bsum_m, dflag);

    // gather both sequences, then merged gates GEMM (1024 blocks) + merged activation
    gather_embed2<<<20480, 256, 0, stream>>>(premise, hypothesis, embed, XbufP, XbufH, dflag);
    gemm_bt<<<dim3(128, 8), 256, 0, stream>>>(XbufP, Wp_pad, (u16*)regB, bsum_p, N3H, N3H, 0,
                                              XbufH, Wh_pad, (u16*)regC, bsum_h);
    lstm_act2<<<20480, 256, 0, stream>>>((u16*)regB, (u16*)regC, h_s, h_t);

    // projections (ordering chosen so region reuse is safe)
    gemm_bt<<<dim3(64, 3), 256, 0, stream>>>(h_s, Ws_pad, s_proj, nullptr, HH, KPAD, 0,
                                             nullptr, nullptr, nullptr, nullptr);          // into A (XbufP dead)
    gemm_bt<<<dim3(64, 8), 256, 0, stream>>>(h_s, Wa_pad, (u16*)regB, nullptr, N3H, 0, 1,
                                             nullptr, nullptr, nullptr, nullptr);          // Gm FRAGS into B
    gemm_bt<<<dim3(64, 3), 256, 0, stream>>>(h_t, Wt_pad, t_proj, nullptr, HH, KPAD, 0,
                                             nullptr, nullptr, nullptr, nullptr);          // into D (h_s dead)
    gemm_bt<<<dim3(64, 8), 256, 0, stream>>>(h_t, Whm_pad, (u16*)regC, bsum_m, N3H, N3H, 0,
                                             nullptr, nullptr, nullptr, nullptr);          // hproj into C

    // sequential match-LSTM scan, one WG per batch, 1024 threads (16 waves)
    scan_kernel<<<BB, 1024, 0, stream>>>(s_proj, t_proj, (const uint4*)regB,
                                         (const u16*)regC, Wf, we2g,
                                         premise_len, hypothesis_len, h_fin);
    // classifier
    fc_softmax<<<1, 384, 0, stream>>>(h_fin, fc_w, fc_b, d_out, dflag);
}